// Round 1
// baseline (1567.936 us; speedup 1.0000x reference)
//
#include <hip/hip_runtime.h>
#include <math.h>

#define Bb 4
#define Tt 1024
#define Cc 512
#define Hh 4
#define Dd 128
#define Mrows (Bb*Tt)   // 4096

__device__ __forceinline__ float readlane_f(float v, int lane) {
  return __uint_as_float(__builtin_amdgcn_readlane(__float_as_uint(v), lane));
}

// ---------------- LayerNorm (one block per row) ----------------
__global__ __launch_bounds__(256) void ln_kernel(const float* __restrict__ x,
    const float* __restrict__ g, const float* __restrict__ bta, float* __restrict__ out)
{
  int row = blockIdx.x, tid = threadIdx.x;
  const float* xr = x + (size_t)row * Cc;
  float v0 = xr[tid], v1 = xr[tid + 256];
  float s = v0 + v1, s2 = v0*v0 + v1*v1;
  #pragma unroll
  for (int off = 32; off > 0; off >>= 1) {
    s  += __shfl_down(s,  off, 64);
    s2 += __shfl_down(s2, off, 64);
  }
  __shared__ float rs[4], rq[4];
  int w = tid >> 6;
  if ((tid & 63) == 0) { rs[w] = s; rq[w] = s2; }
  __syncthreads();
  float S  = rs[0]+rs[1]+rs[2]+rs[3];
  float S2 = rq[0]+rq[1]+rq[2]+rq[3];
  float mean = S * (1.0f/Cc);
  float var  = S2 * (1.0f/Cc) - mean*mean;
  float inv = rsqrtf(var + 1e-5f);
  out[(size_t)row*Cc + tid]       = g[tid]     * (v0-mean)*inv + bta[tid];
  out[(size_t)row*Cc + tid + 256] = g[tid+256] * (v1-mean)*inv + bta[tid+256];
}

// ---------------- time-shift mix: xq,xk,xv,xg ----------------
__global__ __launch_bounds__(256) void mix_kernel(const float* __restrict__ h,
    const float* __restrict__ tmq, const float* __restrict__ tmk,
    const float* __restrict__ tmv, const float* __restrict__ tmg,
    float* __restrict__ xq, float* __restrict__ xk,
    float* __restrict__ xv, float* __restrict__ xg)
{
  int i = blockIdx.x * 256 + threadIdx.x;     // [0, B*T*C/4)
  size_t f = (size_t)i * 4;
  int bt = i / (Cc/4);
  int t  = bt % Tt;
  int c  = (i % (Cc/4)) * 4;
  float4 hv = *(const float4*)(h + f);
  float4 xxv = make_float4(0.f,0.f,0.f,0.f);
  if (t > 0) xxv = *(const float4*)(h + f - Cc);
  float4 tq = *(const float4*)(tmq + c);
  float4 tk = *(const float4*)(tmk + c);
  float4 tv = *(const float4*)(tmv + c);
  float4 tg = *(const float4*)(tmg + c);
  float4 o;
  o.x = hv.x*tq.x + xxv.x*(1.f-tq.x); o.y = hv.y*tq.y + xxv.y*(1.f-tq.y);
  o.z = hv.z*tq.z + xxv.z*(1.f-tq.z); o.w = hv.w*tq.w + xxv.w*(1.f-tq.w);
  *(float4*)(xq + f) = o;
  o.x = hv.x*tk.x + xxv.x*(1.f-tk.x); o.y = hv.y*tk.y + xxv.y*(1.f-tk.y);
  o.z = hv.z*tk.z + xxv.z*(1.f-tk.z); o.w = hv.w*tk.w + xxv.w*(1.f-tk.w);
  *(float4*)(xk + f) = o;
  o.x = hv.x*tv.x + xxv.x*(1.f-tv.x); o.y = hv.y*tv.y + xxv.y*(1.f-tv.y);
  o.z = hv.z*tv.z + xxv.z*(1.f-tv.z); o.w = hv.w*tv.w + xxv.w*(1.f-tv.w);
  *(float4*)(xv + f) = o;
  o.x = hv.x*tg.x + xxv.x*(1.f-tg.x); o.y = hv.y*tg.y + xxv.y*(1.f-tg.y);
  o.z = hv.z*tg.z + xxv.z*(1.f-tg.z); o.w = hv.w*tg.w + xxv.w*(1.f-tg.w);
  *(float4*)(xg + f) = o;
}

// ---------------- fp32 GEMM: out[M,N] = act(A[M,K] @ W[N,K]^T + res) ----------------
#define GBM 64
#define GBN 64
#define GBK 16
__global__ __launch_bounds__(256) void gemm_tn(const float* __restrict__ A,
    const float* __restrict__ W, const float* __restrict__ res,
    float* __restrict__ out, int M, int N, int K, int act)
{
  __shared__ float As[GBK][GBM];
  __shared__ float Ws[GBK][GBN];
  int tid = threadIdx.x;
  int m0 = blockIdx.y * GBM, n0 = blockIdx.x * GBN;
  int tx = tid & 15, ty = tid >> 4;
  int lr = tid >> 2;          // 0..63 row within tile
  int lc = (tid & 3) << 2;    // 0,4,8,12 within BK
  float acc[4][4];
  #pragma unroll
  for (int i=0;i<4;i++)
    #pragma unroll
    for (int j=0;j<4;j++) acc[i][j]=0.f;

  for (int k0 = 0; k0 < K; k0 += GBK) {
    float4 av = *(const float4*)&A[(size_t)(m0 + lr) * K + k0 + lc];
    float4 wv = *(const float4*)&W[(size_t)(n0 + lr) * K + k0 + lc];
    __syncthreads();
    As[lc+0][lr] = av.x; As[lc+1][lr] = av.y; As[lc+2][lr] = av.z; As[lc+3][lr] = av.w;
    Ws[lc+0][lr] = wv.x; Ws[lc+1][lr] = wv.y; Ws[lc+2][lr] = wv.z; Ws[lc+3][lr] = wv.w;
    __syncthreads();
    #pragma unroll
    for (int kk = 0; kk < GBK; ++kk) {
      float4 a4 = *(const float4*)&As[kk][ty*4];
      float4 b4 = *(const float4*)&Ws[kk][tx*4];
      float a[4] = {a4.x,a4.y,a4.z,a4.w};
      float b[4] = {b4.x,b4.y,b4.z,b4.w};
      #pragma unroll
      for (int i=0;i<4;i++)
        #pragma unroll
        for (int j=0;j<4;j++) acc[i][j] += a[i]*b[j];
    }
  }
  #pragma unroll
  for (int i=0;i<4;i++){
    int m = m0 + ty*4 + i;
    #pragma unroll
    for (int j=0;j<4;j++){
      int n = n0 + tx*4 + j;
      float vv = acc[i][j];
      if (res) vv += res[(size_t)m*N + n];
      if (act == 1) vv = 0.5f*vv*(1.f+erff(vv*0.70710678118f)); // exact gelu
      else if (act == 2) vv = 1.f/(1.f+expf(-vv));              // sigmoid
      out[(size_t)m*N + n] = vv;
    }
  }
}

// ---------------- exp(rmsnorm(x)) in place, per row ----------------
__global__ __launch_bounds__(256) void rmsexp_kernel(float* __restrict__ x,
    const float* __restrict__ scale)
{
  int row = blockIdx.x, tid = threadIdx.x;
  float* xr = x + (size_t)row * Cc;
  float v0 = xr[tid], v1 = xr[tid+256];
  float s2 = v0*v0 + v1*v1;
  #pragma unroll
  for (int off = 32; off > 0; off >>= 1) s2 += __shfl_down(s2, off, 64);
  __shared__ float rq[4];
  int w = tid >> 6;
  if ((tid & 63) == 0) rq[w] = s2;
  __syncthreads();
  float S2 = rq[0]+rq[1]+rq[2]+rq[3];
  float norm = sqrtf(S2) * 0.044194173824159216f;  // 1/sqrt(512)
  float r = 1.f / (norm + 1e-8f);
  xr[tid]     = expf(scale[tid]     * v0 * r);
  xr[tid+256] = expf(scale[tid+256] * v1 * r);
}

// ---------------- Z scan: Z[b,t,h] = q_t . z_t,  z = lam*z + k ----------------
__global__ __launch_bounds__(128) void z_kernel(const float* __restrict__ q,
    const float* __restrict__ k, const float* __restrict__ td, float* __restrict__ Z)
{
  int bh = blockIdx.x; int b = bh >> 2, h = bh & 3;
  int tid = threadIdx.x;       // i = tid (0..127)
  __shared__ float ws2[2];
  size_t base = ((size_t)b*Tt)*Cc + h*Dd + tid;
  float lam = expf(-expf(td[h*Dd + tid]));
  float z = 0.f;
  for (int t = 0; t < Tt; ++t) {
    float kv = k[base + (size_t)t*Cc];
    float qv = q[base + (size_t)t*Cc];
    z = lam*z + kv;
    float p = qv*z;
    #pragma unroll
    for (int off = 32; off > 0; off >>= 1) p += __shfl_down(p, off, 64);
    if ((tid & 63) == 0) ws2[tid >> 6] = p;
    __syncthreads();
    if (tid == 0) Z[((size_t)b*Tt + t)*Hh + h] = ws2[0] + ws2[1];
    __syncthreads();
  }
}

// ---------------- main decayed-linear-attention scan: S[b,t,h,:] ----------------
// block = (b,h); 4 waves; wave w owns i in [w*32,w*32+32); lane l owns j0=l, j1=l+64
__global__ __launch_bounds__(256) void scan_kernel(const float* __restrict__ q,
    const float* __restrict__ k, const float* __restrict__ v,
    const float* __restrict__ td, float* __restrict__ S)
{
  __shared__ float part[4*128];
  int bh = blockIdx.x; int b = bh >> 2, h = bh & 3;
  int tid = threadIdx.x; int w = tid >> 6, l = tid & 63;
  const size_t base = ((size_t)b*Tt)*Cc + h*Dd;
  int iq = w*32 + (l & 31);
  float lamv = expf(-expf(td[h*Dd + iq]));
  float lam_s[32];
  #pragma unroll
  for (int ii = 0; ii < 32; ++ii) lam_s[ii] = readlane_f(lamv, ii);

  float A0[32], A1[32];
  #pragma unroll
  for (int ii = 0; ii < 32; ++ii) { A0[ii]=0.f; A1[ii]=0.f; }

  const float* qk_ptr = (l < 32) ? q : k;
  float qk = qk_ptr[base + iq];
  float v0 = v[base + l];
  float v1 = v[base + l + 64];

  for (int t = 0; t < Tt; ++t) {
    float qk_c = qk, v0c = v0, v1c = v1;
    if (t + 1 < Tt) {
      size_t nb = base + (size_t)(t+1)*Cc;
      qk = qk_ptr[nb + iq];
      v0 = v[nb + l];
      v1 = v[nb + l + 64];
    }
    float s0 = 0.f, s1 = 0.f;
    #pragma unroll
    for (int ii = 0; ii < 32; ++ii) {
      float qs = readlane_f(qk_c, ii);
      float ks = readlane_f(qk_c, 32 + ii);
      float kv0 = ks * v0c;
      float kv1 = ks * v1c;
      A0[ii] = lam_s[ii]*A0[ii] + kv0;
      A1[ii] = lam_s[ii]*A1[ii] + kv1;
      s0 += qs * A0[ii];
      s1 += qs * A1[ii];
    }
    part[w*128 + l]      = s0;
    part[w*128 + l + 64] = s1;
    __syncthreads();
    if (tid < 128) {
      float sv = part[tid] + part[128+tid] + part[256+tid] + part[384+tid];
      S[base + (size_t)t*Cc + tid] = sv;
    }
    __syncthreads();
  }
}

// ---------------- gatt = g * S / Z ----------------
__global__ __launch_bounds__(256) void gatt_kernel(const float* __restrict__ g,
    const float* __restrict__ S, const float* __restrict__ Z, float* __restrict__ out)
{
  int i = blockIdx.x * 256 + threadIdx.x;    // [0, B*T*C/4)
  size_t f = (size_t)i * 4;
  int bt = i / (Cc/4);
  int c  = (i % (Cc/4)) * 4;
  int h  = c >> 7;
  float zi = 1.f / Z[(size_t)bt*Hh + h];
  float4 gv = *(const float4*)(g + f);
  float4 sv = *(const float4*)(S + f);
  float4 o;
  o.x = gv.x*sv.x*zi; o.y = gv.y*sv.y*zi; o.z = gv.z*sv.z*zi; o.w = gv.w*sv.w*zi;
  *(float4*)(out + f) = o;
}

extern "C" void kernel_launch(void* const* d_in, const int* in_sizes, int n_in,
                              void* d_out, int out_size, void* d_ws, size_t ws_size,
                              hipStream_t stream) {
  const float* x    = (const float*)d_in[0];
  const float* ln1g = (const float*)d_in[1];
  const float* ln1b = (const float*)d_in[2];
  const float* ln2g = (const float*)d_in[3];
  const float* ln2b = (const float*)d_in[4];
  const float* td   = (const float*)d_in[5];
  const float* tmq  = (const float*)d_in[6];
  const float* tmk  = (const float*)d_in[7];
  const float* tmv  = (const float*)d_in[8];
  const float* tmg  = (const float*)d_in[9];
  const float* Wq   = (const float*)d_in[10];
  const float* Wk   = (const float*)d_in[11];
  const float* Wv   = (const float*)d_in[12];
  const float* Wg   = (const float*)d_in[13];
  const float* Wo   = (const float*)d_in[14];
  const float* rsc  = (const float*)d_in[15];
  const float* W1   = (const float*)d_in[16];
  const float* W2   = (const float*)d_in[17];
  float* ws = (float*)d_ws;
  const size_t E = (size_t)Bb*Tt*Cc;           // 2,097,152
  float* s0 = ws;          // h -> q -> h2
  float* s1 = ws + E;      // xq -> k
  float* s2 = ws + 2*E;    // xk -> v
  float* s3 = ws + 3*E;    // xv -> g
  float* s4 = ws + 4*E;    // xg -> S -> gatt
  float* x1 = ws + 5*E;
  float* mid= ws + 6*E;    // 4E
  float* Z  = ws + 10*E;   // B*T*H

  dim3 g512(8, 64), g2048(32, 64);
  int ew = (int)(E/4/256);  // 2048 blocks for float4-elementwise

  ln_kernel<<<Mrows,256,0,stream>>>(x, ln1g, ln1b, s0);
  mix_kernel<<<ew,256,0,stream>>>(s0, tmq,tmk,tmv,tmg, s1,s2,s3,s4);
  gemm_tn<<<g512,256,0,stream>>>(s1, Wq, nullptr, s0, Mrows,512,512, 0);  // q
  gemm_tn<<<g512,256,0,stream>>>(s2, Wk, nullptr, s1, Mrows,512,512, 0);  // k
  gemm_tn<<<g512,256,0,stream>>>(s3, Wv, nullptr, s2, Mrows,512,512, 0);  // v
  gemm_tn<<<g512,256,0,stream>>>(s4, Wg, nullptr, s3, Mrows,512,512, 2);  // g=sigmoid
  rmsexp_kernel<<<Mrows,256,0,stream>>>(s0, rsc);                          // q
  rmsexp_kernel<<<Mrows,256,0,stream>>>(s1, rsc);                          // k
  z_kernel<<<Bb*Hh,128,0,stream>>>(s0, s1, td, Z);
  scan_kernel<<<Bb*Hh,256,0,stream>>>(s0, s1, s2, td, s4);                 // S
  gatt_kernel<<<ew,256,0,stream>>>(s3, s4, Z, s4);                         // g*S/Z
  gemm_tn<<<g512,256,0,stream>>>(s4, Wo, x, x1, Mrows,512,512, 0);         // x1 = x + att
  ln_kernel<<<Mrows,256,0,stream>>>(x1, ln2g, ln2b, s0);                   // h2
  gemm_tn<<<g2048,256,0,stream>>>(s0, W1, nullptr, mid, Mrows,2048,512, 1); // gelu
  gemm_tn<<<g512,256,0,stream>>>(mid, W2, x1, (float*)d_out, Mrows,512,2048, 0);
}

// Round 2
// 567.983 us; speedup vs baseline: 2.7605x; 2.7605x over previous
//
#include <hip/hip_runtime.h>
#include <math.h>

#define Bb 4
#define Tt 1024
#define Cc 512
#define Hh 4
#define Dd 128
#define Mrows (Bb*Tt)   // 4096
#define NC 32           // chunks
#define CL 32           // chunk length (NC*CL == Tt)
#define AUGSZ (Dd*(Dd+1))        // 16512 floats per (chunk, bh): [j(129)][i(128)]
#define AUGSTRIDE (16*AUGSZ)     // per-chunk stride (16 = B*H)

__device__ __forceinline__ float readlane_f(float v, int lane) {
  return __uint_as_float(__builtin_amdgcn_readlane(__float_as_uint(v), lane));
}

// ---------------- LayerNorm (one block per row) ----------------
__global__ __launch_bounds__(256) void ln_kernel(const float* __restrict__ x,
    const float* __restrict__ g, const float* __restrict__ bta, float* __restrict__ out)
{
  int row = blockIdx.x, tid = threadIdx.x;
  const float* xr = x + (size_t)row * Cc;
  float v0 = xr[tid], v1 = xr[tid + 256];
  float s = v0 + v1, s2 = v0*v0 + v1*v1;
  #pragma unroll
  for (int off = 32; off > 0; off >>= 1) {
    s  += __shfl_down(s,  off, 64);
    s2 += __shfl_down(s2, off, 64);
  }
  __shared__ float rs[4], rq[4];
  int w = tid >> 6;
  if ((tid & 63) == 0) { rs[w] = s; rq[w] = s2; }
  __syncthreads();
  float S  = rs[0]+rs[1]+rs[2]+rs[3];
  float S2 = rq[0]+rq[1]+rq[2]+rq[3];
  float mean = S * (1.0f/Cc);
  float var  = S2 * (1.0f/Cc) - mean*mean;
  float inv = rsqrtf(var + 1e-5f);
  out[(size_t)row*Cc + tid]       = g[tid]     * (v0-mean)*inv + bta[tid];
  out[(size_t)row*Cc + tid + 256] = g[tid+256] * (v1-mean)*inv + bta[tid+256];
}

// ---------------- time-shift mix: xq,xk,xv,xg ----------------
__global__ __launch_bounds__(256) void mix_kernel(const float* __restrict__ h,
    const float* __restrict__ tmq, const float* __restrict__ tmk,
    const float* __restrict__ tmv, const float* __restrict__ tmg,
    float* __restrict__ xq, float* __restrict__ xk,
    float* __restrict__ xv, float* __restrict__ xg)
{
  int i = blockIdx.x * 256 + threadIdx.x;     // [0, B*T*C/4)
  size_t f = (size_t)i * 4;
  int bt = i / (Cc/4);
  int t  = bt % Tt;
  int c  = (i % (Cc/4)) * 4;
  float4 hv = *(const float4*)(h + f);
  float4 xxv = make_float4(0.f,0.f,0.f,0.f);
  if (t > 0) xxv = *(const float4*)(h + f - Cc);
  float4 tq = *(const float4*)(tmq + c);
  float4 tk = *(const float4*)(tmk + c);
  float4 tv = *(const float4*)(tmv + c);
  float4 tg = *(const float4*)(tmg + c);
  float4 o;
  o.x = hv.x*tq.x + xxv.x*(1.f-tq.x); o.y = hv.y*tq.y + xxv.y*(1.f-tq.y);
  o.z = hv.z*tq.z + xxv.z*(1.f-tq.z); o.w = hv.w*tq.w + xxv.w*(1.f-tq.w);
  *(float4*)(xq + f) = o;
  o.x = hv.x*tk.x + xxv.x*(1.f-tk.x); o.y = hv.y*tk.y + xxv.y*(1.f-tk.y);
  o.z = hv.z*tk.z + xxv.z*(1.f-tk.z); o.w = hv.w*tk.w + xxv.w*(1.f-tk.w);
  *(float4*)(xk + f) = o;
  o.x = hv.x*tv.x + xxv.x*(1.f-tv.x); o.y = hv.y*tv.y + xxv.y*(1.f-tv.y);
  o.z = hv.z*tv.z + xxv.z*(1.f-tv.z); o.w = hv.w*tv.w + xxv.w*(1.f-tv.w);
  *(float4*)(xv + f) = o;
  o.x = hv.x*tg.x + xxv.x*(1.f-tg.x); o.y = hv.y*tg.y + xxv.y*(1.f-tg.y);
  o.z = hv.z*tg.z + xxv.z*(1.f-tg.z); o.w = hv.w*tg.w + xxv.w*(1.f-tg.w);
  *(float4*)(xg + f) = o;
}

// ---------------- fp32 GEMM: out[M,N] = act(A[M,K] @ W[N,K]^T + res) ----------------
#define GBM 64
#define GBN 64
#define GBK 16
__global__ __launch_bounds__(256) void gemm_tn(const float* __restrict__ A,
    const float* __restrict__ W, const float* __restrict__ res,
    float* __restrict__ out, int M, int N, int K, int act)
{
  __shared__ float As[GBK][GBM];
  __shared__ float Ws[GBK][GBN];
  int tid = threadIdx.x;
  int m0 = blockIdx.y * GBM, n0 = blockIdx.x * GBN;
  int tx = tid & 15, ty = tid >> 4;
  int lr = tid >> 2;          // 0..63 row within tile
  int lc = (tid & 3) << 2;    // 0,4,8,12 within BK
  float acc[4][4];
  #pragma unroll
  for (int i=0;i<4;i++)
    #pragma unroll
    for (int j=0;j<4;j++) acc[i][j]=0.f;

  for (int k0 = 0; k0 < K; k0 += GBK) {
    float4 av = *(const float4*)&A[(size_t)(m0 + lr) * K + k0 + lc];
    float4 wv = *(const float4*)&W[(size_t)(n0 + lr) * K + k0 + lc];
    __syncthreads();
    As[lc+0][lr] = av.x; As[lc+1][lr] = av.y; As[lc+2][lr] = av.z; As[lc+3][lr] = av.w;
    Ws[lc+0][lr] = wv.x; Ws[lc+1][lr] = wv.y; Ws[lc+2][lr] = wv.z; Ws[lc+3][lr] = wv.w;
    __syncthreads();
    #pragma unroll
    for (int kk = 0; kk < GBK; ++kk) {
      float4 a4 = *(const float4*)&As[kk][ty*4];
      float4 b4 = *(const float4*)&Ws[kk][tx*4];
      float a[4] = {a4.x,a4.y,a4.z,a4.w};
      float b[4] = {b4.x,b4.y,b4.z,b4.w};
      #pragma unroll
      for (int i=0;i<4;i++)
        #pragma unroll
        for (int j=0;j<4;j++) acc[i][j] += a[i]*b[j];
    }
  }
  #pragma unroll
  for (int i=0;i<4;i++){
    int m = m0 + ty*4 + i;
    #pragma unroll
    for (int j=0;j<4;j++){
      int n = n0 + tx*4 + j;
      float vv = acc[i][j];
      if (res) vv += res[(size_t)m*N + n];
      if (act == 1) vv = 0.5f*vv*(1.f+erff(vv*0.70710678118f)); // exact gelu
      else if (act == 2) vv = 1.f/(1.f+expf(-vv));              // sigmoid
      out[(size_t)m*N + n] = vv;
    }
  }
}

// ---------------- exp(rmsnorm(x)) in place, per row ----------------
__global__ __launch_bounds__(256) void rmsexp_kernel(float* __restrict__ x,
    const float* __restrict__ scale)
{
  int row = blockIdx.x, tid = threadIdx.x;
  float* xr = x + (size_t)row * Cc;
  float v0 = xr[tid], v1 = xr[tid+256];
  float s2 = v0*v0 + v1*v1;
  #pragma unroll
  for (int off = 32; off > 0; off >>= 1) s2 += __shfl_down(s2, off, 64);
  __shared__ float rq[4];
  int w = tid >> 6;
  if ((tid & 63) == 0) rq[w] = s2;
  __syncthreads();
  float S2 = rq[0]+rq[1]+rq[2]+rq[3];
  float norm = sqrtf(S2) * 0.044194173824159216f;  // 1/sqrt(512)
  float r = 1.f / (norm + 1e-8f);
  xr[tid]     = expf(scale[tid]     * v0 * r);
  xr[tid+256] = expf(scale[tid+256] * v1 * r);
}

// ---------------- Phase A: chunk-local end state (incl. z as col 128) ----------------
// Aug[c][bh][j][i] = sum_s lam_i^(CL-1-s) * k[s,i] * vaug[s,j],  vaug[:,128]=1
__global__ __launch_bounds__(256) void chunk_state_kernel(const float* __restrict__ k,
    const float* __restrict__ v, const float* __restrict__ td, float* __restrict__ Aug)
{
  __shared__ float k_lds[CL][Dd];
  __shared__ float v_lds[CL][Dd];
  int blk = blockIdx.x; int c = blk & (NC-1); int bh = blk >> 5;
  int b = bh >> 2, h = bh & 3;
  int tid = threadIdx.x;
  size_t base = ((size_t)b*Tt + (size_t)c*CL)*Cc + h*Dd;
  #pragma unroll
  for (int r = 0; r < 4; ++r) {
    int idx4 = r*256 + tid;          // 0..1023
    int s = idx4 >> 5; int i4 = (idx4 & 31) << 2;
    *(float4*)&k_lds[s][i4] = *(const float4*)&k[base + (size_t)s*Cc + i4];
    *(float4*)&v_lds[s][i4] = *(const float4*)&v[base + (size_t)s*Cc + i4];
  }
  __syncthreads();
  int iq = tid >> 3; int i0 = iq << 2;     // 4 rows i0..i0+3
  int jg = tid & 7;  int j0 = jg << 4;     // 16 cols j0..j0+15
  float lam4[4], powv[4], zacc[4];
  #pragma unroll
  for (int ci=0; ci<4; ++ci) {
    lam4[ci] = expf(-expf(td[h*Dd + i0 + ci]));
    powv[ci] = 1.f; zacc[ci] = 0.f;
  }
  float acc[4][16];
  #pragma unroll
  for (int ci=0; ci<4; ++ci)
    #pragma unroll
    for (int jj=0; jj<16; ++jj) acc[ci][jj] = 0.f;

  for (int s = CL-1; s >= 0; --s) {
    float4 k4 = *(const float4*)&k_lds[s][i0];
    float kw0 = powv[0]*k4.x, kw1 = powv[1]*k4.y, kw2 = powv[2]*k4.z, kw3 = powv[3]*k4.w;
    zacc[0]+=kw0; zacc[1]+=kw1; zacc[2]+=kw2; zacc[3]+=kw3;
    #pragma unroll
    for (int q4 = 0; q4 < 4; ++q4) {
      float4 v4 = *(const float4*)&v_lds[s][j0 + q4*4];
      float vv[4] = {v4.x, v4.y, v4.z, v4.w};
      #pragma unroll
      for (int u=0; u<4; ++u) {
        acc[0][q4*4+u] += kw0*vv[u];
        acc[1][q4*4+u] += kw1*vv[u];
        acc[2][q4*4+u] += kw2*vv[u];
        acc[3][q4*4+u] += kw3*vv[u];
      }
    }
    powv[0]*=lam4[0]; powv[1]*=lam4[1]; powv[2]*=lam4[2]; powv[3]*=lam4[3];
  }
  float* aug = Aug + ((size_t)c*16 + bh)*AUGSZ;
  #pragma unroll
  for (int jj=0; jj<16; ++jj) {
    int j = j0 + jj;
    float4 wv = make_float4(acc[0][jj], acc[1][jj], acc[2][jj], acc[3][jj]);
    *(float4*)&aug[(size_t)j*Dd + i0] = wv;
  }
  if (jg == 0)
    *(float4*)&aug[(size_t)Dd*Dd + i0] = make_float4(zacc[0],zacc[1],zacc[2],zacc[3]);
}

// ---------------- Phase B: inter-chunk prefix scan (in place, Aug[c] -> A_init[c]) ----
__global__ __launch_bounds__(256) void combine_kernel(float* __restrict__ Aug,
    const float* __restrict__ td)
{
  int idx = blockIdx.x*256 + threadIdx.x;
  if (idx >= AUGSZ) return;
  int bh = blockIdx.y; int h = bh & 3;
  int i = idx & (Dd-1);
  float lamL = expf(-expf(td[h*Dd + i]) * (float)CL);
  float* p = Aug + (size_t)bh*AUGSZ + idx;
  float prev = 0.f;
  for (int c = 0; c < NC; ++c) {
    float val = p[(size_t)c*AUGSTRIDE];
    p[(size_t)c*AUGSTRIDE] = prev;
    prev = lamL*prev + val;
  }
}

// ---------------- Phase C: per-chunk scan from A_init; outputs S and Z -------------
// block = (bh, chunk); 4 waves; wave w owns i in [w*32,w*32+32); lane l owns j0=l, j1=l+64
__global__ __launch_bounds__(256, 2) void scan_out_kernel(const float* __restrict__ q,
    const float* __restrict__ k, const float* __restrict__ v,
    const float* __restrict__ td, const float* __restrict__ Aug,
    float* __restrict__ S, float* __restrict__ Z)
{
  __shared__ float part[4*16*128];   // 32KB: [w][t_half(16)][j(128)]
  __shared__ float zpart[4*16];
  int blk = blockIdx.x; int c = blk & (NC-1); int bh = blk >> 5;
  int b = bh >> 2, h = bh & 3;
  int tid = threadIdx.x; int w = tid >> 6, l = tid & 63;
  const size_t base = ((size_t)b*Tt)*Cc + h*Dd;
  const float* augc = Aug + ((size_t)c*16 + bh)*AUGSZ;
  int iq = w*32 + (l & 31);
  float lamv = expf(-expf(td[h*Dd + iq]));
  float lam_s[32];
  #pragma unroll
  for (int ii = 0; ii < 32; ++ii) lam_s[ii] = readlane_f(lamv, ii);

  float A0[32], A1[32];
  {
    const float4* p0 = (const float4*)(augc + (size_t)l*Dd + w*32);
    const float4* p1 = (const float4*)(augc + (size_t)(l+64)*Dd + w*32);
    #pragma unroll
    for (int r = 0; r < 8; ++r) {
      float4 a = p0[r];
      A0[4*r+0]=a.x; A0[4*r+1]=a.y; A0[4*r+2]=a.z; A0[4*r+3]=a.w;
      float4 bb = p1[r];
      A1[4*r+0]=bb.x; A1[4*r+1]=bb.y; A1[4*r+2]=bb.z; A1[4*r+3]=bb.w;
    }
  }
  float z = 0.f;
  if (l < 32) z = augc[(size_t)Dd*Dd + w*32 + l];

  int t0 = c*CL;
  const float* qk_ptr = (l < 32) ? q : k;
  size_t pbase = base + (size_t)t0*Cc;
  float qk = qk_ptr[pbase + iq];
  float v0 = v[pbase + l];
  float v1 = v[pbase + l + 64];

  #pragma unroll
  for (int half = 0; half < 2; ++half) {
    for (int tl = 0; tl < 16; ++tl) {
      int t = half*16 + tl;
      float qk_c = qk, v0c = v0, v1c = v1;
      if (t + 1 < CL) {
        size_t nb = pbase + (size_t)(t+1)*Cc;
        qk = qk_ptr[nb + iq];
        v0 = v[nb + l];
        v1 = v[nb + l + 64];
      }
      float s0 = 0.f, s1 = 0.f;
      #pragma unroll
      for (int ii = 0; ii < 32; ++ii) {
        float qs = readlane_f(qk_c, ii);
        float ks = readlane_f(qk_c, 32 + ii);
        A0[ii] = lam_s[ii]*A0[ii] + ks*v0c;
        A1[ii] = lam_s[ii]*A1[ii] + ks*v1c;
        s0 += qs * A0[ii];
        s1 += qs * A1[ii];
      }
      part[(w*16 + tl)*128 + l]      = s0;
      part[(w*16 + tl)*128 + l + 64] = s1;
      // z: lanes<32 hold z_i (i = w*32+l); k_i lives on lane l+32
      float kme = __shfl(qk_c, (l & 31) + 32);
      float p = 0.f;
      if (l < 32) { z = lamv*z + kme; p = qk_c * z; }
      #pragma unroll
      for (int off = 16; off > 0; off >>= 1) p += __shfl_down(p, off);
      if (l == 0) zpart[w*16 + tl] = p;
    }
    __syncthreads();
    #pragma unroll
    for (int r = 0; r < 8; ++r) {
      int lin = r*256 + tid; int tt = lin >> 7; int j = lin & 127;
      float sv = part[tt*128 + j] + part[(16+tt)*128 + j]
               + part[(32+tt)*128 + j] + part[(48+tt)*128 + j];
      S[base + (size_t)(t0 + half*16 + tt)*Cc + j] = sv;
    }
    if (tid < 16) {
      float zv = zpart[tid] + zpart[16+tid] + zpart[32+tid] + zpart[48+tid];
      Z[((size_t)b*Tt + t0 + half*16 + tid)*Hh + h] = zv;
    }
    __syncthreads();
  }
}

// ---------------- gatt = g * S / Z ----------------
__global__ __launch_bounds__(256) void gatt_kernel(const float* __restrict__ g,
    const float* __restrict__ S, const float* __restrict__ Z, float* __restrict__ out)
{
  int i = blockIdx.x * 256 + threadIdx.x;    // [0, B*T*C/4)
  size_t f = (size_t)i * 4;
  int bt = i / (Cc/4);
  int c  = (i % (Cc/4)) * 4;
  int h  = c >> 7;
  float zi = 1.f / Z[(size_t)bt*Hh + h];
  float4 gv = *(const float4*)(g + f);
  float4 sv = *(const float4*)(S + f);
  float4 o;
  o.x = gv.x*sv.x*zi; o.y = gv.y*sv.y*zi; o.z = gv.z*sv.z*zi; o.w = gv.w*sv.w*zi;
  *(float4*)(out + f) = o;
}

extern "C" void kernel_launch(void* const* d_in, const int* in_sizes, int n_in,
                              void* d_out, int out_size, void* d_ws, size_t ws_size,
                              hipStream_t stream) {
  const float* x    = (const float*)d_in[0];
  const float* ln1g = (const float*)d_in[1];
  const float* ln1b = (const float*)d_in[2];
  const float* ln2g = (const float*)d_in[3];
  const float* ln2b = (const float*)d_in[4];
  const float* td   = (const float*)d_in[5];
  const float* tmq  = (const float*)d_in[6];
  const float* tmk  = (const float*)d_in[7];
  const float* tmv  = (const float*)d_in[8];
  const float* tmg  = (const float*)d_in[9];
  const float* Wq   = (const float*)d_in[10];
  const float* Wk   = (const float*)d_in[11];
  const float* Wv   = (const float*)d_in[12];
  const float* Wg   = (const float*)d_in[13];
  const float* Wo   = (const float*)d_in[14];
  const float* rsc  = (const float*)d_in[15];
  const float* W1   = (const float*)d_in[16];
  const float* W2   = (const float*)d_in[17];
  float* ws = (float*)d_ws;
  const size_t E = (size_t)Bb*Tt*Cc;           // 2,097,152
  float* s0 = ws;          // h -> q -> x1
  float* s1 = ws + E;      // xq -> k -> mid(4E: s1..s4)
  float* s2 = ws + 2*E;    // xk -> v
  float* s3 = ws + 3*E;    // xv -> g
  float* s4 = ws + 4*E;    // xg -> S -> gatt
  float* Aug = ws + 5*E;   // NC*16*AUGSZ = 8,454,144 floats (33.8 MB) -> later h2
  float* Zbuf = ws + 5*E + (size_t)NC*16*AUGSZ;  // B*T*H floats
  float* mid = s1;         // 4E, used only after scan
  float* x1  = s0;
  float* h2  = Aug;

  dim3 g512(8, 64), g2048(32, 64);
  int ew = (int)(E/4/256);  // 2048 blocks for float4-elementwise

  ln_kernel<<<Mrows,256,0,stream>>>(x, ln1g, ln1b, s0);
  mix_kernel<<<ew,256,0,stream>>>(s0, tmq,tmk,tmv,tmg, s1,s2,s3,s4);
  gemm_tn<<<g512,256,0,stream>>>(s1, Wq, nullptr, s0, Mrows,512,512, 0);  // q
  gemm_tn<<<g512,256,0,stream>>>(s2, Wk, nullptr, s1, Mrows,512,512, 0);  // k
  gemm_tn<<<g512,256,0,stream>>>(s3, Wv, nullptr, s2, Mrows,512,512, 0);  // v
  gemm_tn<<<g512,256,0,stream>>>(s4, Wg, nullptr, s3, Mrows,512,512, 2);  // g=sigmoid
  rmsexp_kernel<<<Mrows,256,0,stream>>>(s0, rsc);                          // q
  rmsexp_kernel<<<Mrows,256,0,stream>>>(s1, rsc);                          // k
  chunk_state_kernel<<<16*NC,256,0,stream>>>(s1, s2, td, Aug);             // A_loc
  combine_kernel<<<dim3((AUGSZ+255)/256,16),256,0,stream>>>(Aug, td);      // -> A_init
  scan_out_kernel<<<16*NC,256,0,stream>>>(s0, s1, s2, td, Aug, s4, Zbuf);  // S, Z
  gatt_kernel<<<ew,256,0,stream>>>(s3, s4, Zbuf, s4);                      // g*S/Z
  gemm_tn<<<g512,256,0,stream>>>(s4, Wo, x, x1, Mrows,512,512, 0);         // x1 = x + att
  ln_kernel<<<Mrows,256,0,stream>>>(x1, ln2g, ln2b, h2);                   // h2
  gemm_tn<<<g2048,256,0,stream>>>(h2, W1, nullptr, mid, Mrows,2048,512, 1); // gelu
  gemm_tn<<<g512,256,0,stream>>>(mid, W2, x1, (float*)d_out, Mrows,512,2048, 0);
}

// Round 3
// 334.428 us; speedup vs baseline: 4.6884x; 1.6984x over previous
//
#include <hip/hip_runtime.h>
#include <math.h>

#define Bb 4
#define Tt 1024
#define Cc 512
#define Hh 4
#define Dd 128
#define Mrows (Bb*Tt)   // 4096
#define NC 32           // chunks
#define CL 32           // chunk length (NC*CL == Tt)
#define AUGSZ (Dd*(Dd+1))        // 16512 floats per (chunk, bh)
#define AUGSTRIDE (16*AUGSZ)

typedef unsigned short u16;
typedef __attribute__((ext_vector_type(8))) short bf16x8;
typedef __attribute__((ext_vector_type(4))) float f32x4;

__device__ __forceinline__ float readlane_f(float v, int lane) {
  return __uint_as_float(__builtin_amdgcn_readlane(__float_as_uint(v), lane));
}
__device__ __forceinline__ u16 f2bf(float f) {
  unsigned u = __float_as_uint(f);
  unsigned r = (u + 0x7fffu + ((u >> 16) & 1u)) >> 16;
  return (u16)r;
}
__device__ __forceinline__ unsigned pack2(float a, float b) {
  return (unsigned)f2bf(a) | ((unsigned)f2bf(b) << 16);
}

// ---------------- LayerNorm (one block per row) ----------------
__global__ __launch_bounds__(256) void ln_kernel(const float* __restrict__ x,
    const float* __restrict__ g, const float* __restrict__ bta, float* __restrict__ out)
{
  int row = blockIdx.x, tid = threadIdx.x;
  const float* xr = x + (size_t)row * Cc;
  float v0 = xr[tid], v1 = xr[tid + 256];
  float s = v0 + v1, s2 = v0*v0 + v1*v1;
  #pragma unroll
  for (int off = 32; off > 0; off >>= 1) {
    s  += __shfl_down(s,  off, 64);
    s2 += __shfl_down(s2, off, 64);
  }
  __shared__ float rs[4], rq[4];
  int w = tid >> 6;
  if ((tid & 63) == 0) { rs[w] = s; rq[w] = s2; }
  __syncthreads();
  float S  = rs[0]+rs[1]+rs[2]+rs[3];
  float S2 = rq[0]+rq[1]+rq[2]+rq[3];
  float mean = S * (1.0f/Cc);
  float var  = S2 * (1.0f/Cc) - mean*mean;
  float inv = rsqrtf(var + 1e-5f);
  out[(size_t)row*Cc + tid]       = g[tid]     * (v0-mean)*inv + bta[tid];
  out[(size_t)row*Cc + tid + 256] = g[tid+256] * (v1-mean)*inv + bta[tid+256];
}

// ---------------- time-shift mix -> blocked bf16 [C/8][M][8] ----------------
__device__ __forceinline__ void mix_one(const float* tm, int c0,
    float4 ha, float4 hb, float4 xa, float4 xb, u16* dst, size_t i8)
{
  float4 ta = *(const float4*)(tm + c0);
  float4 tb = *(const float4*)(tm + c0 + 4);
  uint4 o;
  o.x = pack2(ha.x*ta.x + xa.x*(1.f-ta.x), ha.y*ta.y + xa.y*(1.f-ta.y));
  o.y = pack2(ha.z*ta.z + xa.z*(1.f-ta.z), ha.w*ta.w + xa.w*(1.f-ta.w));
  o.z = pack2(hb.x*tb.x + xb.x*(1.f-tb.x), hb.y*tb.y + xb.y*(1.f-tb.y));
  o.w = pack2(hb.z*tb.z + xb.z*(1.f-tb.z), hb.w*tb.w + xb.w*(1.f-tb.w));
  *(uint4*)(dst + i8) = o;
}

__global__ __launch_bounds__(256) void mix_kernel(const float* __restrict__ h,
    const float* __restrict__ tmq, const float* __restrict__ tmk,
    const float* __restrict__ tmv, const float* __restrict__ tmg,
    u16* __restrict__ xqb, u16* __restrict__ xkb,
    u16* __restrict__ xvb, u16* __restrict__ xgb)
{
  int i = blockIdx.x * 256 + threadIdx.x;     // kg*4096 + m
  int m = i & 4095, c0 = (i >> 12) << 3;
  const float* hp = h + (size_t)m*Cc + c0;
  float4 ha = *(const float4*)hp, hb = *(const float4*)(hp + 4);
  float4 xa = make_float4(0,0,0,0), xb = make_float4(0,0,0,0);
  if (m & 1023) { xa = *(const float4*)(hp - Cc); xb = *(const float4*)(hp - Cc + 4); }
  size_t i8 = (size_t)i * 8;
  mix_one(tmq, c0, ha, hb, xa, xb, xqb, i8);
  mix_one(tmk, c0, ha, hb, xa, xb, xkb, i8);
  mix_one(tmv, c0, ha, hb, xa, xb, xvb, i8);
  mix_one(tmg, c0, ha, hb, xa, xb, xgb, i8);
}

// ---------------- weight / activation fp32 -> blocked bf16 ----------------
__global__ __launch_bounds__(256) void wconv_kernel(const float* __restrict__ src,
    u16* __restrict__ out, int K, int nshift)
{
  int i = blockIdx.x * 256 + threadIdx.x;       // kg*N + n
  int n = i & ((1 << nshift) - 1), kg = i >> nshift;
  const float* p = src + (size_t)n * K + kg * 8;
  float4 a = *(const float4*)p, b = *(const float4*)(p + 4);
  uint4 o;
  o.x = pack2(a.x, a.y); o.y = pack2(a.z, a.w);
  o.z = pack2(b.x, b.y); o.w = pack2(b.z, b.w);
  *(uint4*)(out + (size_t)i * 8) = o;
}

// ---------------- bf16 MFMA GEMM: out = act(A @ W^T + res) ----------------
// A blocked [K/8][M][8], W blocked [K/8][N][8]. Tile 128x128, BK=32, 4 waves.
__global__ __launch_bounds__(256) void gemm_bf(const u16* __restrict__ A,
    const u16* __restrict__ W, const float* __restrict__ res,
    float* __restrict__ outf, u16* __restrict__ outb,
    int Mr, int Nr, int Kr, int act)
{
  __shared__ __align__(16) u16 Asm[4096];   // [kg(4)][row(128)][8]
  __shared__ __align__(16) u16 Bsm[4096];
  const int tid = threadIdx.x, w = tid >> 6, l = tid & 63;
  const int m0 = blockIdx.y * 128, n0 = blockIdx.x * 128;
  const int wr = w >> 1, wc = w & 1;
  f32x4 acc[4][4];
  #pragma unroll
  for (int i = 0; i < 4; ++i)
    #pragma unroll
    for (int j = 0; j < 4; ++j) acc[i][j] = (f32x4){0.f,0.f,0.f,0.f};

  const int kgl = l >> 4, rl = l & 15;

  for (int k0 = 0; k0 < Kr; k0 += 32) {
    __syncthreads();
    #pragma unroll
    for (int ii = 0; ii < 4; ++ii) {
      int q = w * 4 + ii;
      int isB = q >> 3, idx = q & 7, kg = idx >> 1, hf = idx & 1;
      const u16* src = isB
        ? W + ((size_t)((k0 >> 3) + kg) * Nr + n0 + hf*64 + l) * 8
        : A + ((size_t)((k0 >> 3) + kg) * Mr + m0 + hf*64 + l) * 8;
      u16* dst = (isB ? Bsm : Asm) + (kg * 128 + hf * 64) * 8;
      __builtin_amdgcn_global_load_lds(
          (const __attribute__((address_space(1))) void*)src,
          (__attribute__((address_space(3))) void*)dst, 16, 0, 0);
    }
    asm volatile("s_waitcnt vmcnt(0)" ::: "memory");
    __syncthreads();
    bf16x8 af[4], bfr[4];
    #pragma unroll
    for (int f = 0; f < 4; ++f)
      af[f] = *(const bf16x8*)&Asm[(kgl*128 + wr*64 + f*16 + rl) * 8];
    #pragma unroll
    for (int f = 0; f < 4; ++f)
      bfr[f] = *(const bf16x8*)&Bsm[(kgl*128 + wc*64 + f*16 + rl) * 8];
    #pragma unroll
    for (int i = 0; i < 4; ++i)
      #pragma unroll
      for (int j = 0; j < 4; ++j)
        acc[i][j] = __builtin_amdgcn_mfma_f32_16x16x32_bf16(af[i], bfr[j], acc[i][j], 0, 0, 0);
  }

  const int rbase = (l >> 4) * 4, cn = l & 15;
  #pragma unroll
  for (int i = 0; i < 4; ++i) {
    #pragma unroll
    for (int j = 0; j < 4; ++j) {
      #pragma unroll
      for (int r = 0; r < 4; ++r) {
        int m = m0 + wr*64 + i*16 + rbase + r;
        int n = n0 + wc*64 + j*16 + cn;
        float vv = acc[i][j][r];
        if (res) vv += res[(size_t)m * Nr + n];
        if (act == 1) vv = 0.5f*vv*(1.f + erff(vv * 0.70710678118f));
        else if (act == 2) vv = 1.f/(1.f + expf(-vv));
        if (outb) outb[((size_t)(n >> 3) * Mr + m) * 8 + (n & 7)] = f2bf(vv);
        else outf[(size_t)m * Nr + n] = vv;
      }
    }
  }
}

// ---------------- exp(rmsnorm(x)) in place, per row ----------------
__global__ __launch_bounds__(256) void rmsexp_kernel(float* __restrict__ x,
    const float* __restrict__ scale)
{
  int row = blockIdx.x, tid = threadIdx.x;
  float* xr = x + (size_t)row * Cc;
  float v0 = xr[tid], v1 = xr[tid+256];
  float s2 = v0*v0 + v1*v1;
  #pragma unroll
  for (int off = 32; off > 0; off >>= 1) s2 += __shfl_down(s2, off, 64);
  __shared__ float rq[4];
  int w = tid >> 6;
  if ((tid & 63) == 0) rq[w] = s2;
  __syncthreads();
  float S2 = rq[0]+rq[1]+rq[2]+rq[3];
  float norm = sqrtf(S2) * 0.044194173824159216f;  // 1/sqrt(512)
  float r = 1.f / (norm + 1e-8f);
  xr[tid]     = expf(scale[tid]     * v0 * r);
  xr[tid+256] = expf(scale[tid+256] * v1 * r);
}

// ---------------- Phase A: chunk-local end state (incl. z as col 128) ----------------
__global__ __launch_bounds__(256) void chunk_state_kernel(const float* __restrict__ k,
    const float* __restrict__ v, const float* __restrict__ td, float* __restrict__ Aug)
{
  __shared__ float k_lds[CL][Dd];
  __shared__ float v_lds[CL][Dd];
  int blk = blockIdx.x; int c = blk & (NC-1); int bh = blk >> 5;
  int b = bh >> 2, h = bh & 3;
  int tid = threadIdx.x;
  size_t base = ((size_t)b*Tt + (size_t)c*CL)*Cc + h*Dd;
  #pragma unroll
  for (int r = 0; r < 4; ++r) {
    int idx4 = r*256 + tid;
    int s = idx4 >> 5; int i4 = (idx4 & 31) << 2;
    *(float4*)&k_lds[s][i4] = *(const float4*)&k[base + (size_t)s*Cc + i4];
    *(float4*)&v_lds[s][i4] = *(const float4*)&v[base + (size_t)s*Cc + i4];
  }
  __syncthreads();
  int iq = tid >> 3; int i0 = iq << 2;
  int jg = tid & 7;  int j0 = jg << 4;
  float lam4[4], powv[4], zacc[4];
  #pragma unroll
  for (int ci=0; ci<4; ++ci) {
    lam4[ci] = expf(-expf(td[h*Dd + i0 + ci]));
    powv[ci] = 1.f; zacc[ci] = 0.f;
  }
  float acc[4][16];
  #pragma unroll
  for (int ci=0; ci<4; ++ci)
    #pragma unroll
    for (int jj=0; jj<16; ++jj) acc[ci][jj] = 0.f;

  for (int s = CL-1; s >= 0; --s) {
    float4 k4 = *(const float4*)&k_lds[s][i0];
    float kw0 = powv[0]*k4.x, kw1 = powv[1]*k4.y, kw2 = powv[2]*k4.z, kw3 = powv[3]*k4.w;
    zacc[0]+=kw0; zacc[1]+=kw1; zacc[2]+=kw2; zacc[3]+=kw3;
    #pragma unroll
    for (int q4 = 0; q4 < 4; ++q4) {
      float4 v4 = *(const float4*)&v_lds[s][j0 + q4*4];
      float vv[4] = {v4.x, v4.y, v4.z, v4.w};
      #pragma unroll
      for (int u=0; u<4; ++u) {
        acc[0][q4*4+u] += kw0*vv[u];
        acc[1][q4*4+u] += kw1*vv[u];
        acc[2][q4*4+u] += kw2*vv[u];
        acc[3][q4*4+u] += kw3*vv[u];
      }
    }
    powv[0]*=lam4[0]; powv[1]*=lam4[1]; powv[2]*=lam4[2]; powv[3]*=lam4[3];
  }
  float* aug = Aug + ((size_t)c*16 + bh)*AUGSZ;
  #pragma unroll
  for (int jj=0; jj<16; ++jj) {
    int j = j0 + jj;
    float4 wv = make_float4(acc[0][jj], acc[1][jj], acc[2][jj], acc[3][jj]);
    *(float4*)&aug[(size_t)j*Dd + i0] = wv;
  }
  if (jg == 0)
    *(float4*)&aug[(size_t)Dd*Dd + i0] = make_float4(zacc[0],zacc[1],zacc[2],zacc[3]);
}

// ---------------- Phase B: inter-chunk prefix scan ----------------
__global__ __launch_bounds__(256) void combine_kernel(float* __restrict__ Aug,
    const float* __restrict__ td)
{
  int idx = blockIdx.x*256 + threadIdx.x;
  if (idx >= AUGSZ) return;
  int bh = blockIdx.y; int h = bh & 3;
  int i = idx & (Dd-1);
  float lamL = expf(-expf(td[h*Dd + i]) * (float)CL);
  float* p = Aug + (size_t)bh*AUGSZ + idx;
  float prev = 0.f;
  for (int c = 0; c < NC; ++c) {
    float val = p[(size_t)c*AUGSTRIDE];
    p[(size_t)c*AUGSTRIDE] = prev;
    prev = lamL*prev + val;
  }
}

// ---------------- Phase C: per-chunk scan from A_init; outputs S and Z -----------
__global__ __launch_bounds__(256, 2) void scan_out_kernel(const float* __restrict__ q,
    const float* __restrict__ k, const float* __restrict__ v,
    const float* __restrict__ td, const float* __restrict__ Aug,
    float* __restrict__ S, float* __restrict__ Z)
{
  __shared__ float part[4*16*128];
  __shared__ float zpart[4*16];
  int blk = blockIdx.x; int c = blk & (NC-1); int bh = blk >> 5;
  int b = bh >> 2, h = bh & 3;
  int tid = threadIdx.x; int w = tid >> 6, l = tid & 63;
  const size_t base = ((size_t)b*Tt)*Cc + h*Dd;
  const float* augc = Aug + ((size_t)c*16 + bh)*AUGSZ;
  int iq = w*32 + (l & 31);
  float lamv = expf(-expf(td[h*Dd + iq]));
  float lam_s[32];
  #pragma unroll
  for (int ii = 0; ii < 32; ++ii) lam_s[ii] = readlane_f(lamv, ii);

  float A0[32], A1[32];
  {
    const float4* p0 = (const float4*)(augc + (size_t)l*Dd + w*32);
    const float4* p1 = (const float4*)(augc + (size_t)(l+64)*Dd + w*32);
    #pragma unroll
    for (int r = 0; r < 8; ++r) {
      float4 a = p0[r];
      A0[4*r+0]=a.x; A0[4*r+1]=a.y; A0[4*r+2]=a.z; A0[4*r+3]=a.w;
      float4 bb = p1[r];
      A1[4*r+0]=bb.x; A1[4*r+1]=bb.y; A1[4*r+2]=bb.z; A1[4*r+3]=bb.w;
    }
  }
  float z = 0.f;
  if (l < 32) z = augc[(size_t)Dd*Dd + w*32 + l];

  int t0 = c*CL;
  const float* qk_ptr = (l < 32) ? q : k;
  size_t pbase = base + (size_t)t0*Cc;
  float qk = qk_ptr[pbase + iq];
  float v0 = v[pbase + l];
  float v1 = v[pbase + l + 64];

  #pragma unroll
  for (int half = 0; half < 2; ++half) {
    for (int tl = 0; tl < 16; ++tl) {
      int t = half*16 + tl;
      float qk_c = qk, v0c = v0, v1c = v1;
      if (t + 1 < CL) {
        size_t nb = pbase + (size_t)(t+1)*Cc;
        qk = qk_ptr[nb + iq];
        v0 = v[nb + l];
        v1 = v[nb + l + 64];
      }
      float s0 = 0.f, s1 = 0.f;
      #pragma unroll
      for (int ii = 0; ii < 32; ++ii) {
        float qs = readlane_f(qk_c, ii);
        float ks = readlane_f(qk_c, 32 + ii);
        A0[ii] = lam_s[ii]*A0[ii] + ks*v0c;
        A1[ii] = lam_s[ii]*A1[ii] + ks*v1c;
        s0 += qs * A0[ii];
        s1 += qs * A1[ii];
      }
      part[(w*16 + tl)*128 + l]      = s0;
      part[(w*16 + tl)*128 + l + 64] = s1;
      float kme = __shfl(qk_c, (l & 31) + 32);
      float p = 0.f;
      if (l < 32) { z = lamv*z + kme; p = qk_c * z; }
      #pragma unroll
      for (int off = 16; off > 0; off >>= 1) p += __shfl_down(p, off);
      if (l == 0) zpart[w*16 + tl] = p;
    }
    __syncthreads();
    #pragma unroll
    for (int r = 0; r < 8; ++r) {
      int lin = r*256 + tid; int tt = lin >> 7; int j = lin & 127;
      float sv = part[tt*128 + j] + part[(16+tt)*128 + j]
               + part[(32+tt)*128 + j] + part[(48+tt)*128 + j];
      S[base + (size_t)(t0 + half*16 + tt)*Cc + j] = sv;
    }
    if (tid < 16) {
      float zv = zpart[tid] + zpart[16+tid] + zpart[32+tid] + zpart[48+tid];
      Z[((size_t)b*Tt + t0 + half*16 + tid)*Hh + h] = zv;
    }
    __syncthreads();
  }
}

// ---------------- gatt = g * S / Z -> blocked bf16 ----------------
__global__ __launch_bounds__(256) void gatt_kernel(const float* __restrict__ g,
    const float* __restrict__ S, const float* __restrict__ Z, u16* __restrict__ out)
{
  int i = blockIdx.x * 256 + threadIdx.x;   // kg*4096 + m
  int m = i & 4095, c0 = (i >> 12) << 3;
  float zi = 1.f / Z[(size_t)m*Hh + (c0 >> 7)];
  const float* gp = g + (size_t)m*Cc + c0;
  const float* sp = S + (size_t)m*Cc + c0;
  float4 ga = *(const float4*)gp, gb = *(const float4*)(gp+4);
  float4 sa = *(const float4*)sp, sb = *(const float4*)(sp+4);
  uint4 o;
  o.x = pack2(ga.x*sa.x*zi, ga.y*sa.y*zi);
  o.y = pack2(ga.z*sa.z*zi, ga.w*sa.w*zi);
  o.z = pack2(gb.x*sb.x*zi, gb.y*sb.y*zi);
  o.w = pack2(gb.z*sb.z*zi, gb.w*sb.w*zi);
  *(uint4*)(out + (size_t)i*8) = o;
}

extern "C" void kernel_launch(void* const* d_in, const int* in_sizes, int n_in,
                              void* d_out, int out_size, void* d_ws, size_t ws_size,
                              hipStream_t stream) {
  const float* x    = (const float*)d_in[0];
  const float* ln1g = (const float*)d_in[1];
  const float* ln1b = (const float*)d_in[2];
  const float* ln2g = (const float*)d_in[3];
  const float* ln2b = (const float*)d_in[4];
  const float* td   = (const float*)d_in[5];
  const float* tmq  = (const float*)d_in[6];
  const float* tmk  = (const float*)d_in[7];
  const float* tmv  = (const float*)d_in[8];
  const float* tmg  = (const float*)d_in[9];
  const float* Wq   = (const float*)d_in[10];
  const float* Wk   = (const float*)d_in[11];
  const float* Wv   = (const float*)d_in[12];
  const float* Wg   = (const float*)d_in[13];
  const float* Wo   = (const float*)d_in[14];
  const float* rsc  = (const float*)d_in[15];
  const float* W1   = (const float*)d_in[16];
  const float* W2   = (const float*)d_in[17];
  float* ws = (float*)d_ws;
  const size_t E = (size_t)Mrows*Cc;           // 2,097,152 floats
  float* s0 = ws;          // h -> q -> h2
  float* s1 = ws + E;      // k -> x1
  float* s2 = ws + 2*E;    // v
  float* s3 = ws + 3*E;    // g
  float* s4 = ws + 4*E;    // S
  u16* xqb = (u16*)(ws + 5*E);             // E u16 each
  u16* xkb = xqb + E;
  u16* xvb = xkb + E;
  u16* xgb = xvb + E;
  float* Aug = ws + 7*E;                   // 8,454,144 floats; reused as mid_b
  u16* midb = (u16*)Aug;                   // 4096*2048 u16 = 16.8MB <= 33.8MB
  float* wreg = ws + 7*E + (size_t)NC*16*AUGSZ;
  u16* Wqb = (u16*)wreg;                   // 5 x 262144 u16
  u16* Wkb = Wqb + 262144;
  u16* Wvb = Wkb + 262144;
  u16* Wgb = Wvb + 262144;
  u16* Wob = Wgb + 262144;
  u16* W1b = Wob + 262144;                 // 1,048,576 u16
  u16* W2b = W1b + 1048576;                // 1,048,576 u16
  float* Zbuf = (float*)(W2b + 1048576);   // B*T*H floats
  u16* gattb = xqb;                        // reuse (xq dead after q GEMM)
  u16* h2b   = xkb;                        // reuse (xk dead after k GEMM)
  float* x1  = s1;

  // weights -> blocked bf16
  wconv_kernel<<<128,256,0,stream>>>(Wq, Wqb, 512, 9);
  wconv_kernel<<<128,256,0,stream>>>(Wk, Wkb, 512, 9);
  wconv_kernel<<<128,256,0,stream>>>(Wv, Wvb, 512, 9);
  wconv_kernel<<<128,256,0,stream>>>(Wg, Wgb, 512, 9);
  wconv_kernel<<<128,256,0,stream>>>(Wo, Wob, 512, 9);
  wconv_kernel<<<512,256,0,stream>>>(W1, W1b, 512, 11);
  wconv_kernel<<<512,256,0,stream>>>(W2, W2b, 2048, 9);

  ln_kernel<<<Mrows,256,0,stream>>>(x, ln1g, ln1b, s0);
  mix_kernel<<<1024,256,0,stream>>>(s0, tmq,tmk,tmv,tmg, xqb,xkb,xvb,xgb);
  gemm_bf<<<dim3(4,32),256,0,stream>>>(xqb, Wqb, nullptr, s0, nullptr, Mrows,512,512, 0);
  gemm_bf<<<dim3(4,32),256,0,stream>>>(xkb, Wkb, nullptr, s1, nullptr, Mrows,512,512, 0);
  gemm_bf<<<dim3(4,32),256,0,stream>>>(xvb, Wvb, nullptr, s2, nullptr, Mrows,512,512, 0);
  gemm_bf<<<dim3(4,32),256,0,stream>>>(xgb, Wgb, nullptr, s3, nullptr, Mrows,512,512, 2);
  rmsexp_kernel<<<Mrows,256,0,stream>>>(s0, rsc);                          // q
  rmsexp_kernel<<<Mrows,256,0,stream>>>(s1, rsc);                          // k
  chunk_state_kernel<<<16*NC,256,0,stream>>>(s1, s2, td, Aug);
  combine_kernel<<<dim3((AUGSZ+255)/256,16),256,0,stream>>>(Aug, td);
  scan_out_kernel<<<16*NC,256,0,stream>>>(s0, s1, s2, td, Aug, s4, Zbuf);
  gatt_kernel<<<1024,256,0,stream>>>(s3, s4, Zbuf, gattb);
  gemm_bf<<<dim3(4,32),256,0,stream>>>(gattb, Wob, x, x1, nullptr, Mrows,512,512, 0);
  ln_kernel<<<Mrows,256,0,stream>>>(x1, ln2g, ln2b, s0);                   // h2
  wconv_kernel<<<1024,256,0,stream>>>(s0, h2b, 512, 12);                   // h2 -> blocked bf16
  gemm_bf<<<dim3(16,32),256,0,stream>>>(h2b, W1b, nullptr, nullptr, midb, Mrows,2048,512, 1);
  gemm_bf<<<dim3(4,32),256,0,stream>>>(midb, W2b, x1, (float*)d_out, nullptr, Mrows,512,2048, 0);
}

// Round 4
// 248.705 us; speedup vs baseline: 6.3044x; 1.3447x over previous
//
#include <hip/hip_runtime.h>
#include <math.h>

#define Bb 4
#define Tt 1024
#define Cc 512
#define Hh 4
#define Dd 128
#define Mrows (Bb*Tt)   // 4096
#define NC 32           // chunks
#define CL 32           // chunk length (NC*CL == Tt)
#define AUGSZ (Dd*(Dd+1))        // 16512 floats per (chunk, bh)
#define AUGSTRIDE (16*AUGSZ)

typedef unsigned short u16;
typedef __attribute__((ext_vector_type(8))) short bf16x8;
typedef __attribute__((ext_vector_type(4))) float f32x4;

__device__ __forceinline__ float readlane_f(float v, int lane) {
  return __uint_as_float(__builtin_amdgcn_readlane(__float_as_uint(v), lane));
}
__device__ __forceinline__ u16 f2bf(float f) {
  unsigned u = __float_as_uint(f);
  unsigned r = (u + 0x7fffu + ((u >> 16) & 1u)) >> 16;
  return (u16)r;
}
__device__ __forceinline__ unsigned pack2(float a, float b) {
  return (unsigned)f2bf(a) | ((unsigned)f2bf(b) << 16);
}

// ---------------- LayerNorm (one block per row) ----------------
__global__ __launch_bounds__(256) void ln_kernel(const float* __restrict__ x,
    const float* __restrict__ g, const float* __restrict__ bta, float* __restrict__ out)
{
  int row = blockIdx.x, tid = threadIdx.x;
  const float* xr = x + (size_t)row * Cc;
  float v0 = xr[tid], v1 = xr[tid + 256];
  float s = v0 + v1, s2 = v0*v0 + v1*v1;
  #pragma unroll
  for (int off = 32; off > 0; off >>= 1) {
    s  += __shfl_down(s,  off, 64);
    s2 += __shfl_down(s2, off, 64);
  }
  __shared__ float rs[4], rq[4];
  int w = tid >> 6;
  if ((tid & 63) == 0) { rs[w] = s; rq[w] = s2; }
  __syncthreads();
  float S  = rs[0]+rs[1]+rs[2]+rs[3];
  float S2 = rq[0]+rq[1]+rq[2]+rq[3];
  float mean = S * (1.0f/Cc);
  float var  = S2 * (1.0f/Cc) - mean*mean;
  float inv = rsqrtf(var + 1e-5f);
  out[(size_t)row*Cc + tid]       = g[tid]     * (v0-mean)*inv + bta[tid];
  out[(size_t)row*Cc + tid + 256] = g[tid+256] * (v1-mean)*inv + bta[tid+256];
}

// ---------------- time-shift mix -> blocked bf16 [C/8][M][8] ----------------
__device__ __forceinline__ void mix_one(const float* tm, int c0,
    float4 ha, float4 hb, float4 xa, float4 xb, u16* dst, size_t i8)
{
  float4 ta = *(const float4*)(tm + c0);
  float4 tb = *(const float4*)(tm + c0 + 4);
  uint4 o;
  o.x = pack2(ha.x*ta.x + xa.x*(1.f-ta.x), ha.y*ta.y + xa.y*(1.f-ta.y));
  o.y = pack2(ha.z*ta.z + xa.z*(1.f-ta.z), ha.w*ta.w + xa.w*(1.f-ta.w));
  o.z = pack2(hb.x*tb.x + xb.x*(1.f-tb.x), hb.y*tb.y + xb.y*(1.f-tb.y));
  o.w = pack2(hb.z*tb.z + xb.z*(1.f-tb.z), hb.w*tb.w + xb.w*(1.f-tb.w));
  *(uint4*)(dst + i8) = o;
}

__global__ __launch_bounds__(256) void mix_kernel(const float* __restrict__ h,
    const float* __restrict__ tmq, const float* __restrict__ tmk,
    const float* __restrict__ tmv, const float* __restrict__ tmg,
    u16* __restrict__ xqb, u16* __restrict__ xkb,
    u16* __restrict__ xvb, u16* __restrict__ xgb)
{
  int i = blockIdx.x * 256 + threadIdx.x;     // kg*4096 + m
  int m = i & 4095, c0 = (i >> 12) << 3;
  const float* hp = h + (size_t)m*Cc + c0;
  float4 ha = *(const float4*)hp, hb = *(const float4*)(hp + 4);
  float4 xa = make_float4(0,0,0,0), xb = make_float4(0,0,0,0);
  if (m & 1023) { xa = *(const float4*)(hp - Cc); xb = *(const float4*)(hp - Cc + 4); }
  size_t i8 = (size_t)i * 8;
  mix_one(tmq, c0, ha, hb, xa, xb, xqb, i8);
  mix_one(tmk, c0, ha, hb, xa, xb, xkb, i8);
  mix_one(tmv, c0, ha, hb, xa, xb, xvb, i8);
  mix_one(tmg, c0, ha, hb, xa, xb, xgb, i8);
}

// ---------------- weight / activation fp32 -> blocked bf16 ----------------
__global__ __launch_bounds__(256) void wconv_kernel(const float* __restrict__ src,
    u16* __restrict__ out, int K, int nshift)
{
  int i = blockIdx.x * 256 + threadIdx.x;       // kg*N + n
  int n = i & ((1 << nshift) - 1), kg = i >> nshift;
  const float* p = src + (size_t)n * K + kg * 8;
  float4 a = *(const float4*)p, b = *(const float4*)(p + 4);
  uint4 o;
  o.x = pack2(a.x, a.y); o.y = pack2(a.z, a.w);
  o.z = pack2(b.x, b.y); o.w = pack2(b.z, b.w);
  *(uint4*)(out + (size_t)i * 8) = o;
}

// 5 square 512x512 weights in one dispatch (each 128 blocks)
__global__ __launch_bounds__(256) void wconv5_kernel(const float* __restrict__ s0,
    const float* __restrict__ s1, const float* __restrict__ s2,
    const float* __restrict__ s3, const float* __restrict__ s4,
    u16* __restrict__ out)
{
  int wsel = blockIdx.x >> 7;
  const float* src = wsel == 0 ? s0 : wsel == 1 ? s1 : wsel == 2 ? s2 : wsel == 3 ? s3 : s4;
  int i = (blockIdx.x & 127) * 256 + threadIdx.x;  // kg*512 + n
  int n = i & 511, kg = i >> 9;
  const float* p = src + (size_t)n * 512 + kg * 8;
  float4 a = *(const float4*)p, b = *(const float4*)(p + 4);
  uint4 o;
  o.x = pack2(a.x, a.y); o.y = pack2(a.z, a.w);
  o.z = pack2(b.x, b.y); o.w = pack2(b.z, b.w);
  *(uint4*)(out + (size_t)wsel * 262144 + (size_t)i * 8) = o;
}

// ---------------- bf16 MFMA GEMM core: out = act(A @ W^T + res) ----------------
// A blocked [K/8][M][8], W blocked [K/8][N][8]. Tile 128x128, BK=32, 4 waves,
// double-buffered LDS, 1 barrier + vmcnt(0) per K-step (T3 minimum-2-phase).
__device__ __forceinline__ void gemm_core(const u16* __restrict__ A,
    const u16* __restrict__ W, const float* __restrict__ res,
    float* __restrict__ outf, u16* __restrict__ outb,
    int Mr, int Nr, int Kr, int act, int m0, int n0,
    u16* Asm, u16* Bsm)   // each [2][4096]
{
  const int tid = threadIdx.x, w = tid >> 6, l = tid & 63;
  const int wr = w >> 1, wc = w & 1;
  f32x4 acc[4][4];
  #pragma unroll
  for (int i = 0; i < 4; ++i)
    #pragma unroll
    for (int j = 0; j < 4; ++j) acc[i][j] = (f32x4){0.f,0.f,0.f,0.f};
  const int kgl = l >> 4, rl = l & 15;
  const int q = w * 4;  // wave's load-slot base

  // per-wave: 4 global_load_lds (1 KiB each); slots 0..7 = A-tile, 8..15 = B-tile
  #define STAGE(KT, BUF) do {                                               \
    _Pragma("unroll")                                                       \
    for (int ii = 0; ii < 4; ++ii) {                                        \
      int qq = q + ii;                                                      \
      int isB = qq >> 3, idx = qq & 7, kg = idx >> 1, hf = idx & 1;         \
      const u16* src = isB                                                  \
        ? W + ((size_t)((KT)*4 + kg) * Nr + n0 + hf*64 + l) * 8             \
        : A + ((size_t)((KT)*4 + kg) * Mr + m0 + hf*64 + l) * 8;            \
      u16* dst = (isB ? Bsm : Asm) + (BUF)*4096 + (kg * 128 + hf * 64) * 8; \
      __builtin_amdgcn_global_load_lds(                                     \
          (const __attribute__((address_space(1))) void*)src,               \
          (__attribute__((address_space(3))) void*)dst, 16, 0, 0);          \
    }                                                                       \
  } while (0)

  const int nk = Kr >> 5;
  STAGE(0, 0);
  asm volatile("s_waitcnt vmcnt(0)" ::: "memory");
  __builtin_amdgcn_s_barrier();
  int cur = 0;
  for (int kt = 0; kt < nk; ++kt) {
    if (kt + 1 < nk) STAGE(kt + 1, cur ^ 1);
    bf16x8 af[4], bfr[4];
    #pragma unroll
    for (int f = 0; f < 4; ++f)
      af[f] = *(const bf16x8*)&Asm[cur*4096 + (kgl*128 + wr*64 + f*16 + rl) * 8];
    #pragma unroll
    for (int f = 0; f < 4; ++f)
      bfr[f] = *(const bf16x8*)&Bsm[cur*4096 + (kgl*128 + wc*64 + f*16 + rl) * 8];
    __builtin_amdgcn_s_setprio(1);
    #pragma unroll
    for (int i = 0; i < 4; ++i)
      #pragma unroll
      for (int j = 0; j < 4; ++j)
        acc[i][j] = __builtin_amdgcn_mfma_f32_16x16x32_bf16(af[i], bfr[j], acc[i][j], 0, 0, 0);
    __builtin_amdgcn_s_setprio(0);
    asm volatile("s_waitcnt vmcnt(0)" ::: "memory");
    __builtin_amdgcn_s_barrier();
    cur ^= 1;
  }
  #undef STAGE

  const int rbase = (l >> 4) * 4, cn = l & 15;
  #pragma unroll
  for (int i = 0; i < 4; ++i) {
    #pragma unroll
    for (int j = 0; j < 4; ++j) {
      #pragma unroll
      for (int r = 0; r < 4; ++r) {
        int m = m0 + wr*64 + i*16 + rbase + r;
        int n = n0 + wc*64 + j*16 + cn;
        float vv = acc[i][j][r];
        if (res) vv += res[(size_t)m * Nr + n];
        if (act == 1) vv = 0.5f*vv*(1.f + erff(vv * 0.70710678118f));
        else if (act == 2) vv = 1.f/(1.f + expf(-vv));
        if (outb) outb[((size_t)(n >> 3) * Mr + m) * 8 + (n & 7)] = f2bf(vv);
        else outf[(size_t)m * Nr + n] = vv;
      }
    }
  }
}

__global__ __launch_bounds__(256) void gemm_bf(const u16* __restrict__ A,
    const u16* __restrict__ W, const float* __restrict__ res,
    float* __restrict__ outf, u16* __restrict__ outb,
    int Mr, int Nr, int Kr, int act)
{
  __shared__ __align__(16) u16 Asm[2*4096];
  __shared__ __align__(16) u16 Bsm[2*4096];
  gemm_core(A, W, res, outf, outb, Mr, Nr, Kr, act,
            blockIdx.y * 128, blockIdx.x * 128, Asm, Bsm);
}

// q,k,v,g in one dispatch: z selects (A,W,out); act=sigmoid for z==3
__global__ __launch_bounds__(256) void gemm_qkvg(const u16* __restrict__ xall,
    const u16* __restrict__ Wall, float* __restrict__ outall)
{
  __shared__ __align__(16) u16 Asm[2*4096];
  __shared__ __align__(16) u16 Bsm[2*4096];
  int z = blockIdx.z;
  const size_t E = (size_t)Mrows * Cc;
  gemm_core(xall + z*E, Wall + (size_t)z*262144, nullptr,
            outall + z*E, nullptr, Mrows, 512, 512, z == 3 ? 2 : 0,
            blockIdx.y * 128, blockIdx.x * 128, Asm, Bsm);
}

// ---------------- exp(rmsnorm(x)) in place, per row ----------------
__global__ __launch_bounds__(256) void rmsexp_kernel(float* __restrict__ x,
    const float* __restrict__ scale)
{
  int row = blockIdx.x, tid = threadIdx.x;
  float* xr = x + (size_t)row * Cc;
  float v0 = xr[tid], v1 = xr[tid+256];
  float s2 = v0*v0 + v1*v1;
  #pragma unroll
  for (int off = 32; off > 0; off >>= 1) s2 += __shfl_down(s2, off, 64);
  __shared__ float rq[4];
  int w = tid >> 6;
  if ((tid & 63) == 0) rq[w] = s2;
  __syncthreads();
  float S2 = rq[0]+rq[1]+rq[2]+rq[3];
  float norm = sqrtf(S2) * 0.044194173824159216f;  // 1/sqrt(512)
  float r = 1.f / (norm + 1e-8f);
  xr[tid]     = expf(scale[tid]     * v0 * r);
  xr[tid+256] = expf(scale[tid+256] * v1 * r);
}

// ---------------- Phase A: chunk-local end state (incl. z as col 128) ----------------
__global__ __launch_bounds__(256) void chunk_state_kernel(const float* __restrict__ k,
    const float* __restrict__ v, const float* __restrict__ td, float* __restrict__ Aug)
{
  __shared__ float k_lds[CL][Dd];
  __shared__ float v_lds[CL][Dd];
  int blk = blockIdx.x; int c = blk & (NC-1); int bh = blk >> 5;
  int b = bh >> 2, h = bh & 3;
  int tid = threadIdx.x;
  size_t base = ((size_t)b*Tt + (size_t)c*CL)*Cc + h*Dd;
  #pragma unroll
  for (int r = 0; r < 4; ++r) {
    int idx4 = r*256 + tid;
    int s = idx4 >> 5; int i4 = (idx4 & 31) << 2;
    *(float4*)&k_lds[s][i4] = *(const float4*)&k[base + (size_t)s*Cc + i4];
    *(float4*)&v_lds[s][i4] = *(const float4*)&v[base + (size_t)s*Cc + i4];
  }
  __syncthreads();
  int iq = tid >> 3; int i0 = iq << 2;
  int jg = tid & 7;  int j0 = jg << 4;
  float lam4[4], powv[4], zacc[4];
  #pragma unroll
  for (int ci=0; ci<4; ++ci) {
    lam4[ci] = expf(-expf(td[h*Dd + i0 + ci]));
    powv[ci] = 1.f; zacc[ci] = 0.f;
  }
  float acc[4][16];
  #pragma unroll
  for (int ci=0; ci<4; ++ci)
    #pragma unroll
    for (int jj=0; jj<16; ++jj) acc[ci][jj] = 0.f;

  for (int s = CL-1; s >= 0; --s) {
    float4 k4 = *(const float4*)&k_lds[s][i0];
    float kw0 = powv[0]*k4.x, kw1 = powv[1]*k4.y, kw2 = powv[2]*k4.z, kw3 = powv[3]*k4.w;
    zacc[0]+=kw0; zacc[1]+=kw1; zacc[2]+=kw2; zacc[3]+=kw3;
    #pragma unroll
    for (int q4 = 0; q4 < 4; ++q4) {
      float4 v4 = *(const float4*)&v_lds[s][j0 + q4*4];
      float vv[4] = {v4.x, v4.y, v4.z, v4.w};
      #pragma unroll
      for (int u=0; u<4; ++u) {
        acc[0][q4*4+u] += kw0*vv[u];
        acc[1][q4*4+u] += kw1*vv[u];
        acc[2][q4*4+u] += kw2*vv[u];
        acc[3][q4*4+u] += kw3*vv[u];
      }
    }
    powv[0]*=lam4[0]; powv[1]*=lam4[1]; powv[2]*=lam4[2]; powv[3]*=lam4[3];
  }
  float* aug = Aug + ((size_t)c*16 + bh)*AUGSZ;
  #pragma unroll
  for (int jj=0; jj<16; ++jj) {
    int j = j0 + jj;
    float4 wv = make_float4(acc[0][jj], acc[1][jj], acc[2][jj], acc[3][jj]);
    *(float4*)&aug[(size_t)j*Dd + i0] = wv;
  }
  if (jg == 0)
    *(float4*)&aug[(size_t)Dd*Dd + i0] = make_float4(zacc[0],zacc[1],zacc[2],zacc[3]);
}

// ---------------- Phase B: inter-chunk prefix scan ----------------
__global__ __launch_bounds__(256) void combine_kernel(float* __restrict__ Aug,
    const float* __restrict__ td)
{
  int idx = blockIdx.x*256 + threadIdx.x;
  if (idx >= AUGSZ) return;
  int bh = blockIdx.y; int h = bh & 3;
  int i = idx & (Dd-1);
  float lamL = expf(-expf(td[h*Dd + i]) * (float)CL);
  float* p = Aug + (size_t)bh*AUGSZ + idx;
  float prev = 0.f;
  for (int c = 0; c < NC; ++c) {
    float val = p[(size_t)c*AUGSTRIDE];
    p[(size_t)c*AUGSTRIDE] = prev;
    prev = lamL*prev + val;
  }
}

// ---------------- Phase C: per-chunk scan from A_init; outputs S and Z -----------
__global__ __launch_bounds__(256, 2) void scan_out_kernel(const float* __restrict__ q,
    const float* __restrict__ k, const float* __restrict__ v,
    const float* __restrict__ td, const float* __restrict__ Aug,
    float* __restrict__ S, float* __restrict__ Z)
{
  __shared__ float part[4*16*128];
  __shared__ float zpart[4*16];
  int blk = blockIdx.x; int c = blk & (NC-1); int bh = blk >> 5;
  int b = bh >> 2, h = bh & 3;
  int tid = threadIdx.x; int w = tid >> 6, l = tid & 63;
  const size_t base = ((size_t)b*Tt)*Cc + h*Dd;
  const float* augc = Aug + ((size_t)c*16 + bh)*AUGSZ;
  int iq = w*32 + (l & 31);
  float lamv = expf(-expf(td[h*Dd + iq]));
  float lam_s[32];
  #pragma unroll
  for (int ii = 0; ii < 32; ++ii) lam_s[ii] = readlane_f(lamv, ii);

  float A0[32], A1[32];
  {
    const float4* p0 = (const float4*)(augc + (size_t)l*Dd + w*32);
    const float4* p1 = (const float4*)(augc + (size_t)(l+64)*Dd + w*32);
    #pragma unroll
    for (int r = 0; r < 8; ++r) {
      float4 a = p0[r];
      A0[4*r+0]=a.x; A0[4*r+1]=a.y; A0[4*r+2]=a.z; A0[4*r+3]=a.w;
      float4 bb = p1[r];
      A1[4*r+0]=bb.x; A1[4*r+1]=bb.y; A1[4*r+2]=bb.z; A1[4*r+3]=bb.w;
    }
  }
  float z = 0.f;
  if (l < 32) z = augc[(size_t)Dd*Dd + w*32 + l];

  int t0 = c*CL;
  const float* qk_ptr = (l < 32) ? q : k;
  size_t pbase = base + (size_t)t0*Cc;
  float qk = qk_ptr[pbase + iq];
  float v0 = v[pbase + l];
  float v1 = v[pbase + l + 64];

  #pragma unroll
  for (int half = 0; half < 2; ++half) {
    for (int tl = 0; tl < 16; ++tl) {
      int t = half*16 + tl;
      float qk_c = qk, v0c = v0, v1c = v1;
      if (t + 1 < CL) {
        size_t nb = pbase + (size_t)(t+1)*Cc;
        qk = qk_ptr[nb + iq];
        v0 = v[nb + l];
        v1 = v[nb + l + 64];
      }
      float s0 = 0.f, s1 = 0.f;
      #pragma unroll
      for (int ii = 0; ii < 32; ++ii) {
        float qs = readlane_f(qk_c, ii);
        float ks = readlane_f(qk_c, 32 + ii);
        A0[ii] = lam_s[ii]*A0[ii] + ks*v0c;
        A1[ii] = lam_s[ii]*A1[ii] + ks*v1c;
        s0 += qs * A0[ii];
        s1 += qs * A1[ii];
      }
      part[(w*16 + tl)*128 + l]      = s0;
      part[(w*16 + tl)*128 + l + 64] = s1;
      float kme = __shfl(qk_c, (l & 31) + 32);
      float p = 0.f;
      if (l < 32) { z = lamv*z + kme; p = qk_c * z; }
      #pragma unroll
      for (int off = 16; off > 0; off >>= 1) p += __shfl_down(p, off);
      if (l == 0) zpart[w*16 + tl] = p;
    }
    __syncthreads();
    #pragma unroll
    for (int r = 0; r < 8; ++r) {
      int lin = r*256 + tid; int tt = lin >> 7; int j = lin & 127;
      float sv = part[tt*128 + j] + part[(16+tt)*128 + j]
               + part[(32+tt)*128 + j] + part[(48+tt)*128 + j];
      S[base + (size_t)(t0 + half*16 + tt)*Cc + j] = sv;
    }
    if (tid < 16) {
      float zv = zpart[tid] + zpart[16+tid] + zpart[32+tid] + zpart[48+tid];
      Z[((size_t)b*Tt + t0 + half*16 + tid)*Hh + h] = zv;
    }
    __syncthreads();
  }
}

// ---------------- gatt = g * S / Z -> blocked bf16 ----------------
__global__ __launch_bounds__(256) void gatt_kernel(const float* __restrict__ g,
    const float* __restrict__ S, const float* __restrict__ Z, u16* __restrict__ out)
{
  int i = blockIdx.x * 256 + threadIdx.x;   // kg*4096 + m
  int m = i & 4095, c0 = (i >> 12) << 3;
  float zi = 1.f / Z[(size_t)m*Hh + (c0 >> 7)];
  const float* gp = g + (size_t)m*Cc + c0;
  const float* sp = S + (size_t)m*Cc + c0;
  float4 ga = *(const float4*)gp, gb = *(const float4*)(gp+4);
  float4 sa = *(const float4*)sp, sb = *(const float4*)(sp+4);
  uint4 o;
  o.x = pack2(ga.x*sa.x*zi, ga.y*sa.y*zi);
  o.y = pack2(ga.z*sa.z*zi, ga.w*sa.w*zi);
  o.z = pack2(gb.x*sb.x*zi, gb.y*sb.y*zi);
  o.w = pack2(gb.z*sb.z*zi, gb.w*sb.w*zi);
  *(uint4*)(out + (size_t)i*8) = o;
}

extern "C" void kernel_launch(void* const* d_in, const int* in_sizes, int n_in,
                              void* d_out, int out_size, void* d_ws, size_t ws_size,
                              hipStream_t stream) {
  const float* x    = (const float*)d_in[0];
  const float* ln1g = (const float*)d_in[1];
  const float* ln1b = (const float*)d_in[2];
  const float* ln2g = (const float*)d_in[3];
  const float* ln2b = (const float*)d_in[4];
  const float* td   = (const float*)d_in[5];
  const float* tmq  = (const float*)d_in[6];
  const float* tmk  = (const float*)d_in[7];
  const float* tmv  = (const float*)d_in[8];
  const float* tmg  = (const float*)d_in[9];
  const float* Wq   = (const float*)d_in[10];
  const float* Wk   = (const float*)d_in[11];
  const float* Wv   = (const float*)d_in[12];
  const float* Wg   = (const float*)d_in[13];
  const float* Wo   = (const float*)d_in[14];
  const float* rsc  = (const float*)d_in[15];
  const float* W1   = (const float*)d_in[16];
  const float* W2   = (const float*)d_in[17];
  float* ws = (float*)d_ws;
  const size_t E = (size_t)Mrows*Cc;           // 2,097,152 floats
  float* s0 = ws;          // h -> q -> h2
  float* s1 = ws + E;      // k -> x1
  float* s2 = ws + 2*E;    // v
  float* s3 = ws + 3*E;    // g
  float* s4 = ws + 4*E;    // S
  u16* xqb = (u16*)(ws + 5*E);             // E u16 each, contiguous x4
  u16* xkb = xqb + E;
  u16* xvb = xkb + E;
  u16* xgb = xvb + E;
  float* Aug = ws + 7*E;                   // 8,454,144 floats; reused as mid_b
  u16* midb = (u16*)Aug;                   // 4096*2048 u16 = 16.8MB <= 33.8MB
  float* wreg = ws + 7*E + (size_t)NC*16*AUGSZ;
  u16* Wqb = (u16*)wreg;                   // 5 x 262144 u16, contiguous
  u16* Wkb = Wqb + 262144;
  u16* Wvb = Wkb + 262144;
  u16* Wgb = Wvb + 262144;
  u16* Wob = Wgb + 262144;
  u16* W1b = Wob + 262144;                 // 1,048,576 u16
  u16* W2b = W1b + 1048576;                // 1,048,576 u16
  float* Zbuf = (float*)(W2b + 1048576);   // B*T*H floats
  u16* gattb = xqb;                        // reuse (xq dead after q GEMM)
  u16* h2b   = xkb;                        // reuse (xk dead after k GEMM)
  float* x1  = s1;

  // weights -> blocked bf16 (5 square in one dispatch, W1/W2 separate)
  wconv5_kernel<<<640,256,0,stream>>>(Wq, Wk, Wv, Wg, Wo, Wqb);
  wconv_kernel<<<512,256,0,stream>>>(W1, W1b, 512, 11);
  wconv_kernel<<<512,256,0,stream>>>(W2, W2b, 2048, 9);

  ln_kernel<<<Mrows,256,0,stream>>>(x, ln1g, ln1b, s0);
  mix_kernel<<<1024,256,0,stream>>>(s0, tmq,tmk,tmv,tmg, xqb,xkb,xvb,xgb);
  gemm_qkvg<<<dim3(4,32,4),256,0,stream>>>(xqb, Wqb, s0);                  // q,k,v,g
  rmsexp_kernel<<<Mrows,256,0,stream>>>(s0, rsc);                          // q
  rmsexp_kernel<<<Mrows,256,0,stream>>>(s1, rsc);                          // k
  chunk_state_kernel<<<16*NC,256,0,stream>>>(s1, s2, td, Aug);
  combine_kernel<<<dim3((AUGSZ+255)/256,16),256,0,stream>>>(Aug, td);
  scan_out_kernel<<<16*NC,256,0,stream>>>(s0, s1, s2, td, Aug, s4, Zbuf);
  gatt_kernel<<<1024,256,0,stream>>>(s3, s4, Zbuf, gattb);
  gemm_bf<<<dim3(4,32),256,0,stream>>>(gattb, Wob, x, x1, nullptr, Mrows,512,512, 0);
  ln_kernel<<<Mrows,256,0,stream>>>(x1, ln2g, ln2b, s0);                   // h2
  wconv_kernel<<<1024,256,0,stream>>>(s0, h2b, 512, 12);                   // h2 -> blocked bf16
  gemm_bf<<<dim3(16,32),256,0,stream>>>(h2b, W1b, nullptr, nullptr, midb, Mrows,2048,512, 1);
  gemm_bf<<<dim3(4,32),256,0,stream>>>(midb, W2b, x1, (float*)d_out, nullptr, Mrows,512,2048, 0);
}

// Round 5
// 228.292 us; speedup vs baseline: 6.8681x; 1.0894x over previous
//
#include <hip/hip_runtime.h>
#include <math.h>

#define Bb 4
#define Tt 1024
#define Cc 512
#define Hh 4
#define Dd 128
#define Mrows (Bb*Tt)   // 4096
#define NC 32           // chunks
#define CL 32           // chunk length (NC*CL == Tt)
#define AUGSZ (Dd*(Dd+1))        // 16512 floats per (chunk, bh)
#define AUGSTRIDE (16*AUGSZ)

typedef unsigned short u16;
typedef __attribute__((ext_vector_type(8))) short bf16x8;
typedef __attribute__((ext_vector_type(4))) float f32x4;

__device__ __forceinline__ float readlane_f(float v, int lane) {
  return __uint_as_float(__builtin_amdgcn_readlane(__float_as_uint(v), lane));
}
__device__ __forceinline__ u16 f2bf(float f) {
  unsigned u = __float_as_uint(f);
  unsigned r = (u + 0x7fffu + ((u >> 16) & 1u)) >> 16;
  return (u16)r;
}
__device__ __forceinline__ unsigned pack2(float a, float b) {
  return (unsigned)f2bf(a) | ((unsigned)f2bf(b) << 16);
}

// ---------------- LayerNorm (one block per row), fp32 out ----------------
__global__ __launch_bounds__(256) void ln_kernel(const float* __restrict__ x,
    const float* __restrict__ g, const float* __restrict__ bta, float* __restrict__ out)
{
  int row = blockIdx.x, tid = threadIdx.x;
  const float* xr = x + (size_t)row * Cc;
  float v0 = xr[tid], v1 = xr[tid + 256];
  float s = v0 + v1, s2 = v0*v0 + v1*v1;
  #pragma unroll
  for (int off = 32; off > 0; off >>= 1) {
    s  += __shfl_down(s,  off, 64);
    s2 += __shfl_down(s2, off, 64);
  }
  __shared__ float rs[4], rq[4];
  int w = tid >> 6;
  if ((tid & 63) == 0) { rs[w] = s; rq[w] = s2; }
  __syncthreads();
  float S  = rs[0]+rs[1]+rs[2]+rs[3];
  float S2 = rq[0]+rq[1]+rq[2]+rq[3];
  float mean = S * (1.0f/Cc);
  float var  = S2 * (1.0f/Cc) - mean*mean;
  float inv = rsqrtf(var + 1e-5f);
  out[(size_t)row*Cc + tid]       = g[tid]     * (v0-mean)*inv + bta[tid];
  out[(size_t)row*Cc + tid + 256] = g[tid+256] * (v1-mean)*inv + bta[tid+256];
}

// ---------------- LayerNorm -> blocked bf16 [C/8][M][8] ----------------
__global__ __launch_bounds__(256) void ln2b_kernel(const float* __restrict__ x,
    const float* __restrict__ g, const float* __restrict__ bta, u16* __restrict__ out)
{
  int row = blockIdx.x, tid = threadIdx.x;
  const float* xr = x + (size_t)row * Cc;
  float v0 = xr[tid], v1 = xr[tid + 256];
  float s = v0 + v1, s2 = v0*v0 + v1*v1;
  #pragma unroll
  for (int off = 32; off > 0; off >>= 1) {
    s  += __shfl_down(s,  off, 64);
    s2 += __shfl_down(s2, off, 64);
  }
  __shared__ float rs[4], rq[4];
  int w = tid >> 6;
  if ((tid & 63) == 0) { rs[w] = s; rq[w] = s2; }
  __syncthreads();
  float S  = rs[0]+rs[1]+rs[2]+rs[3];
  float S2 = rq[0]+rq[1]+rq[2]+rq[3];
  float mean = S * (1.0f/Cc);
  float var  = S2 * (1.0f/Cc) - mean*mean;
  float inv = rsqrtf(var + 1e-5f);
  int c0 = tid, c1 = tid + 256;
  float o0 = g[c0] * (v0-mean)*inv + bta[c0];
  float o1 = g[c1] * (v1-mean)*inv + bta[c1];
  out[((size_t)(c0 >> 3) * Mrows + row) * 8 + (c0 & 7)] = f2bf(o0);
  out[((size_t)(c1 >> 3) * Mrows + row) * 8 + (c1 & 7)] = f2bf(o1);
}

// ---------------- time-shift mix -> blocked bf16 [C/8][M][8] ----------------
__device__ __forceinline__ void mix_one(const float* tm, int c0,
    float4 ha, float4 hb, float4 xa, float4 xb, u16* dst, size_t i8)
{
  float4 ta = *(const float4*)(tm + c0);
  float4 tb = *(const float4*)(tm + c0 + 4);
  uint4 o;
  o.x = pack2(ha.x*ta.x + xa.x*(1.f-ta.x), ha.y*ta.y + xa.y*(1.f-ta.y));
  o.y = pack2(ha.z*ta.z + xa.z*(1.f-ta.z), ha.w*ta.w + xa.w*(1.f-ta.w));
  o.z = pack2(hb.x*tb.x + xb.x*(1.f-tb.x), hb.y*tb.y + xb.y*(1.f-tb.y));
  o.w = pack2(hb.z*tb.z + xb.z*(1.f-tb.z), hb.w*tb.w + xb.w*(1.f-tb.w));
  *(uint4*)(dst + i8) = o;
}

__global__ __launch_bounds__(256) void mix_kernel(const float* __restrict__ h,
    const float* __restrict__ tmq, const float* __restrict__ tmk,
    const float* __restrict__ tmv, const float* __restrict__ tmg,
    u16* __restrict__ xqb, u16* __restrict__ xkb,
    u16* __restrict__ xvb, u16* __restrict__ xgb)
{
  int i = blockIdx.x * 256 + threadIdx.x;     // kg*4096 + m
  int m = i & 4095, c0 = (i >> 12) << 3;
  const float* hp = h + (size_t)m*Cc + c0;
  float4 ha = *(const float4*)hp, hb = *(const float4*)(hp + 4);
  float4 xa = make_float4(0,0,0,0), xb = make_float4(0,0,0,0);
  if (m & 1023) { xa = *(const float4*)(hp - Cc); xb = *(const float4*)(hp - Cc + 4); }
  size_t i8 = (size_t)i * 8;
  mix_one(tmq, c0, ha, hb, xa, xb, xqb, i8);
  mix_one(tmk, c0, ha, hb, xa, xb, xkb, i8);
  mix_one(tmv, c0, ha, hb, xa, xb, xvb, i8);
  mix_one(tmg, c0, ha, hb, xa, xb, xgb, i8);
}

// ---------------- weight fp32 -> blocked bf16 ----------------
__global__ __launch_bounds__(256) void wconv_kernel(const float* __restrict__ src,
    u16* __restrict__ out, int K, int nshift)
{
  int i = blockIdx.x * 256 + threadIdx.x;       // kg*N + n
  int n = i & ((1 << nshift) - 1), kg = i >> nshift;
  const float* p = src + (size_t)n * K + kg * 8;
  float4 a = *(const float4*)p, b = *(const float4*)(p + 4);
  uint4 o;
  o.x = pack2(a.x, a.y); o.y = pack2(a.z, a.w);
  o.z = pack2(b.x, b.y); o.w = pack2(b.z, b.w);
  *(uint4*)(out + (size_t)i * 8) = o;
}

__global__ __launch_bounds__(256) void wconv5_kernel(const float* __restrict__ s0,
    const float* __restrict__ s1, const float* __restrict__ s2,
    const float* __restrict__ s3, const float* __restrict__ s4,
    u16* __restrict__ out)
{
  int wsel = blockIdx.x >> 7;
  const float* src = wsel == 0 ? s0 : wsel == 1 ? s1 : wsel == 2 ? s2 : wsel == 3 ? s3 : s4;
  int i = (blockIdx.x & 127) * 256 + threadIdx.x;  // kg*512 + n
  int n = i & 511, kg = i >> 9;
  const float* p = src + (size_t)n * 512 + kg * 8;
  float4 a = *(const float4*)p, b = *(const float4*)(p + 4);
  uint4 o;
  o.x = pack2(a.x, a.y); o.y = pack2(a.z, a.w);
  o.z = pack2(b.x, b.y); o.w = pack2(b.z, b.w);
  *(uint4*)(out + (size_t)wsel * 262144 + (size_t)i * 8) = o;
}

// ---------------- bf16 MFMA GEMM core: out = act(A @ W^T + res) ----------------
// A blocked [K/8][M][8], W blocked [K/8][N][8]. Tile 128x128, BK=32, 4 waves,
// 4-buffer LDS, depth-3 prefetch with counted vmcnt, 1 barrier per K-step.
__device__ __forceinline__ void gemm_core(const u16* __restrict__ A,
    const u16* __restrict__ W, const float* __restrict__ res,
    float* __restrict__ outf, u16* __restrict__ outb,
    int Mr, int Nr, int Kr, int act, int m0, int n0,
    u16* Asm, u16* Bsm)   // each [4][4096]
{
  const int tid = threadIdx.x, w = tid >> 6, l = tid & 63;
  const int wr = w >> 1, wc = w & 1;
  f32x4 acc[4][4];
  #pragma unroll
  for (int i = 0; i < 4; ++i)
    #pragma unroll
    for (int j = 0; j < 4; ++j) acc[i][j] = (f32x4){0.f,0.f,0.f,0.f};
  const int kgl = l >> 4, rl = l & 15;
  const int q = w * 4;  // wave's load-slot base

  // per-wave: 4 global_load_lds (1 KiB each); slots 0..7 = A-tile, 8..15 = B-tile
  #define STAGE(KT, BUF) do {                                               \
    _Pragma("unroll")                                                       \
    for (int ii = 0; ii < 4; ++ii) {                                        \
      int qq = q + ii;                                                      \
      int isB = qq >> 3, idx = qq & 7, kg = idx >> 1, hf = idx & 1;         \
      const u16* src = isB                                                  \
        ? W + ((size_t)((KT)*4 + kg) * Nr + n0 + hf*64 + l) * 8             \
        : A + ((size_t)((KT)*4 + kg) * Mr + m0 + hf*64 + l) * 8;            \
      u16* dst = (isB ? Bsm : Asm) + (BUF)*4096 + (kg * 128 + hf * 64) * 8; \
      __builtin_amdgcn_global_load_lds(                                     \
          (const __attribute__((address_space(1))) void*)src,               \
          (__attribute__((address_space(3))) void*)dst, 16, 0, 0);          \
    }                                                                       \
  } while (0)

  const int nk = Kr >> 5;
  STAGE(0, 0); STAGE(1, 1); STAGE(2, 2);
  for (int kt = 0; kt < nk; ++kt) {
    const int cur = kt & 3;
    if (kt < nk - 2)       asm volatile("s_waitcnt vmcnt(8)" ::: "memory");
    else if (kt == nk - 2) asm volatile("s_waitcnt vmcnt(4)" ::: "memory");
    else                   asm volatile("s_waitcnt vmcnt(0)" ::: "memory");
    __builtin_amdgcn_s_barrier();
    bf16x8 af[4], bfr[4];
    #pragma unroll
    for (int f = 0; f < 4; ++f)
      af[f] = *(const bf16x8*)&Asm[cur*4096 + (kgl*128 + wr*64 + f*16 + rl) * 8];
    #pragma unroll
    for (int f = 0; f < 4; ++f)
      bfr[f] = *(const bf16x8*)&Bsm[cur*4096 + (kgl*128 + wc*64 + f*16 + rl) * 8];
    if (kt + 3 < nk) STAGE(kt + 3, (kt + 3) & 3);
    __builtin_amdgcn_s_setprio(1);
    #pragma unroll
    for (int i = 0; i < 4; ++i)
      #pragma unroll
      for (int j = 0; j < 4; ++j)
        acc[i][j] = __builtin_amdgcn_mfma_f32_16x16x32_bf16(af[i], bfr[j], acc[i][j], 0, 0, 0);
    __builtin_amdgcn_s_setprio(0);
  }
  #undef STAGE

  const int rbase = (l >> 4) * 4, cn = l & 15;
  #pragma unroll
  for (int i = 0; i < 4; ++i) {
    #pragma unroll
    for (int j = 0; j < 4; ++j) {
      #pragma unroll
      for (int r = 0; r < 4; ++r) {
        int m = m0 + wr*64 + i*16 + rbase + r;
        int n = n0 + wc*64 + j*16 + cn;
        float vv = acc[i][j][r];
        if (res) vv += res[(size_t)m * Nr + n];
        if (act == 1) vv = 0.5f*vv*(1.f + erff(vv * 0.70710678118f));
        else if (act == 2) vv = 1.f/(1.f + expf(-vv));
        if (outb) outb[((size_t)(n >> 3) * Mr + m) * 8 + (n & 7)] = f2bf(vv);
        else outf[(size_t)m * Nr + n] = vv;
      }
    }
  }
}

__global__ __launch_bounds__(256) void gemm_bf(const u16* __restrict__ A,
    const u16* __restrict__ W, const float* __restrict__ res,
    float* __restrict__ outf, u16* __restrict__ outb,
    int Mr, int Nr, int Kr, int act)
{
  __shared__ __align__(16) u16 Asm[4*4096];
  __shared__ __align__(16) u16 Bsm[4*4096];
  gemm_core(A, W, res, outf, outb, Mr, Nr, Kr, act,
            blockIdx.y * 128, blockIdx.x * 128, Asm, Bsm);
}

// q,k,v,g in one dispatch: z selects (A,W,out); act=sigmoid for z==3
__global__ __launch_bounds__(256) void gemm_qkvg(const u16* __restrict__ xall,
    const u16* __restrict__ Wall, float* __restrict__ outall)
{
  __shared__ __align__(16) u16 Asm[4*4096];
  __shared__ __align__(16) u16 Bsm[4*4096];
  int z = blockIdx.z;
  const size_t E = (size_t)Mrows * Cc;
  gemm_core(xall + z*E, Wall + (size_t)z*262144, nullptr,
            outall + z*E, nullptr, Mrows, 512, 512, z == 3 ? 2 : 0,
            blockIdx.y * 128, blockIdx.x * 128, Asm, Bsm);
}

// ---------------- exp(rmsnorm(x)) in place (q and k in one dispatch) ----------------
__global__ __launch_bounds__(256) void rmsexp_kernel(float* __restrict__ qm,
    float* __restrict__ km, const float* __restrict__ scale)
{
  int row = blockIdx.x, tid = threadIdx.x;
  float* xr = (blockIdx.y ? km : qm) + (size_t)row * Cc;
  float v0 = xr[tid], v1 = xr[tid+256];
  float s2 = v0*v0 + v1*v1;
  #pragma unroll
  for (int off = 32; off > 0; off >>= 1) s2 += __shfl_down(s2, off, 64);
  __shared__ float rq[4];
  int w = tid >> 6;
  if ((tid & 63) == 0) rq[w] = s2;
  __syncthreads();
  float S2 = rq[0]+rq[1]+rq[2]+rq[3];
  float norm = sqrtf(S2) * 0.044194173824159216f;  // 1/sqrt(512)
  float r = 1.f / (norm + 1e-8f);
  xr[tid]     = expf(scale[tid]     * v0 * r);
  xr[tid+256] = expf(scale[tid+256] * v1 * r);
}

// ---------------- Phase A: chunk-local end state (incl. z as col 128) ----------------
__global__ __launch_bounds__(256) void chunk_state_kernel(const float* __restrict__ k,
    const float* __restrict__ v, const float* __restrict__ td, float* __restrict__ Aug)
{
  __shared__ float k_lds[CL][Dd];
  __shared__ float v_lds[CL][Dd];
  int blk = blockIdx.x; int c = blk & (NC-1); int bh = blk >> 5;
  int b = bh >> 2, h = bh & 3;
  int tid = threadIdx.x;
  size_t base = ((size_t)b*Tt + (size_t)c*CL)*Cc + h*Dd;
  #pragma unroll
  for (int r = 0; r < 4; ++r) {
    int idx4 = r*256 + tid;
    int s = idx4 >> 5; int i4 = (idx4 & 31) << 2;
    *(float4*)&k_lds[s][i4] = *(const float4*)&k[base + (size_t)s*Cc + i4];
    *(float4*)&v_lds[s][i4] = *(const float4*)&v[base + (size_t)s*Cc + i4];
  }
  __syncthreads();
  int iq = tid >> 3; int i0 = iq << 2;
  int jg = tid & 7;  int j0 = jg << 4;
  float lam4[4], powv[4], zacc[4];
  #pragma unroll
  for (int ci=0; ci<4; ++ci) {
    lam4[ci] = expf(-expf(td[h*Dd + i0 + ci]));
    powv[ci] = 1.f; zacc[ci] = 0.f;
  }
  float acc[4][16];
  #pragma unroll
  for (int ci=0; ci<4; ++ci)
    #pragma unroll
    for (int jj=0; jj<16; ++jj) acc[ci][jj] = 0.f;

  for (int s = CL-1; s >= 0; --s) {
    float4 k4 = *(const float4*)&k_lds[s][i0];
    float kw0 = powv[0]*k4.x, kw1 = powv[1]*k4.y, kw2 = powv[2]*k4.z, kw3 = powv[3]*k4.w;
    zacc[0]+=kw0; zacc[1]+=kw1; zacc[2]+=kw2; zacc[3]+=kw3;
    #pragma unroll
    for (int q4 = 0; q4 < 4; ++q4) {
      float4 v4 = *(const float4*)&v_lds[s][j0 + q4*4];
      float vv[4] = {v4.x, v4.y, v4.z, v4.w};
      #pragma unroll
      for (int u=0; u<4; ++u) {
        acc[0][q4*4+u] += kw0*vv[u];
        acc[1][q4*4+u] += kw1*vv[u];
        acc[2][q4*4+u] += kw2*vv[u];
        acc[3][q4*4+u] += kw3*vv[u];
      }
    }
    powv[0]*=lam4[0]; powv[1]*=lam4[1]; powv[2]*=lam4[2]; powv[3]*=lam4[3];
  }
  float* aug = Aug + ((size_t)c*16 + bh)*AUGSZ;
  #pragma unroll
  for (int jj=0; jj<16; ++jj) {
    int j = j0 + jj;
    float4 wv = make_float4(acc[0][jj], acc[1][jj], acc[2][jj], acc[3][jj]);
    *(float4*)&aug[(size_t)j*Dd + i0] = wv;
  }
  if (jg == 0)
    *(float4*)&aug[(size_t)Dd*Dd + i0] = make_float4(zacc[0],zacc[1],zacc[2],zacc[3]);
}

// ---------------- Phase B: inter-chunk prefix scan ----------------
__global__ __launch_bounds__(256) void combine_kernel(float* __restrict__ Aug,
    const float* __restrict__ td)
{
  int idx = blockIdx.x*256 + threadIdx.x;
  if (idx >= AUGSZ) return;
  int bh = blockIdx.y; int h = bh & 3;
  int i = idx & (Dd-1);
  float lamL = expf(-expf(td[h*Dd + i]) * (float)CL);
  float* p = Aug + (size_t)bh*AUGSZ + idx;
  float prev = 0.f;
  for (int c = 0; c < NC; ++c) {
    float val = p[(size_t)c*AUGSTRIDE];
    p[(size_t)c*AUGSTRIDE] = prev;
    prev = lamL*prev + val;
  }
}

// ---------------- Phase C: per-chunk scan; fused gatt = g*S/Z -> blocked bf16 ------
__global__ __launch_bounds__(256, 2) void scan_out_kernel(const float* __restrict__ q,
    const float* __restrict__ k, const float* __restrict__ v,
    const float* __restrict__ td, const float* __restrict__ Aug,
    const float* __restrict__ gmat, u16* __restrict__ out)
{
  __shared__ float part[4*16*128];
  __shared__ float zpart[4*16];
  int blk = blockIdx.x; int c = blk & (NC-1); int bh = blk >> 5;
  int b = bh >> 2, h = bh & 3;
  int tid = threadIdx.x; int w = tid >> 6, l = tid & 63;
  const size_t base = ((size_t)b*Tt)*Cc + h*Dd;
  const float* augc = Aug + ((size_t)c*16 + bh)*AUGSZ;
  int iq = w*32 + (l & 31);
  float lamv = expf(-expf(td[h*Dd + iq]));
  float lam_s[32];
  #pragma unroll
  for (int ii = 0; ii < 32; ++ii) lam_s[ii] = readlane_f(lamv, ii);

  float A0[32], A1[32];
  {
    const float4* p0 = (const float4*)(augc + (size_t)l*Dd + w*32);
    const float4* p1 = (const float4*)(augc + (size_t)(l+64)*Dd + w*32);
    #pragma unroll
    for (int r = 0; r < 8; ++r) {
      float4 a = p0[r];
      A0[4*r+0]=a.x; A0[4*r+1]=a.y; A0[4*r+2]=a.z; A0[4*r+3]=a.w;
      float4 bb = p1[r];
      A1[4*r+0]=bb.x; A1[4*r+1]=bb.y; A1[4*r+2]=bb.z; A1[4*r+3]=bb.w;
    }
  }
  float z = 0.f;
  if (l < 32) z = augc[(size_t)Dd*Dd + w*32 + l];

  int t0 = c*CL;
  const float* qk_ptr = (l < 32) ? q : k;
  size_t pbase = base + (size_t)t0*Cc;
  float qk = qk_ptr[pbase + iq];
  float v0 = v[pbase + l];
  float v1 = v[pbase + l + 64];

  #pragma unroll
  for (int half = 0; half < 2; ++half) {
    for (int tl = 0; tl < 16; ++tl) {
      int t = half*16 + tl;
      float qk_c = qk, v0c = v0, v1c = v1;
      if (t + 1 < CL) {
        size_t nb = pbase + (size_t)(t+1)*Cc;
        qk = qk_ptr[nb + iq];
        v0 = v[nb + l];
        v1 = v[nb + l + 64];
      }
      float s0 = 0.f, s1 = 0.f;
      #pragma unroll
      for (int ii = 0; ii < 32; ++ii) {
        float qs = readlane_f(qk_c, ii);
        float ks = readlane_f(qk_c, 32 + ii);
        A0[ii] = lam_s[ii]*A0[ii] + ks*v0c;
        A1[ii] = lam_s[ii]*A1[ii] + ks*v1c;
        s0 += qs * A0[ii];
        s1 += qs * A1[ii];
      }
      part[(w*16 + tl)*128 + l]      = s0;
      part[(w*16 + tl)*128 + l + 64] = s1;
      float kme = __shfl(qk_c, (l & 31) + 32);
      float p = 0.f;
      if (l < 32) { z = lamv*z + kme; p = qk_c * z; }
      #pragma unroll
      for (int off = 16; off > 0; off >>= 1) p += __shfl_down(p, off);
      if (l == 0) zpart[w*16 + tl] = p;
    }
    __syncthreads();
    #pragma unroll
    for (int r = 0; r < 8; ++r) {
      int lin = r*256 + tid; int tt = lin >> 7; int j = lin & 127;
      float sv = part[tt*128 + j] + part[(16+tt)*128 + j]
               + part[(32+tt)*128 + j] + part[(48+tt)*128 + j];
      float zv = zpart[tt] + zpart[16+tt] + zpart[32+tt] + zpart[48+tt];
      int m = b*Tt + t0 + half*16 + tt;
      int cc = h*Dd + j;
      float gv = gmat[(size_t)m*Cc + cc];
      out[((size_t)(cc >> 3) * Mrows + m) * 8 + (cc & 7)] = f2bf(gv * sv / zv);
    }
    __syncthreads();
  }
}

extern "C" void kernel_launch(void* const* d_in, const int* in_sizes, int n_in,
                              void* d_out, int out_size, void* d_ws, size_t ws_size,
                              hipStream_t stream) {
  const float* x    = (const float*)d_in[0];
  const float* ln1g = (const float*)d_in[1];
  const float* ln1b = (const float*)d_in[2];
  const float* ln2g = (const float*)d_in[3];
  const float* ln2b = (const float*)d_in[4];
  const float* td   = (const float*)d_in[5];
  const float* tmq  = (const float*)d_in[6];
  const float* tmk  = (const float*)d_in[7];
  const float* tmv  = (const float*)d_in[8];
  const float* tmg  = (const float*)d_in[9];
  const float* Wq   = (const float*)d_in[10];
  const float* Wk   = (const float*)d_in[11];
  const float* Wv   = (const float*)d_in[12];
  const float* Wg   = (const float*)d_in[13];
  const float* Wo   = (const float*)d_in[14];
  const float* rsc  = (const float*)d_in[15];
  const float* W1   = (const float*)d_in[16];
  const float* W2   = (const float*)d_in[17];
  float* ws = (float*)d_ws;
  const size_t E = (size_t)Mrows*Cc;           // 2,097,152 floats
  float* s0 = ws;          // h -> q -> h2(fp32 src for ln2b)
  float* s1 = ws + E;      // k -> x1
  float* s2 = ws + 2*E;    // v
  float* s3 = ws + 3*E;    // g
  // s4 slot free
  u16* xqb = (u16*)(ws + 5*E);             // E u16 each, contiguous x4
  u16* xkb = xqb + E;
  u16* xvb = xkb + E;
  u16* xgb = xvb + E;
  float* Aug = ws + 7*E;                   // 8,454,144 floats; reused as mid_b
  u16* midb = (u16*)Aug;                   // 4096*2048 u16 = 16.8MB <= 33.8MB
  float* wreg = ws + 7*E + (size_t)NC*16*AUGSZ;
  u16* Wqb = (u16*)wreg;                   // 5 x 262144 u16, contiguous
  u16* W1b = Wqb + 5*262144;               // 1,048,576 u16
  u16* W2b = W1b + 1048576;                // 1,048,576 u16
  u16* Wob = Wqb + 4*262144;
  u16* gattb = xqb;                        // reuse (xq dead after qkvg GEMM)
  u16* h2b   = xkb;                        // reuse (xk dead after qkvg GEMM)
  float* x1  = s1;

  wconv5_kernel<<<640,256,0,stream>>>(Wq, Wk, Wv, Wg, Wo, Wqb);
  wconv_kernel<<<512,256,0,stream>>>(W1, W1b, 512, 11);
  wconv_kernel<<<512,256,0,stream>>>(W2, W2b, 2048, 9);

  ln_kernel<<<Mrows,256,0,stream>>>(x, ln1g, ln1b, s0);
  mix_kernel<<<1024,256,0,stream>>>(s0, tmq,tmk,tmv,tmg, xqb,xkb,xvb,xgb);
  gemm_qkvg<<<dim3(4,32,4),256,0,stream>>>(xqb, Wqb, s0);                  // q,k,v,g
  rmsexp_kernel<<<dim3(Mrows,2),256,0,stream>>>(s0, s1, rsc);              // q,k
  chunk_state_kernel<<<16*NC,256,0,stream>>>(s1, s2, td, Aug);
  combine_kernel<<<dim3((AUGSZ+255)/256,16),256,0,stream>>>(Aug, td);
  scan_out_kernel<<<16*NC,256,0,stream>>>(s0, s1, s2, td, Aug, s3, gattb); // gatt bf16
  gemm_bf<<<dim3(4,32),256,0,stream>>>(gattb, Wob, x, x1, nullptr, Mrows,512,512, 0);
  ln2b_kernel<<<Mrows,256,0,stream>>>(x1, ln2g, ln2b, h2b);                // h2 -> bf16
  gemm_bf<<<dim3(16,32),256,0,stream>>>(h2b, W1b, nullptr, nullptr, midb, Mrows,2048,512, 1);
  gemm_bf<<<dim3(4,32),256,0,stream>>>(midb, W2b, x1, (float*)d_out, nullptr, Mrows,512,2048, 0);
}

// Round 6
// 191.500 us; speedup vs baseline: 8.1876x; 1.1921x over previous
//
#include <hip/hip_runtime.h>
#include <math.h>

#define Bb 4
#define Tt 1024
#define Cc 512
#define Hh 4
#define Dd 128
#define Mrows (Bb*Tt)   // 4096
#define NC 32           // chunks
#define CL 32           // chunk length (NC*CL == Tt)
#define AUGSZ (Dd*(Dd+1))        // 16512 floats per (chunk, bh)
#define AUGSTRIDE (16*AUGSZ)

typedef unsigned short u16;
typedef __attribute__((ext_vector_type(8))) short bf16x8;
typedef __attribute__((ext_vector_type(4))) float f32x4;

__device__ __forceinline__ float readlane_f(float v, int lane) {
  return __uint_as_float(__builtin_amdgcn_readlane(__float_as_uint(v), lane));
}
__device__ __forceinline__ u16 f2bf(float f) {
  unsigned u = __float_as_uint(f);
  unsigned r = (u + 0x7fffu + ((u >> 16) & 1u)) >> 16;
  return (u16)r;
}
__device__ __forceinline__ unsigned pack2(float a, float b) {
  return (unsigned)f2bf(a) | ((unsigned)f2bf(b) << 16);
}

// ---------------- LayerNorm (one block per row), fp32 out ----------------
__global__ __launch_bounds__(256) void ln_kernel(const float* __restrict__ x,
    const float* __restrict__ g, const float* __restrict__ bta, float* __restrict__ out)
{
  int row = blockIdx.x, tid = threadIdx.x;
  const float* xr = x + (size_t)row * Cc;
  float v0 = xr[tid], v1 = xr[tid + 256];
  float s = v0 + v1, s2 = v0*v0 + v1*v1;
  #pragma unroll
  for (int off = 32; off > 0; off >>= 1) {
    s  += __shfl_down(s,  off, 64);
    s2 += __shfl_down(s2, off, 64);
  }
  __shared__ float rs[4], rq[4];
  int w = tid >> 6;
  if ((tid & 63) == 0) { rs[w] = s; rq[w] = s2; }
  __syncthreads();
  float S  = rs[0]+rs[1]+rs[2]+rs[3];
  float S2 = rq[0]+rq[1]+rq[2]+rq[3];
  float mean = S * (1.0f/Cc);
  float var  = S2 * (1.0f/Cc) - mean*mean;
  float inv = rsqrtf(var + 1e-5f);
  out[(size_t)row*Cc + tid]       = g[tid]     * (v0-mean)*inv + bta[tid];
  out[(size_t)row*Cc + tid + 256] = g[tid+256] * (v1-mean)*inv + bta[tid+256];
}

// --------- fused: x1 = x + p0 + p1 (Wo split-K partials); h2b = LN(x1) blocked bf16 ---------
__global__ __launch_bounds__(256) void ln2b_kernel(const float* __restrict__ x,
    const float* __restrict__ p0, const float* __restrict__ p1,
    const float* __restrict__ g, const float* __restrict__ bta,
    float* __restrict__ x1, u16* __restrict__ out)
{
  int row = blockIdx.x, tid = threadIdx.x;
  size_t r0 = (size_t)row * Cc + tid, r1 = r0 + 256;
  float v0 = x[r0] + p0[r0] + p1[r0];
  float v1 = x[r1] + p0[r1] + p1[r1];
  x1[r0] = v0; x1[r1] = v1;
  float s = v0 + v1, s2 = v0*v0 + v1*v1;
  #pragma unroll
  for (int off = 32; off > 0; off >>= 1) {
    s  += __shfl_down(s,  off, 64);
    s2 += __shfl_down(s2, off, 64);
  }
  __shared__ float rs[4], rq[4];
  int w = tid >> 6;
  if ((tid & 63) == 0) { rs[w] = s; rq[w] = s2; }
  __syncthreads();
  float S  = rs[0]+rs[1]+rs[2]+rs[3];
  float S2 = rq[0]+rq[1]+rq[2]+rq[3];
  float mean = S * (1.0f/Cc);
  float var  = S2 * (1.0f/Cc) - mean*mean;
  float inv = rsqrtf(var + 1e-5f);
  int c0 = tid, c1 = tid + 256;
  float o0 = g[c0] * (v0-mean)*inv + bta[c0];
  float o1 = g[c1] * (v1-mean)*inv + bta[c1];
  out[((size_t)(c0 >> 3) * Mrows + row) * 8 + (c0 & 7)] = f2bf(o0);
  out[((size_t)(c1 >> 3) * Mrows + row) * 8 + (c1 & 7)] = f2bf(o1);
}

// ---------------- time-shift mix -> blocked bf16 [C/8][M][8] ----------------
__device__ __forceinline__ void mix_one(const float* tm, int c0,
    float4 ha, float4 hb, float4 xa, float4 xb, u16* dst, size_t i8)
{
  float4 ta = *(const float4*)(tm + c0);
  float4 tb = *(const float4*)(tm + c0 + 4);
  uint4 o;
  o.x = pack2(ha.x*ta.x + xa.x*(1.f-ta.x), ha.y*ta.y + xa.y*(1.f-ta.y));
  o.y = pack2(ha.z*ta.z + xa.z*(1.f-ta.z), ha.w*ta.w + xa.w*(1.f-ta.w));
  o.z = pack2(hb.x*tb.x + xb.x*(1.f-tb.x), hb.y*tb.y + xb.y*(1.f-tb.y));
  o.w = pack2(hb.z*tb.z + xb.z*(1.f-tb.z), hb.w*tb.w + xb.w*(1.f-tb.w));
  *(uint4*)(dst + i8) = o;
}

__global__ __launch_bounds__(256) void mix_kernel(const float* __restrict__ h,
    const float* __restrict__ tmq, const float* __restrict__ tmk,
    const float* __restrict__ tmv, const float* __restrict__ tmg,
    u16* __restrict__ xqb, u16* __restrict__ xkb,
    u16* __restrict__ xvb, u16* __restrict__ xgb)
{
  int i = blockIdx.x * 256 + threadIdx.x;     // kg*4096 + m
  int m = i & 4095, c0 = (i >> 12) << 3;
  const float* hp = h + (size_t)m*Cc + c0;
  float4 ha = *(const float4*)hp, hb = *(const float4*)(hp + 4);
  float4 xa = make_float4(0,0,0,0), xb = make_float4(0,0,0,0);
  if (m & 1023) { xa = *(const float4*)(hp - Cc); xb = *(const float4*)(hp - Cc + 4); }
  size_t i8 = (size_t)i * 8;
  mix_one(tmq, c0, ha, hb, xa, xb, xqb, i8);
  mix_one(tmk, c0, ha, hb, xa, xb, xkb, i8);
  mix_one(tmv, c0, ha, hb, xa, xb, xvb, i8);
  mix_one(tmg, c0, ha, hb, xa, xb, xgb, i8);
}

// ---------------- weight fp32 -> blocked bf16 ----------------
__global__ __launch_bounds__(256) void wconv_kernel(const float* __restrict__ src,
    u16* __restrict__ out, int K, int nshift)
{
  int i = blockIdx.x * 256 + threadIdx.x;       // kg*N + n
  int n = i & ((1 << nshift) - 1), kg = i >> nshift;
  const float* p = src + (size_t)n * K + kg * 8;
  float4 a = *(const float4*)p, b = *(const float4*)(p + 4);
  uint4 o;
  o.x = pack2(a.x, a.y); o.y = pack2(a.z, a.w);
  o.z = pack2(b.x, b.y); o.w = pack2(b.z, b.w);
  *(uint4*)(out + (size_t)i * 8) = o;
}

__global__ __launch_bounds__(256) void wconv5_kernel(const float* __restrict__ s0,
    const float* __restrict__ s1, const float* __restrict__ s2,
    const float* __restrict__ s3, const float* __restrict__ s4,
    u16* __restrict__ out)
{
  int wsel = blockIdx.x >> 7;
  const float* src = wsel == 0 ? s0 : wsel == 1 ? s1 : wsel == 2 ? s2 : wsel == 3 ? s3 : s4;
  int i = (blockIdx.x & 127) * 256 + threadIdx.x;  // kg*512 + n
  int n = i & 511, kg = i >> 9;
  const float* p = src + (size_t)n * 512 + kg * 8;
  float4 a = *(const float4*)p, b = *(const float4*)(p + 4);
  uint4 o;
  o.x = pack2(a.x, a.y); o.y = pack2(a.z, a.w);
  o.z = pack2(b.x, b.y); o.w = pack2(b.z, b.w);
  *(uint4*)(out + (size_t)wsel * 262144 + (size_t)i * 8) = o;
}

// ---------------- bf16 MFMA GEMM core (templated dims) ----------------
// A blocked [KR/8][MR][8], W blocked [KR/8][NR][8]. Tile 128x128, BK=32, 4 waves,
// 4-buffer LDS, depth-3 prefetch with counted vmcnt, 1 barrier per K-step.
template<int MR, int NR, int KR>
__device__ __forceinline__ void gemm_core(const u16* __restrict__ A,
    const u16* __restrict__ W, const float* __restrict__ res,
    float* __restrict__ outf, u16* __restrict__ outb, int act,
    int m0, int n0, u16* Asm, u16* Bsm)   // each [4][4096]
{
  const int tid = threadIdx.x, w = tid >> 6, l = tid & 63;
  const int wr = w >> 1, wc = w & 1;
  f32x4 acc[4][4];
  #pragma unroll
  for (int i = 0; i < 4; ++i)
    #pragma unroll
    for (int j = 0; j < 4; ++j) acc[i][j] = (f32x4){0.f,0.f,0.f,0.f};
  const int kgl = l >> 4, rl = l & 15;
  const int q = w * 4;  // wave's load-slot base

  #define STAGE(KT, BUF) do {                                               \
    _Pragma("unroll")                                                       \
    for (int ii = 0; ii < 4; ++ii) {                                        \
      int qq = q + ii;                                                      \
      int isB = qq >> 3, idx = qq & 7, kg = idx >> 1, hf = idx & 1;         \
      const u16* src = isB                                                  \
        ? W + ((size_t)((KT)*4 + kg) * NR + n0 + hf*64 + l) * 8             \
        : A + ((size_t)((KT)*4 + kg) * MR + m0 + hf*64 + l) * 8;            \
      u16* dst = (isB ? Bsm : Asm) + (BUF)*4096 + (kg * 128 + hf * 64) * 8; \
      __builtin_amdgcn_global_load_lds(                                     \
          (const __attribute__((address_space(1))) void*)src,               \
          (__attribute__((address_space(3))) void*)dst, 16, 0, 0);          \
    }                                                                       \
  } while (0)

  constexpr int nk = KR >> 5;
  STAGE(0, 0); STAGE(1, 1); STAGE(2, 2);
  for (int kt = 0; kt < nk; ++kt) {
    const int cur = kt & 3;
    if (kt < nk - 2)       asm volatile("s_waitcnt vmcnt(8)" ::: "memory");
    else if (kt == nk - 2) asm volatile("s_waitcnt vmcnt(4)" ::: "memory");
    else                   asm volatile("s_waitcnt vmcnt(0)" ::: "memory");
    __builtin_amdgcn_s_barrier();
    bf16x8 af[4], bfr[4];
    #pragma unroll
    for (int f = 0; f < 4; ++f)
      af[f] = *(const bf16x8*)&Asm[cur*4096 + (kgl*128 + wr*64 + f*16 + rl) * 8];
    #pragma unroll
    for (int f = 0; f < 4; ++f)
      bfr[f] = *(const bf16x8*)&Bsm[cur*4096 + (kgl*128 + wc*64 + f*16 + rl) * 8];
    if (kt + 3 < nk) STAGE(kt + 3, (kt + 3) & 3);
    __builtin_amdgcn_s_setprio(1);
    #pragma unroll
    for (int i = 0; i < 4; ++i)
      #pragma unroll
      for (int j = 0; j < 4; ++j)
        acc[i][j] = __builtin_amdgcn_mfma_f32_16x16x32_bf16(af[i], bfr[j], acc[i][j], 0, 0, 0);
    __builtin_amdgcn_s_setprio(0);
  }
  #undef STAGE

  const int rbase = (l >> 4) * 4, cn = l & 15;
  #pragma unroll
  for (int i = 0; i < 4; ++i) {
    #pragma unroll
    for (int j = 0; j < 4; ++j) {
      #pragma unroll
      for (int r = 0; r < 4; ++r) {
        int m = m0 + wr*64 + i*16 + rbase + r;
        int n = n0 + wc*64 + j*16 + cn;
        float vv = acc[i][j][r];
        if (res) vv += res[(size_t)m * NR + n];
        if (act == 1) vv = 0.5f*vv*(1.f + erff(vv * 0.70710678118f));
        else if (act == 2) vv = 1.f/(1.f + expf(-vv));
        if (outb) outb[((size_t)(n >> 3) * MR + m) * 8 + (n & 7)] = f2bf(vv);
        else outf[(size_t)m * NR + n] = vv;
      }
    }
  }
}

// q,k,v,g in one dispatch (z selects; sigmoid for z==3)
__global__ __launch_bounds__(256) void gemm_qkvg(const u16* __restrict__ xall,
    const u16* __restrict__ Wall, float* __restrict__ outall)
{
  __shared__ __align__(16) u16 Asm[4*4096];
  __shared__ __align__(16) u16 Bsm[4*4096];
  int z = blockIdx.z;
  const size_t E = (size_t)Mrows * Cc;
  gemm_core<Mrows,512,512>(xall + z*E, Wall + (size_t)z*262144, nullptr,
            outall + z*E, nullptr, z == 3 ? 2 : 0,
            blockIdx.y * 128, blockIdx.x * 128, Asm, Bsm);
}

// Wo split-K=2: partials -> pbuf + z*E
__global__ __launch_bounds__(256) void gemm_wo(const u16* __restrict__ A,
    const u16* __restrict__ W, float* __restrict__ pbuf)
{
  __shared__ __align__(16) u16 Asm[4*4096];
  __shared__ __align__(16) u16 Bsm[4*4096];
  int z = blockIdx.z;
  const size_t E = (size_t)Mrows * Cc;
  gemm_core<Mrows,512,256>(A + (size_t)z*32*Mrows*8, W + (size_t)z*32*512*8, nullptr,
            pbuf + z*E, nullptr, 0, blockIdx.y * 128, blockIdx.x * 128, Asm, Bsm);
}

// W1: gelu, blocked bf16 out
__global__ __launch_bounds__(256) void gemm_w1(const u16* __restrict__ A,
    const u16* __restrict__ W, u16* __restrict__ outb)
{
  __shared__ __align__(16) u16 Asm[4*4096];
  __shared__ __align__(16) u16 Bsm[4*4096];
  gemm_core<Mrows,2048,512>(A, W, nullptr, nullptr, outb, 1,
            blockIdx.y * 128, blockIdx.x * 128, Asm, Bsm);
}

// W2 split-K=4: partials -> pbuf + z*E
__global__ __launch_bounds__(256) void gemm_w2(const u16* __restrict__ A,
    const u16* __restrict__ W, float* __restrict__ pbuf)
{
  __shared__ __align__(16) u16 Asm[4*4096];
  __shared__ __align__(16) u16 Bsm[4*4096];
  int z = blockIdx.z;
  const size_t E = (size_t)Mrows * Cc;
  gemm_core<Mrows,512,512>(A + (size_t)z*64*Mrows*8, W + (size_t)z*64*512*8, nullptr,
            pbuf + z*E, nullptr, 0, blockIdx.y * 128, blockIdx.x * 128, Asm, Bsm);
}

// ---------------- out = x1 + p0+p1+p2+p3 ----------------
__global__ __launch_bounds__(256) void reduce4_kernel(const float* __restrict__ x1,
    const float* __restrict__ p, float* __restrict__ out)
{
  const size_t E = (size_t)Mrows * Cc;
  size_t f = ((size_t)blockIdx.x * 256 + threadIdx.x) * 4;
  float4 a = *(const float4*)(x1 + f);
  float4 q0 = *(const float4*)(p + f);
  float4 q1 = *(const float4*)(p + E + f);
  float4 q2 = *(const float4*)(p + 2*E + f);
  float4 q3 = *(const float4*)(p + 3*E + f);
  float4 o;
  o.x = a.x + q0.x + q1.x + q2.x + q3.x;
  o.y = a.y + q0.y + q1.y + q2.y + q3.y;
  o.z = a.z + q0.z + q1.z + q2.z + q3.z;
  o.w = a.w + q0.w + q1.w + q2.w + q3.w;
  *(float4*)(out + f) = o;
}

// ---------------- exp(rmsnorm(x)) in place (q and k in one dispatch) ----------------
__global__ __launch_bounds__(256) void rmsexp_kernel(float* __restrict__ qm,
    float* __restrict__ km, const float* __restrict__ scale)
{
  int row = blockIdx.x, tid = threadIdx.x;
  float* xr = (blockIdx.y ? km : qm) + (size_t)row * Cc;
  float v0 = xr[tid], v1 = xr[tid+256];
  float s2 = v0*v0 + v1*v1;
  #pragma unroll
  for (int off = 32; off > 0; off >>= 1) s2 += __shfl_down(s2, off, 64);
  __shared__ float rq[4];
  int w = tid >> 6;
  if ((tid & 63) == 0) rq[w] = s2;
  __syncthreads();
  float S2 = rq[0]+rq[1]+rq[2]+rq[3];
  float norm = sqrtf(S2) * 0.044194173824159216f;  // 1/sqrt(512)
  float r = 1.f / (norm + 1e-8f);
  xr[tid]     = expf(scale[tid]     * v0 * r);
  xr[tid+256] = expf(scale[tid+256] * v1 * r);
}

// ---------------- Phase A: chunk-local end state (incl. z as col 128) ----------------
__global__ __launch_bounds__(256) void chunk_state_kernel(const float* __restrict__ k,
    const float* __restrict__ v, const float* __restrict__ td, float* __restrict__ Aug)
{
  __shared__ float k_lds[CL][Dd];
  __shared__ float v_lds[CL][Dd];
  int blk = blockIdx.x; int c = blk & (NC-1); int bh = blk >> 5;
  int b = bh >> 2, h = bh & 3;
  int tid = threadIdx.x;
  size_t base = ((size_t)b*Tt + (size_t)c*CL)*Cc + h*Dd;
  #pragma unroll
  for (int r = 0; r < 4; ++r) {
    int idx4 = r*256 + tid;
    int s = idx4 >> 5; int i4 = (idx4 & 31) << 2;
    *(float4*)&k_lds[s][i4] = *(const float4*)&k[base + (size_t)s*Cc + i4];
    *(float4*)&v_lds[s][i4] = *(const float4*)&v[base + (size_t)s*Cc + i4];
  }
  __syncthreads();
  int iq = tid >> 3; int i0 = iq << 2;
  int jg = tid & 7;  int j0 = jg << 4;
  float lam4[4], powv[4], zacc[4];
  #pragma unroll
  for (int ci=0; ci<4; ++ci) {
    lam4[ci] = expf(-expf(td[h*Dd + i0 + ci]));
    powv[ci] = 1.f; zacc[ci] = 0.f;
  }
  float acc[4][16];
  #pragma unroll
  for (int ci=0; ci<4; ++ci)
    #pragma unroll
    for (int jj=0; jj<16; ++jj) acc[ci][jj] = 0.f;

  for (int s = CL-1; s >= 0; --s) {
    float4 k4 = *(const float4*)&k_lds[s][i0];
    float kw0 = powv[0]*k4.x, kw1 = powv[1]*k4.y, kw2 = powv[2]*k4.z, kw3 = powv[3]*k4.w;
    zacc[0]+=kw0; zacc[1]+=kw1; zacc[2]+=kw2; zacc[3]+=kw3;
    #pragma unroll
    for (int q4 = 0; q4 < 4; ++q4) {
      float4 v4 = *(const float4*)&v_lds[s][j0 + q4*4];
      float vv[4] = {v4.x, v4.y, v4.z, v4.w};
      #pragma unroll
      for (int u=0; u<4; ++u) {
        acc[0][q4*4+u] += kw0*vv[u];
        acc[1][q4*4+u] += kw1*vv[u];
        acc[2][q4*4+u] += kw2*vv[u];
        acc[3][q4*4+u] += kw3*vv[u];
      }
    }
    powv[0]*=lam4[0]; powv[1]*=lam4[1]; powv[2]*=lam4[2]; powv[3]*=lam4[3];
  }
  float* aug = Aug + ((size_t)c*16 + bh)*AUGSZ;
  #pragma unroll
  for (int jj=0; jj<16; ++jj) {
    int j = j0 + jj;
    float4 wv = make_float4(acc[0][jj], acc[1][jj], acc[2][jj], acc[3][jj]);
    *(float4*)&aug[(size_t)j*Dd + i0] = wv;
  }
  if (jg == 0)
    *(float4*)&aug[(size_t)Dd*Dd + i0] = make_float4(zacc[0],zacc[1],zacc[2],zacc[3]);
}

// ---------------- Phase B: inter-chunk prefix scan ----------------
__global__ __launch_bounds__(256) void combine_kernel(float* __restrict__ Aug,
    const float* __restrict__ td)
{
  int idx = blockIdx.x*256 + threadIdx.x;
  if (idx >= AUGSZ) return;
  int bh = blockIdx.y; int h = bh & 3;
  int i = idx & (Dd-1);
  float lamL = expf(-expf(td[h*Dd + i]) * (float)CL);
  float* p = Aug + (size_t)bh*AUGSZ + idx;
  float prev = 0.f;
  for (int c = 0; c < NC; ++c) {
    float val = p[(size_t)c*AUGSTRIDE];
    p[(size_t)c*AUGSTRIDE] = prev;
    prev = lamL*prev + val;
  }
}

// ---------------- Phase C: per-chunk scan; fused gatt = g*S/Z -> blocked bf16 ------
__global__ __launch_bounds__(256, 2) void scan_out_kernel(const float* __restrict__ q,
    const float* __restrict__ k, const float* __restrict__ v,
    const float* __restrict__ td, const float* __restrict__ Aug,
    const float* __restrict__ gmat, u16* __restrict__ out)
{
  __shared__ float part[4*16*128];
  __shared__ float zpart[4*16];
  int blk = blockIdx.x; int c = blk & (NC-1); int bh = blk >> 5;
  int b = bh >> 2, h = bh & 3;
  int tid = threadIdx.x; int w = tid >> 6, l = tid & 63;
  const size_t base = ((size_t)b*Tt)*Cc + h*Dd;
  const float* augc = Aug + ((size_t)c*16 + bh)*AUGSZ;
  int iq = w*32 + (l & 31);
  float lamv = expf(-expf(td[h*Dd + iq]));
  float lam_s[32];
  #pragma unroll
  for (int ii = 0; ii < 32; ++ii) lam_s[ii] = readlane_f(lamv, ii);

  float A0[32], A1[32];
  {
    const float4* p0 = (const float4*)(augc + (size_t)l*Dd + w*32);
    const float4* p1 = (const float4*)(augc + (size_t)(l+64)*Dd + w*32);
    #pragma unroll
    for (int r = 0; r < 8; ++r) {
      float4 a = p0[r];
      A0[4*r+0]=a.x; A0[4*r+1]=a.y; A0[4*r+2]=a.z; A0[4*r+3]=a.w;
      float4 bb = p1[r];
      A1[4*r+0]=bb.x; A1[4*r+1]=bb.y; A1[4*r+2]=bb.z; A1[4*r+3]=bb.w;
    }
  }
  float z = 0.f;
  if (l < 32) z = augc[(size_t)Dd*Dd + w*32 + l];

  int t0 = c*CL;
  const float* qk_ptr = (l < 32) ? q : k;
  size_t pbase = base + (size_t)t0*Cc;
  float qk = qk_ptr[pbase + iq];
  float v0 = v[pbase + l];
  float v1 = v[pbase + l + 64];

  #pragma unroll
  for (int half = 0; half < 2; ++half) {
    for (int tl = 0; tl < 16; ++tl) {
      int t = half*16 + tl;
      float qk_c = qk, v0c = v0, v1c = v1;
      if (t + 1 < CL) {
        size_t nb = pbase + (size_t)(t+1)*Cc;
        qk = qk_ptr[nb + iq];
        v0 = v[nb + l];
        v1 = v[nb + l + 64];
      }
      float s0 = 0.f, s1 = 0.f;
      #pragma unroll
      for (int ii = 0; ii < 32; ++ii) {
        float qs = readlane_f(qk_c, ii);
        float ks = readlane_f(qk_c, 32 + ii);
        A0[ii] = lam_s[ii]*A0[ii] + ks*v0c;
        A1[ii] = lam_s[ii]*A1[ii] + ks*v1c;
        s0 += qs * A0[ii];
        s1 += qs * A1[ii];
      }
      part[(w*16 + tl)*128 + l]      = s0;
      part[(w*16 + tl)*128 + l + 64] = s1;
      float kme = __shfl(qk_c, (l & 31) + 32);
      float p = 0.f;
      if (l < 32) { z = lamv*z + kme; p = qk_c * z; }
      #pragma unroll
      for (int off = 16; off > 0; off >>= 1) p += __shfl_down(p, off);
      if (l == 0) zpart[w*16 + tl] = p;
    }
    __syncthreads();
    #pragma unroll
    for (int r = 0; r < 8; ++r) {
      int lin = r*256 + tid; int tt = lin >> 7; int j = lin & 127;
      float sv = part[tt*128 + j] + part[(16+tt)*128 + j]
               + part[(32+tt)*128 + j] + part[(48+tt)*128 + j];
      float zv = zpart[tt] + zpart[16+tt] + zpart[32+tt] + zpart[48+tt];
      int m = b*Tt + t0 + half*16 + tt;
      int cc = h*Dd + j;
      float gv = gmat[(size_t)m*Cc + cc];
      out[((size_t)(cc >> 3) * Mrows + m) * 8 + (cc & 7)] = f2bf(gv * sv / zv);
    }
    __syncthreads();
  }
}

extern "C" void kernel_launch(void* const* d_in, const int* in_sizes, int n_in,
                              void* d_out, int out_size, void* d_ws, size_t ws_size,
                              hipStream_t stream) {
  const float* x    = (const float*)d_in[0];
  const float* ln1g = (const float*)d_in[1];
  const float* ln1b = (const float*)d_in[2];
  const float* ln2g = (const float*)d_in[3];
  const float* ln2b = (const float*)d_in[4];
  const float* td   = (const float*)d_in[5];
  const float* tmq  = (const float*)d_in[6];
  const float* tmk  = (const float*)d_in[7];
  const float* tmv  = (const float*)d_in[8];
  const float* tmg  = (const float*)d_in[9];
  const float* Wq   = (const float*)d_in[10];
  const float* Wk   = (const float*)d_in[11];
  const float* Wv   = (const float*)d_in[12];
  const float* Wg   = (const float*)d_in[13];
  const float* Wo   = (const float*)d_in[14];
  const float* rsc  = (const float*)d_in[15];
  const float* W1   = (const float*)d_in[16];
  const float* W2   = (const float*)d_in[17];
  float* ws = (float*)d_ws;
  const size_t E = (size_t)Mrows*Cc;           // 2,097,152 floats
  float* s0 = ws;          // h -> q -> W2 partial0
  float* s1 = ws + E;      // k -> W2 p1
  float* s2 = ws + 2*E;    // v -> Wo p0 -> W2 p2
  float* s3 = ws + 3*E;    // g -> Wo p1 -> W2 p3
  float* x1 = ws + 4*E;    // x + att
  u16* xqb = (u16*)(ws + 5*E);             // E u16 each, contiguous x4
  u16* xkb = xqb + E;
  u16* xvb = xkb + E;
  u16* xgb = xvb + E;
  float* Aug = ws + 7*E;                   // 8,454,144 floats; reused as midb
  u16* midb = (u16*)Aug;                   // 4096*2048 u16 = 16.8MB <= 33.8MB
  float* wreg = ws + 7*E + (size_t)NC*16*AUGSZ;
  u16* Wqb = (u16*)wreg;                   // 5 x 262144 u16, contiguous
  u16* W1b = Wqb + 5*262144;               // 1,048,576 u16
  u16* W2b = W1b + 1048576;                // 1,048,576 u16
  u16* Wob = Wqb + 4*262144;
  u16* gattb = xqb;                        // reuse (xq dead after qkvg GEMM)
  u16* h2b   = xkb;                        // reuse (xk dead after qkvg GEMM)

  wconv5_kernel<<<640,256,0,stream>>>(Wq, Wk, Wv, Wg, Wo, Wqb);
  wconv_kernel<<<512,256,0,stream>>>(W1, W1b, 512, 11);
  wconv_kernel<<<512,256,0,stream>>>(W2, W2b, 2048, 9);

  ln_kernel<<<Mrows,256,0,stream>>>(x, ln1g, ln1b, s0);
  mix_kernel<<<1024,256,0,stream>>>(s0, tmq,tmk,tmv,tmg, xqb,xkb,xvb,xgb);
  gemm_qkvg<<<dim3(4,32,4),256,0,stream>>>(xqb, Wqb, s0);                  // q,k,v,g
  rmsexp_kernel<<<dim3(Mrows,2),256,0,stream>>>(s0, s1, rsc);              // q,k
  chunk_state_kernel<<<16*NC,256,0,stream>>>(s1, s2, td, Aug);
  combine_kernel<<<dim3((AUGSZ+255)/256,16),256,0,stream>>>(Aug, td);
  scan_out_kernel<<<16*NC,256,0,stream>>>(s0, s1, s2, td, Aug, s3, gattb); // gatt bf16
  gemm_wo<<<dim3(4,32,2),256,0,stream>>>(gattb, Wob, s2);                  // p0,p1 -> s2,s3
  ln2b_kernel<<<Mrows,256,0,stream>>>(x, s2, s3, ln2g, ln2b, x1, h2b);     // x1, h2 bf16
  gemm_w1<<<dim3(16,32),256,0,stream>>>(h2b, W1b, midb);                   // gelu -> midb
  gemm_w2<<<dim3(4,32,4),256,0,stream>>>(midb, W2b, s0);                   // partials s0..s3
  reduce4_kernel<<<2048,256,0,stream>>>(x1, s0, (float*)d_out);
}

// Round 7
// 173.767 us; speedup vs baseline: 9.0232x; 1.1021x over previous
//
#include <hip/hip_runtime.h>
#include <math.h>

#define Bb 4
#define Tt 1024
#define Cc 512
#define Hh 4
#define Dd 128
#define Mrows (Bb*Tt)   // 4096
#define NC 32           // chunks
#define CL 32           // chunk length (NC*CL == Tt)
#define AUGSZ (Dd*(Dd+1))        // 16512 floats per (chunk, bh)
#define AUGSTRIDE (16*AUGSZ)
#define AUGB_CB 18432            // u16 per (c,bh): 16 ig * 144 j * 8

typedef unsigned short u16;
typedef __attribute__((ext_vector_type(8))) short bf16x8;
typedef __attribute__((ext_vector_type(4))) float f32x4;

__device__ __forceinline__ float readlane_f(float v, int lane) {
  return __uint_as_float(__builtin_amdgcn_readlane(__float_as_uint(v), lane));
}
__device__ __forceinline__ u16 f2bf(float f) {
  unsigned u = __float_as_uint(f);
  unsigned r = (u + 0x7fffu + ((u >> 16) & 1u)) >> 16;
  return (u16)r;
}
__device__ __forceinline__ unsigned pack2(float a, float b) {
  return (unsigned)f2bf(a) | ((unsigned)f2bf(b) << 16);
}

// ---------------- LayerNorm (one block per row), fp32 out ----------------
__global__ __launch_bounds__(256) void ln_kernel(const float* __restrict__ x,
    const float* __restrict__ g, const float* __restrict__ bta, float* __restrict__ out)
{
  int row = blockIdx.x, tid = threadIdx.x;
  const float* xr = x + (size_t)row * Cc;
  float v0 = xr[tid], v1 = xr[tid + 256];
  float s = v0 + v1, s2 = v0*v0 + v1*v1;
  #pragma unroll
  for (int off = 32; off > 0; off >>= 1) {
    s  += __shfl_down(s,  off, 64);
    s2 += __shfl_down(s2, off, 64);
  }
  __shared__ float rs[4], rq[4];
  int w = tid >> 6;
  if ((tid & 63) == 0) { rs[w] = s; rq[w] = s2; }
  __syncthreads();
  float S  = rs[0]+rs[1]+rs[2]+rs[3];
  float S2 = rq[0]+rq[1]+rq[2]+rq[3];
  float mean = S * (1.0f/Cc);
  float var  = S2 * (1.0f/Cc) - mean*mean;
  float inv = rsqrtf(var + 1e-5f);
  out[(size_t)row*Cc + tid]       = g[tid]     * (v0-mean)*inv + bta[tid];
  out[(size_t)row*Cc + tid + 256] = g[tid+256] * (v1-mean)*inv + bta[tid+256];
}

// --------- fused: x1 = x + p0 + p1 (Wo split-K partials); h2b = LN(x1) blocked bf16 ---------
__global__ __launch_bounds__(256) void ln2b_kernel(const float* __restrict__ x,
    const float* __restrict__ p0, const float* __restrict__ p1,
    const float* __restrict__ g, const float* __restrict__ bta,
    float* __restrict__ x1, u16* __restrict__ out)
{
  int row = blockIdx.x, tid = threadIdx.x;
  size_t r0 = (size_t)row * Cc + tid, r1 = r0 + 256;
  float v0 = x[r0] + p0[r0] + p1[r0];
  float v1 = x[r1] + p0[r1] + p1[r1];
  x1[r0] = v0; x1[r1] = v1;
  float s = v0 + v1, s2 = v0*v0 + v1*v1;
  #pragma unroll
  for (int off = 32; off > 0; off >>= 1) {
    s  += __shfl_down(s,  off, 64);
    s2 += __shfl_down(s2, off, 64);
  }
  __shared__ float rs[4], rq[4];
  int w = tid >> 6;
  if ((tid & 63) == 0) { rs[w] = s; rq[w] = s2; }
  __syncthreads();
  float S  = rs[0]+rs[1]+rs[2]+rs[3];
  float S2 = rq[0]+rq[1]+rq[2]+rq[3];
  float mean = S * (1.0f/Cc);
  float var  = S2 * (1.0f/Cc) - mean*mean;
  float inv = rsqrtf(var + 1e-5f);
  int c0 = tid, c1 = tid + 256;
  float o0 = g[c0] * (v0-mean)*inv + bta[c0];
  float o1 = g[c1] * (v1-mean)*inv + bta[c1];
  out[((size_t)(c0 >> 3) * Mrows + row) * 8 + (c0 & 7)] = f2bf(o0);
  out[((size_t)(c1 >> 3) * Mrows + row) * 8 + (c1 & 7)] = f2bf(o1);
}

// ---------------- time-shift mix -> blocked bf16 [C/8][M][8] ----------------
__device__ __forceinline__ void mix_one(const float* tm, int c0,
    float4 ha, float4 hb, float4 xa, float4 xb, u16* dst, size_t i8)
{
  float4 ta = *(const float4*)(tm + c0);
  float4 tb = *(const float4*)(tm + c0 + 4);
  uint4 o;
  o.x = pack2(ha.x*ta.x + xa.x*(1.f-ta.x), ha.y*ta.y + xa.y*(1.f-ta.y));
  o.y = pack2(ha.z*ta.z + xa.z*(1.f-ta.z), ha.w*ta.w + xa.w*(1.f-ta.w));
  o.z = pack2(hb.x*tb.x + xb.x*(1.f-tb.x), hb.y*tb.y + xb.y*(1.f-tb.y));
  o.w = pack2(hb.z*tb.z + xb.z*(1.f-tb.z), hb.w*tb.w + xb.w*(1.f-tb.w));
  *(uint4*)(dst + i8) = o;
}

__global__ __launch_bounds__(256) void mix_kernel(const float* __restrict__ h,
    const float* __restrict__ tmq, const float* __restrict__ tmk,
    const float* __restrict__ tmv, const float* __restrict__ tmg,
    u16* __restrict__ xqb, u16* __restrict__ xkb,
    u16* __restrict__ xvb, u16* __restrict__ xgb)
{
  int i = blockIdx.x * 256 + threadIdx.x;     // kg*4096 + m
  int m = i & 4095, c0 = (i >> 12) << 3;
  const float* hp = h + (size_t)m*Cc + c0;
  float4 ha = *(const float4*)hp, hb = *(const float4*)(hp + 4);
  float4 xa = make_float4(0,0,0,0), xb = make_float4(0,0,0,0);
  if (m & 1023) { xa = *(const float4*)(hp - Cc); xb = *(const float4*)(hp - Cc + 4); }
  size_t i8 = (size_t)i * 8;
  mix_one(tmq, c0, ha, hb, xa, xb, xqb, i8);
  mix_one(tmk, c0, ha, hb, xa, xb, xkb, i8);
  mix_one(tmv, c0, ha, hb, xa, xb, xvb, i8);
  mix_one(tmg, c0, ha, hb, xa, xb, xgb, i8);
}

// ---------------- weight fp32 -> blocked bf16 ----------------
__global__ __launch_bounds__(256) void wconv_kernel(const float* __restrict__ src,
    u16* __restrict__ out, int K, int nshift)
{
  int i = blockIdx.x * 256 + threadIdx.x;       // kg*N + n
  int n = i & ((1 << nshift) - 1), kg = i >> nshift;
  const float* p = src + (size_t)n * K + kg * 8;
  float4 a = *(const float4*)p, b = *(const float4*)(p + 4);
  uint4 o;
  o.x = pack2(a.x, a.y); o.y = pack2(a.z, a.w);
  o.z = pack2(b.x, b.y); o.w = pack2(b.z, b.w);
  *(uint4*)(out + (size_t)i * 8) = o;
}

__global__ __launch_bounds__(256) void wconv5_kernel(const float* __restrict__ s0,
    const float* __restrict__ s1, const float* __restrict__ s2,
    const float* __restrict__ s3, const float* __restrict__ s4,
    u16* __restrict__ out)
{
  int wsel = blockIdx.x >> 7;
  const float* src = wsel == 0 ? s0 : wsel == 1 ? s1 : wsel == 2 ? s2 : wsel == 3 ? s3 : s4;
  int i = (blockIdx.x & 127) * 256 + threadIdx.x;  // kg*512 + n
  int n = i & 511, kg = i >> 9;
  const float* p = src + (size_t)n * 512 + kg * 8;
  float4 a = *(const float4*)p, b = *(const float4*)(p + 4);
  uint4 o;
  o.x = pack2(a.x, a.y); o.y = pack2(a.z, a.w);
  o.z = pack2(b.x, b.y); o.w = pack2(b.z, b.w);
  *(uint4*)(out + (size_t)wsel * 262144 + (size_t)i * 8) = o;
}

// ---------------- bf16 MFMA GEMM core (templated dims) ----------------
template<int MR, int NR, int KR>
__device__ __forceinline__ void gemm_core(const u16* __restrict__ A,
    const u16* __restrict__ W, const float* __restrict__ res,
    float* __restrict__ outf, u16* __restrict__ outb, int act,
    int m0, int n0, u16* Asm, u16* Bsm)   // each [4][4096]
{
  const int tid = threadIdx.x, w = tid >> 6, l = tid & 63;
  const int wr = w >> 1, wc = w & 1;
  f32x4 acc[4][4];
  #pragma unroll
  for (int i = 0; i < 4; ++i)
    #pragma unroll
    for (int j = 0; j < 4; ++j) acc[i][j] = (f32x4){0.f,0.f,0.f,0.f};
  const int kgl = l >> 4, rl = l & 15;
  const int q = w * 4;  // wave's load-slot base

  #define STAGE(KT, BUF) do {                                               \
    _Pragma("unroll")                                                       \
    for (int ii = 0; ii < 4; ++ii) {                                        \
      int qq = q + ii;                                                      \
      int isB = qq >> 3, idx = qq & 7, kg = idx >> 1, hf = idx & 1;         \
      const u16* src = isB                                                  \
        ? W + ((size_t)((KT)*4 + kg) * NR + n0 + hf*64 + l) * 8             \
        : A + ((size_t)((KT)*4 + kg) * MR + m0 + hf*64 + l) * 8;            \
      u16* dst = (isB ? Bsm : Asm) + (BUF)*4096 + (kg * 128 + hf * 64) * 8; \
      __builtin_amdgcn_global_load_lds(                                     \
          (const __attribute__((address_space(1))) void*)src,               \
          (__attribute__((address_space(3))) void*)dst, 16, 0, 0);          \
    }                                                                       \
  } while (0)

  constexpr int nk = KR >> 5;
  STAGE(0, 0); STAGE(1, 1); STAGE(2, 2);
  for (int kt = 0; kt < nk; ++kt) {
    const int cur = kt & 3;
    if (kt < nk - 2)       asm volatile("s_waitcnt vmcnt(8)" ::: "memory");
    else if (kt == nk - 2) asm volatile("s_waitcnt vmcnt(4)" ::: "memory");
    else                   asm volatile("s_waitcnt vmcnt(0)" ::: "memory");
    __builtin_amdgcn_s_barrier();
    bf16x8 af[4], bfr[4];
    #pragma unroll
    for (int f = 0; f < 4; ++f)
      af[f] = *(const bf16x8*)&Asm[cur*4096 + (kgl*128 + wr*64 + f*16 + rl) * 8];
    #pragma unroll
    for (int f = 0; f < 4; ++f)
      bfr[f] = *(const bf16x8*)&Bsm[cur*4096 + (kgl*128 + wc*64 + f*16 + rl) * 8];
    if (kt + 3 < nk) STAGE(kt + 3, (kt + 3) & 3);
    __builtin_amdgcn_s_setprio(1);
    #pragma unroll
    for (int i = 0; i < 4; ++i)
      #pragma unroll
      for (int j = 0; j < 4; ++j)
        acc[i][j] = __builtin_amdgcn_mfma_f32_16x16x32_bf16(af[i], bfr[j], acc[i][j], 0, 0, 0);
    __builtin_amdgcn_s_setprio(0);
  }
  #undef STAGE

  const int rbase = (l >> 4) * 4, cn = l & 15;
  #pragma unroll
  for (int i = 0; i < 4; ++i) {
    #pragma unroll
    for (int j = 0; j < 4; ++j) {
      #pragma unroll
      for (int r = 0; r < 4; ++r) {
        int m = m0 + wr*64 + i*16 + rbase + r;
        int n = n0 + wc*64 + j*16 + cn;
        float vv = acc[i][j][r];
        if (res) vv += res[(size_t)m * NR + n];
        if (act == 1) vv = 0.5f*vv*(1.f + erff(vv * 0.70710678118f));
        else if (act == 2) vv = 1.f/(1.f + expf(-vv));
        if (outb) outb[((size_t)(n >> 3) * MR + m) * 8 + (n & 7)] = f2bf(vv);
        else outf[(size_t)m * NR + n] = vv;
      }
    }
  }
}

__global__ __launch_bounds__(256) void gemm_qkvg(const u16* __restrict__ xall,
    const u16* __restrict__ Wall, float* __restrict__ outall)
{
  __shared__ __align__(16) u16 Asm[4*4096];
  __shared__ __align__(16) u16 Bsm[4*4096];
  int z = blockIdx.z;
  const size_t E = (size_t)Mrows * Cc;
  gemm_core<Mrows,512,512>(xall + z*E, Wall + (size_t)z*262144, nullptr,
            outall + z*E, nullptr, z == 3 ? 2 : 0,
            blockIdx.y * 128, blockIdx.x * 128, Asm, Bsm);
}

__global__ __launch_bounds__(256) void gemm_wo(const u16* __restrict__ A,
    const u16* __restrict__ W, float* __restrict__ pbuf)
{
  __shared__ __align__(16) u16 Asm[4*4096];
  __shared__ __align__(16) u16 Bsm[4*4096];
  int z = blockIdx.z;
  const size_t E = (size_t)Mrows * Cc;
  gemm_core<Mrows,512,256>(A + (size_t)z*32*Mrows*8, W + (size_t)z*32*512*8, nullptr,
            pbuf + z*E, nullptr, 0, blockIdx.y * 128, blockIdx.x * 128, Asm, Bsm);
}

__global__ __launch_bounds__(256) void gemm_w1(const u16* __restrict__ A,
    const u16* __restrict__ W, u16* __restrict__ outb)
{
  __shared__ __align__(16) u16 Asm[4*4096];
  __shared__ __align__(16) u16 Bsm[4*4096];
  gemm_core<Mrows,2048,512>(A, W, nullptr, nullptr, outb, 1,
            blockIdx.y * 128, blockIdx.x * 128, Asm, Bsm);
}

__global__ __launch_bounds__(256) void gemm_w2(const u16* __restrict__ A,
    const u16* __restrict__ W, float* __restrict__ pbuf)
{
  __shared__ __align__(16) u16 Asm[4*4096];
  __shared__ __align__(16) u16 Bsm[4*4096];
  int z = blockIdx.z;
  const size_t E = (size_t)Mrows * Cc;
  gemm_core<Mrows,512,512>(A + (size_t)z*64*Mrows*8, W + (size_t)z*64*512*8, nullptr,
            pbuf + z*E, nullptr, 0, blockIdx.y * 128, blockIdx.x * 128, Asm, Bsm);
}

// ---------------- out = x1 + p0+p1+p2+p3 ----------------
__global__ __launch_bounds__(256) void reduce4_kernel(const float* __restrict__ x1,
    const float* __restrict__ p, float* __restrict__ out)
{
  const size_t E = (size_t)Mrows * Cc;
  size_t f = ((size_t)blockIdx.x * 256 + threadIdx.x) * 4;
  float4 a = *(const float4*)(x1 + f);
  float4 q0 = *(const float4*)(p + f);
  float4 q1 = *(const float4*)(p + E + f);
  float4 q2 = *(const float4*)(p + 2*E + f);
  float4 q3 = *(const float4*)(p + 3*E + f);
  float4 o;
  o.x = a.x + q0.x + q1.x + q2.x + q3.x;
  o.y = a.y + q0.y + q1.y + q2.y + q3.y;
  o.z = a.z + q0.z + q1.z + q2.z + q3.z;
  o.w = a.w + q0.w + q1.w + q2.w + q3.w;
  *(float4*)(out + f) = o;
}

// ---------------- exp(rmsnorm(x)) in place (q and k in one dispatch) ----------------
__global__ __launch_bounds__(256) void rmsexp_kernel(float* __restrict__ qm,
    float* __restrict__ km, const float* __restrict__ scale)
{
  int row = blockIdx.x, tid = threadIdx.x;
  float* xr = (blockIdx.y ? km : qm) + (size_t)row * Cc;
  float v0 = xr[tid], v1 = xr[tid+256];
  float s2 = v0*v0 + v1*v1;
  #pragma unroll
  for (int off = 32; off > 0; off >>= 1) s2 += __shfl_down(s2, off, 64);
  __shared__ float rq[4];
  int w = tid >> 6;
  if ((tid & 63) == 0) rq[w] = s2;
  __syncthreads();
  float S2 = rq[0]+rq[1]+rq[2]+rq[3];
  float norm = sqrtf(S2) * 0.044194173824159216f;  // 1/sqrt(512)
  float r = 1.f / (norm + 1e-8f);
  xr[tid]     = expf(scale[tid]     * v0 * r);
  xr[tid+256] = expf(scale[tid+256] * v1 * r);
}

// ---------------- Phase A: chunk-local end state (incl. z as col 128) ----------------
__global__ __launch_bounds__(256) void chunk_state_kernel(const float* __restrict__ k,
    const float* __restrict__ v, const float* __restrict__ td, float* __restrict__ Aug)
{
  __shared__ float k_lds[CL][Dd];
  __shared__ float v_lds[CL][Dd];
  int blk = blockIdx.x; int c = blk & (NC-1); int bh = blk >> 5;
  int b = bh >> 2, h = bh & 3;
  int tid = threadIdx.x;
  size_t base = ((size_t)b*Tt + (size_t)c*CL)*Cc + h*Dd;
  #pragma unroll
  for (int r = 0; r < 4; ++r) {
    int idx4 = r*256 + tid;
    int s = idx4 >> 5; int i4 = (idx4 & 31) << 2;
    *(float4*)&k_lds[s][i4] = *(const float4*)&k[base + (size_t)s*Cc + i4];
    *(float4*)&v_lds[s][i4] = *(const float4*)&v[base + (size_t)s*Cc + i4];
  }
  __syncthreads();
  int iq = tid >> 3; int i0 = iq << 2;
  int jg = tid & 7;  int j0 = jg << 4;
  float lam4[4], powv[4], zacc[4];
  #pragma unroll
  for (int ci=0; ci<4; ++ci) {
    lam4[ci] = expf(-expf(td[h*Dd + i0 + ci]));
    powv[ci] = 1.f; zacc[ci] = 0.f;
  }
  float acc[4][16];
  #pragma unroll
  for (int ci=0; ci<4; ++ci)
    #pragma unroll
    for (int jj=0; jj<16; ++jj) acc[ci][jj] = 0.f;

  for (int s = CL-1; s >= 0; --s) {
    float4 k4 = *(const float4*)&k_lds[s][i0];
    float kw0 = powv[0]*k4.x, kw1 = powv[1]*k4.y, kw2 = powv[2]*k4.z, kw3 = powv[3]*k4.w;
    zacc[0]+=kw0; zacc[1]+=kw1; zacc[2]+=kw2; zacc[3]+=kw3;
    #pragma unroll
    for (int q4 = 0; q4 < 4; ++q4) {
      float4 v4 = *(const float4*)&v_lds[s][j0 + q4*4];
      float vv[4] = {v4.x, v4.y, v4.z, v4.w};
      #pragma unroll
      for (int u=0; u<4; ++u) {
        acc[0][q4*4+u] += kw0*vv[u];
        acc[1][q4*4+u] += kw1*vv[u];
        acc[2][q4*4+u] += kw2*vv[u];
        acc[3][q4*4+u] += kw3*vv[u];
      }
    }
    powv[0]*=lam4[0]; powv[1]*=lam4[1]; powv[2]*=lam4[2]; powv[3]*=lam4[3];
  }
  float* aug = Aug + ((size_t)c*16 + bh)*AUGSZ;
  #pragma unroll
  for (int jj=0; jj<16; ++jj) {
    int j = j0 + jj;
    float4 wv = make_float4(acc[0][jj], acc[1][jj], acc[2][jj], acc[3][jj]);
    *(float4*)&aug[(size_t)j*Dd + i0] = wv;
  }
  if (jg == 0)
    *(float4*)&aug[(size_t)Dd*Dd + i0] = make_float4(zacc[0],zacc[1],zacc[2],zacc[3]);
}

// ---------------- Phase B: inter-chunk prefix scan -> bf16 blocked Augb ----------------
// Augb per (c,bh): [ig=i/8 (16)][j (144)][i&7 (8)] bf16, j in [129,144) zeroed.
__global__ __launch_bounds__(256) void combine_kernel(const float* __restrict__ Aug,
    const float* __restrict__ td, u16* __restrict__ Augb)
{
  int idx = blockIdx.x*256 + threadIdx.x;   // [0, 144*128)
  int bh = blockIdx.y; int h = bh & 3;
  int j = idx >> 7, i = idx & 127;
  size_t aoff = (size_t)(i >> 3) * 1152 + (size_t)j * 8 + (i & 7);
  if (j >= 129) {
    for (int c = 0; c < NC; ++c)
      Augb[((size_t)c*16 + bh)*AUGB_CB + aoff] = 0;
    return;
  }
  float lamL = expf(-expf(td[h*Dd + i]) * (float)CL);
  const float* p = Aug + (size_t)bh*AUGSZ + (size_t)j*Dd + i;
  float prev = 0.f;
  for (int c = 0; c < NC; ++c) {
    float val = p[(size_t)c*AUGSTRIDE];
    Augb[((size_t)c*16 + bh)*AUGB_CB + aoff] = f2bf(prev);
    prev = lamL*prev + val;
  }
}

// ---------------- Phase C: chunked MFMA scan; fused gatt = g*S/Z -> blocked bf16 ----
// S[t] = q~_t @ A_init + (P @ V_aug);  q~ = q*lam^(t+1); P[t][s] = sum_i q k lam^(t-s)
// Z = column 128 (z col of A_init + ones col of V).
__global__ __launch_bounds__(256, 2) void scan_mfma_kernel(
    const float* __restrict__ q, const float* __restrict__ k,
    const float* __restrict__ v, const float* __restrict__ td,
    const u16* __restrict__ Augb, const float* __restrict__ gmat,
    u16* __restrict__ out)
{
  __shared__ float k_lds[32*192];     // [s][is*24 + e], 24KB (slice stride 24 to spread banks)
  __shared__ u16  qfrag[32*128];      // [t][(k8 ^ (t&7))*8 + e]
  __shared__ u16  vfrag[4*1152];      // [s8][j(144)][s&7]
  __shared__ float P32[32*33];
  __shared__ u16  pfrag[32*32];       // [t][(s8 ^ (t&3))*8 + (s&7)]
  __shared__ float lam_lds[128];
  __shared__ float zbuf[32];

  const int tid = threadIdx.x;
  const int blk = blockIdx.x; const int c = blk & 31, bh = blk >> 5;
  const int b = bh >> 2, h = bh & 3;
  const int w = tid >> 6, l = tid & 63;
  const int t = (w << 3) + (l >> 3);    // row 0..31 (s-role for k/v loaders)
  const int is = l & 7;                 // i-slice of 16

  if (tid < 128) lam_lds[tid] = expf(-expf(td[h*Dd + tid]));

  const size_t rowbase = ((size_t)(b*Tt + c*CL + t))*Cc + h*Dd + is*16;

  // q: global -> regs (kept for P phase), build q~ bf16 fragments
  float qv[16];
  {
    #pragma unroll
    for (int c4 = 0; c4 < 4; ++c4) {
      float4 q4 = *(const float4*)(q + rowbase + c4*4);
      qv[c4*4+0]=q4.x; qv[c4*4+1]=q4.y; qv[c4*4+2]=q4.z; qv[c4*4+3]=q4.w;
    }
    float lt = (float)(t + 1);
    u16 qt[16];
    #pragma unroll
    for (int e = 0; e < 16; ++e) {
      float el2 = -expf(td[h*Dd + is*16 + e]) * 1.4426950408889634f;
      qt[e] = f2bf(qv[e] * exp2f(el2 * lt));
    }
    #pragma unroll
    for (int hf = 0; hf < 2; ++hf) {
      int k8 = is*2 + hf;
      uint4 pk;
      pk.x = (unsigned)qt[hf*8+0] | ((unsigned)qt[hf*8+1]<<16);
      pk.y = (unsigned)qt[hf*8+2] | ((unsigned)qt[hf*8+3]<<16);
      pk.z = (unsigned)qt[hf*8+4] | ((unsigned)qt[hf*8+5]<<16);
      pk.w = (unsigned)qt[hf*8+6] | ((unsigned)qt[hf*8+7]<<16);
      *(uint4*)&qfrag[t*128 + ((k8 ^ (t&7))<<3)] = pk;
    }
  }
  // k -> LDS f32
  #pragma unroll
  for (int c4 = 0; c4 < 4; ++c4)
    *(float4*)&k_lds[t*192 + is*24 + c4*4] = *(const float4*)(k + rowbase + c4*4);
  // v -> vfrag bf16 (B-fragment blocked layout)
  #pragma unroll
  for (int c4 = 0; c4 < 4; ++c4) {
    float4 v4 = *(const float4*)(v + rowbase + c4*4);
    int j0 = is*16 + c4*4;
    vfrag[(t>>3)*1152 + (j0+0)*8 + (t&7)] = f2bf(v4.x);
    vfrag[(t>>3)*1152 + (j0+1)*8 + (t&7)] = f2bf(v4.y);
    vfrag[(t>>3)*1152 + (j0+2)*8 + (t&7)] = f2bf(v4.z);
    vfrag[(t>>3)*1152 + (j0+3)*8 + (t&7)] = f2bf(v4.w);
  }
  if (tid < 32) vfrag[(tid>>3)*1152 + 128*8 + (tid&7)] = 0x3F80;  // ones column
  if (tid < 240) {  // zero-pad j in [129,144): 480 entries
    #pragma unroll
    for (int u = 0; u < 2; ++u) {
      int e = tid*2 + u;
      int ig = e / 120, rem = e % 120;
      vfrag[ig*1152 + (129 + rem/8)*8 + (rem&7)] = 0;
    }
  }
  __syncthreads();

  // ---- P phase: fp32, incremental lambda^d running product ----
  {
    float lamr[16], wrun[16];
    #pragma unroll
    for (int e4 = 0; e4 < 4; ++e4) {
      float4 l4 = *(const float4*)&lam_lds[is*16 + e4*4];
      lamr[e4*4+0]=l4.x; lamr[e4*4+1]=l4.y; lamr[e4*4+2]=l4.z; lamr[e4*4+3]=l4.w;
    }
    #pragma unroll
    for (int e = 0; e < 16; ++e) wrun[e] = 1.f;
    const int smax = (w << 3) + 7;
    for (int s = smax; s >= 0; --s) {
      float dot = 0.f;
      #pragma unroll
      for (int c4 = 0; c4 < 4; ++c4) {
        float4 k4 = *(const float4*)&k_lds[s*192 + is*24 + c4*4];
        dot = fmaf(qv[c4*4+0], k4.x*wrun[c4*4+0], dot);
        dot = fmaf(qv[c4*4+1], k4.y*wrun[c4*4+1], dot);
        dot = fmaf(qv[c4*4+2], k4.z*wrun[c4*4+2], dot);
        dot = fmaf(qv[c4*4+3], k4.w*wrun[c4*4+3], dot);
      }
      dot += __shfl_xor(dot, 1);
      dot += __shfl_xor(dot, 2);
      dot += __shfl_xor(dot, 4);
      bool act = (s <= t);
      if (act && is == 0) P32[t*33 + s] = dot;
      if (act) {
        #pragma unroll
        for (int e = 0; e < 16; ++e) wrun[e] *= lamr[e];
      }
    }
  }
  __syncthreads();
  // pfrag build (mask s>t to 0)
  {
    int tt = tid >> 3, s0 = (tid & 7) * 4;
    #pragma unroll
    for (int ss = 0; ss < 4; ++ss) {
      int s = s0 + ss;
      float val = (s <= tt) ? P32[tt*33 + s] : 0.f;
      pfrag[tt*32 + (((s>>3) ^ (tt&3))<<3) + (s&7)] = f2bf(val);
    }
  }
  __syncthreads();

  // ---- MFMA: acc = q~ @ A_init + P @ V_aug ----
  const int tau = w >> 1;
  const int jt0 = (w & 1) ? 5 : 0;
  const int njt = (w & 1) ? 4 : 5;
  const int rl = l & 15, kg = l >> 4;
  const int trow = tau*16 + rl;
  const u16* augb_base = Augb + ((size_t)c*16 + bh)*AUGB_CB;

  bf16x8 aq[4];
  #pragma unroll
  for (int kk = 0; kk < 4; ++kk)
    aq[kk] = *(const bf16x8*)&qfrag[trow*128 + ((((kk<<2)+kg) ^ (trow&7))<<3)];
  bf16x8 ap = *(const bf16x8*)&pfrag[trow*32 + ((kg ^ (trow&3))<<3)];

  f32x4 acc[5];
  #pragma unroll
  for (int u = 0; u < 5; ++u) acc[u] = (f32x4){0.f,0.f,0.f,0.f};

  #pragma unroll
  for (int u = 0; u < 5; ++u) {
    if (u < njt) {
      int jt = jt0 + u;
      #pragma unroll
      for (int kk = 0; kk < 4; ++kk) {
        bf16x8 bfr = *(const bf16x8*)&augb_base[(size_t)(((kk<<2)+kg)*1152 + (jt*16 + rl)*8)];
        acc[u] = __builtin_amdgcn_mfma_f32_16x16x32_bf16(aq[kk], bfr, acc[u], 0, 0, 0);
      }
      bf16x8 bv = *(const bf16x8*)&vfrag[kg*1152 + (jt*16 + rl)*8];
      acc[u] = __builtin_amdgcn_mfma_f32_16x16x32_bf16(ap, bv, acc[u], 0, 0, 0);
    }
  }
  // Z staging: odd waves own jt=8 (u=3); C-frag col0 lanes hold Z rows
  if ((w & 1) && rl == 0) {
    #pragma unroll
    for (int r = 0; r < 4; ++r) zbuf[tau*16 + kg*4 + r] = acc[3][r];
  }
  __syncthreads();

  // epilogue: out = bf16(g * S / Z), blocked [cc/8][m][8]
  const int nout = (w & 1) ? 3 : 5;
  #pragma unroll
  for (int u = 0; u < 5; ++u) {
    if (u < nout) {
      int jt = jt0 + u;
      int cc = h*Dd + jt*16 + rl;
      #pragma unroll
      for (int r = 0; r < 4; ++r) {
        int tr = tau*16 + kg*4 + r;
        int m = b*Tt + c*CL + tr;
        float zv = zbuf[tr];
        float gv = gmat[(size_t)m*Cc + cc];
        out[((size_t)(cc >> 3) * Mrows + m) * 8 + (cc & 7)] = f2bf(gv * acc[u][r] / zv);
      }
    }
  }
}

extern "C" void kernel_launch(void* const* d_in, const int* in_sizes, int n_in,
                              void* d_out, int out_size, void* d_ws, size_t ws_size,
                              hipStream_t stream) {
  const float* x    = (const float*)d_in[0];
  const float* ln1g = (const float*)d_in[1];
  const float* ln1b = (const float*)d_in[2];
  const float* ln2g = (const float*)d_in[3];
  const float* ln2b = (const float*)d_in[4];
  const float* td   = (const float*)d_in[5];
  const float* tmq  = (const float*)d_in[6];
  const float* tmk  = (const float*)d_in[7];
  const float* tmv  = (const float*)d_in[8];
  const float* tmg  = (const float*)d_in[9];
  const float* Wq   = (const float*)d_in[10];
  const float* Wk   = (const float*)d_in[11];
  const float* Wv   = (const float*)d_in[12];
  const float* Wg   = (const float*)d_in[13];
  const float* Wo   = (const float*)d_in[14];
  const float* rsc  = (const float*)d_in[15];
  const float* W1   = (const float*)d_in[16];
  const float* W2   = (const float*)d_in[17];
  float* ws = (float*)d_ws;
  const size_t E = (size_t)Mrows*Cc;           // 2,097,152 floats
  float* s0 = ws;          // h -> q -> W2 partial0
  float* s1 = ws + E;      // k -> W2 p1
  float* s2 = ws + 2*E;    // v -> Wo p0 -> W2 p2
  float* s3 = ws + 3*E;    // g -> Wo p1 -> W2 p3
  float* x1 = ws + 4*E;    // x + att
  u16* xqb = (u16*)(ws + 5*E);             // E u16 each, contiguous x4
  u16* xkb = xqb + E;
  u16* xvb = xkb + E;
  u16* xgb = xvb + E;
  float* Aug = ws + 7*E;                   // 8,454,144 floats; reused as midb
  u16* midb = (u16*)Aug;                   // 4096*2048 u16 = 16.8MB
  float* wreg = ws + 7*E + (size_t)NC*16*AUGSZ;
  u16* Wqb = (u16*)wreg;                   // 5 x 262144 u16, contiguous
  u16* W1b = Wqb + 5*262144;               // 1,048,576 u16
  u16* W2b = W1b + 1048576;                // 1,048,576 u16
  u16* Wob = Wqb + 4*262144;
  u16* Augb = W2b + 1048576;               // NC*16*AUGB_CB = 9,437,184 u16 (18.9MB)
  u16* gattb = xqb;                        // reuse (xq dead after qkvg GEMM)
  u16* h2b   = xkb;                        // reuse (xk dead after qkvg GEMM)

  wconv5_kernel<<<640,256,0,stream>>>(Wq, Wk, Wv, Wg, Wo, Wqb);
  wconv_kernel<<<512,256,0,stream>>>(W1, W1b, 512, 11);
  wconv_kernel<<<512,256,0,stream>>>(W2, W2b, 2048, 9);

  ln_kernel<<<Mrows,256,0,stream>>>(x, ln1g, ln1b, s0);
  mix_kernel<<<1024,256,0,stream>>>(s0, tmq,tmk,tmv,tmg, xqb,xkb,xvb,xgb);
  gemm_qkvg<<<dim3(4,32,4),256,0,stream>>>(xqb, Wqb, s0);                  // q,k,v,g
  rmsexp_kernel<<<dim3(Mrows,2),256,0,stream>>>(s0, s1, rsc);              // q,k
  chunk_state_kernel<<<16*NC,256,0,stream>>>(s1, s2, td, Aug);
  combine_kernel<<<dim3(72,16),256,0,stream>>>(Aug, td, Augb);             // -> bf16 frags
  scan_mfma_kernel<<<16*NC,256,0,stream>>>(s0, s1, s2, td, Augb, s3, gattb);
  gemm_wo<<<dim3(4,32,2),256,0,stream>>>(gattb, Wob, s2);                  // p0,p1 -> s2,s3
  ln2b_kernel<<<Mrows,256,0,stream>>>(x, s2, s3, ln2g, ln2b, x1, h2b);     // x1, h2 bf16
  gemm_w1<<<dim3(16,32),256,0,stream>>>(h2b, W1b, midb);                   // gelu -> midb
  gemm_w2<<<dim3(4,32,4),256,0,stream>>>(midb, W2b, s0);                   // partials s0..s3
  reduce4_kernel<<<2048,256,0,stream>>>(x1, s0, (float*)d_out);
}

// Round 8
// 168.261 us; speedup vs baseline: 9.3185x; 1.0327x over previous
//
#include <hip/hip_runtime.h>
#include <math.h>

#define Bb 4
#define Tt 1024
#define Cc 512
#define Hh 4
#define Dd 128
#define Mrows (Bb*Tt)   // 4096
#define NC 32           // chunks
#define CL 32           // chunk length (NC*CL == Tt)
#define AUGSZ (Dd*(Dd+1))        // 16512 floats per (chunk, bh)
#define AUGSTRIDE (16*AUGSZ)
#define AUGB_CB 18432            // u16 per (c,bh): 16 ig * 144 j * 8

typedef unsigned short u16;
typedef __attribute__((ext_vector_type(8))) short bf16x8;
typedef __attribute__((ext_vector_type(4))) float f32x4;

__device__ __forceinline__ float readlane_f(float v, int lane) {
  return __uint_as_float(__builtin_amdgcn_readlane(__float_as_uint(v), lane));
}
__device__ __forceinline__ u16 f2bf(float f) {
  unsigned u = __float_as_uint(f);
  unsigned r = (u + 0x7fffu + ((u >> 16) & 1u)) >> 16;
  return (u16)r;
}
__device__ __forceinline__ unsigned pack2(float a, float b) {
  return (unsigned)f2bf(a) | ((unsigned)f2bf(b) << 16);
}

// ---------------- LayerNorm (one block per row), fp32 out ----------------
__global__ __launch_bounds__(256) void ln_kernel(const float* __restrict__ x,
    const float* __restrict__ g, const float* __restrict__ bta, float* __restrict__ out)
{
  int row = blockIdx.x, tid = threadIdx.x;
  const float* xr = x + (size_t)row * Cc;
  float v0 = xr[tid], v1 = xr[tid + 256];
  float s = v0 + v1, s2 = v0*v0 + v1*v1;
  #pragma unroll
  for (int off = 32; off > 0; off >>= 1) {
    s  += __shfl_down(s,  off, 64);
    s2 += __shfl_down(s2, off, 64);
  }
  __shared__ float rs[4], rq[4];
  int w = tid >> 6;
  if ((tid & 63) == 0) { rs[w] = s; rq[w] = s2; }
  __syncthreads();
  float S  = rs[0]+rs[1]+rs[2]+rs[3];
  float S2 = rq[0]+rq[1]+rq[2]+rq[3];
  float mean = S * (1.0f/Cc);
  float var  = S2 * (1.0f/Cc) - mean*mean;
  float inv = rsqrtf(var + 1e-5f);
  out[(size_t)row*Cc + tid]       = g[tid]     * (v0-mean)*inv + bta[tid];
  out[(size_t)row*Cc + tid + 256] = g[tid+256] * (v1-mean)*inv + bta[tid+256];
}

// --------- fused: x1 = x + p0 + p1 (Wo split-K partials); h2b = LN(x1) blocked bf16 ---------
__global__ __launch_bounds__(256) void ln2b_kernel(const float* __restrict__ x,
    const float* __restrict__ p0, const float* __restrict__ p1,
    const float* __restrict__ g, const float* __restrict__ bta,
    float* __restrict__ x1, u16* __restrict__ out)
{
  int row = blockIdx.x, tid = threadIdx.x;
  size_t r0 = (size_t)row * Cc + tid, r1 = r0 + 256;
  float v0 = x[r0] + p0[r0] + p1[r0];
  float v1 = x[r1] + p0[r1] + p1[r1];
  x1[r0] = v0; x1[r1] = v1;
  float s = v0 + v1, s2 = v0*v0 + v1*v1;
  #pragma unroll
  for (int off = 32; off > 0; off >>= 1) {
    s  += __shfl_down(s,  off, 64);
    s2 += __shfl_down(s2, off, 64);
  }
  __shared__ float rs[4], rq[4];
  int w = tid >> 6;
  if ((tid & 63) == 0) { rs[w] = s; rq[w] = s2; }
  __syncthreads();
  float S  = rs[0]+rs[1]+rs[2]+rs[3];
  float S2 = rq[0]+rq[1]+rq[2]+rq[3];
  float mean = S * (1.0f/Cc);
  float var  = S2 * (1.0f/Cc) - mean*mean;
  float inv = rsqrtf(var + 1e-5f);
  int c0 = tid, c1 = tid + 256;
  float o0 = g[c0] * (v0-mean)*inv + bta[c0];
  float o1 = g[c1] * (v1-mean)*inv + bta[c1];
  out[((size_t)(c0 >> 3) * Mrows + row) * 8 + (c0 & 7)] = f2bf(o0);
  out[((size_t)(c1 >> 3) * Mrows + row) * 8 + (c1 & 7)] = f2bf(o1);
}

// ---------------- time-shift mix -> blocked bf16 [C/8][M][8] ----------------
__device__ __forceinline__ void mix_one(const float* tm, int c0,
    float4 ha, float4 hb, float4 xa, float4 xb, u16* dst, size_t i8)
{
  float4 ta = *(const float4*)(tm + c0);
  float4 tb = *(const float4*)(tm + c0 + 4);
  uint4 o;
  o.x = pack2(ha.x*ta.x + xa.x*(1.f-ta.x), ha.y*ta.y + xa.y*(1.f-ta.y));
  o.y = pack2(ha.z*ta.z + xa.z*(1.f-ta.z), ha.w*ta.w + xa.w*(1.f-ta.w));
  o.z = pack2(hb.x*tb.x + xb.x*(1.f-tb.x), hb.y*tb.y + xb.y*(1.f-tb.y));
  o.w = pack2(hb.z*tb.z + xb.z*(1.f-tb.z), hb.w*tb.w + xb.w*(1.f-tb.w));
  *(uint4*)(dst + i8) = o;
}

__global__ __launch_bounds__(256) void mix_kernel(const float* __restrict__ h,
    const float* __restrict__ tmq, const float* __restrict__ tmk,
    const float* __restrict__ tmv, const float* __restrict__ tmg,
    u16* __restrict__ xqb, u16* __restrict__ xkb,
    u16* __restrict__ xvb, u16* __restrict__ xgb)
{
  int i = blockIdx.x * 256 + threadIdx.x;     // kg*4096 + m
  int m = i & 4095, c0 = (i >> 12) << 3;
  const float* hp = h + (size_t)m*Cc + c0;
  float4 ha = *(const float4*)hp, hb = *(const float4*)(hp + 4);
  float4 xa = make_float4(0,0,0,0), xb = make_float4(0,0,0,0);
  if (m & 1023) { xa = *(const float4*)(hp - Cc); xb = *(const float4*)(hp - Cc + 4); }
  size_t i8 = (size_t)i * 8;
  mix_one(tmq, c0, ha, hb, xa, xb, xqb, i8);
  mix_one(tmk, c0, ha, hb, xa, xb, xkb, i8);
  mix_one(tmv, c0, ha, hb, xa, xb, xvb, i8);
  mix_one(tmg, c0, ha, hb, xa, xb, xgb, i8);
}

// ---------------- ALL weights fp32 -> blocked bf16, one dispatch ----------------
__global__ __launch_bounds__(256) void wconv_all_kernel(
    const float* __restrict__ Wq, const float* __restrict__ Wk,
    const float* __restrict__ Wv, const float* __restrict__ Wg,
    const float* __restrict__ Wo, const float* __restrict__ W1,
    const float* __restrict__ W2, u16* __restrict__ out)
{
  int blk = blockIdx.x;
  const float* src; u16* dst; int K, nshift;
  if (blk < 640) {
    int wsel = blk >> 7;
    src = wsel==0?Wq:wsel==1?Wk:wsel==2?Wv:wsel==3?Wg:Wo;
    dst = out + (size_t)wsel*262144; K = 512; nshift = 9; blk &= 127;
  } else if (blk < 1152) {
    src = W1; dst = out + (size_t)5*262144; K = 512; nshift = 11; blk -= 640;
  } else {
    src = W2; dst = out + (size_t)5*262144 + 1048576; K = 2048; nshift = 9; blk -= 1152;
  }
  int i = blk*256 + threadIdx.x;
  int n = i & ((1 << nshift) - 1), kg = i >> nshift;
  const float* p = src + (size_t)n * K + kg * 8;
  float4 a = *(const float4*)p, b = *(const float4*)(p + 4);
  uint4 o;
  o.x = pack2(a.x, a.y); o.y = pack2(a.z, a.w);
  o.z = pack2(b.x, b.y); o.w = pack2(b.z, b.w);
  *(uint4*)(dst + (size_t)i * 8) = o;
}

// ---------------- bf16 MFMA GEMM core (templated dims) ----------------
// A blocked [KR/8][MR][8], W blocked [KR/8][NR][8]. Tile 128x128, BK=32, 4 waves,
// 3-buffer LDS (48KB -> 3 blocks/CU), depth-2 prefetch, counted vmcnt, 1 barrier/K-step.
template<int MR, int NR, int KR>
__device__ __forceinline__ void gemm_core(const u16* __restrict__ A,
    const u16* __restrict__ W, const float* __restrict__ res,
    float* __restrict__ outf, u16* __restrict__ outb, int act,
    int m0, int n0, u16* Asm, u16* Bsm)   // each [3][4096]
{
  const int tid = threadIdx.x, w = tid >> 6, l = tid & 63;
  const int wr = w >> 1, wc = w & 1;
  f32x4 acc[4][4];
  #pragma unroll
  for (int i = 0; i < 4; ++i)
    #pragma unroll
    for (int j = 0; j < 4; ++j) acc[i][j] = (f32x4){0.f,0.f,0.f,0.f};
  const int kgl = l >> 4, rl = l & 15;
  const int q = w * 4;  // wave's load-slot base

  #define STAGE(KT, BUF) do {                                               \
    _Pragma("unroll")                                                       \
    for (int ii = 0; ii < 4; ++ii) {                                        \
      int qq = q + ii;                                                      \
      int isB = qq >> 3, idx = qq & 7, kg = idx >> 1, hf = idx & 1;         \
      const u16* src = isB                                                  \
        ? W + ((size_t)((KT)*4 + kg) * NR + n0 + hf*64 + l) * 8             \
        : A + ((size_t)((KT)*4 + kg) * MR + m0 + hf*64 + l) * 8;            \
      u16* dst = (isB ? Bsm : Asm) + (BUF)*4096 + (kg * 128 + hf * 64) * 8; \
      __builtin_amdgcn_global_load_lds(                                     \
          (const __attribute__((address_space(1))) void*)src,               \
          (__attribute__((address_space(3))) void*)dst, 16, 0, 0);          \
    }                                                                       \
  } while (0)

  constexpr int nk = KR >> 5;
  STAGE(0, 0); STAGE(1, 1);
  int cur = 0;
  for (int kt = 0; kt < nk; ++kt) {
    if (kt == nk - 1) asm volatile("s_waitcnt vmcnt(0)" ::: "memory");
    else              asm volatile("s_waitcnt vmcnt(4)" ::: "memory");
    __builtin_amdgcn_s_barrier();
    bf16x8 af[4], bfr[4];
    #pragma unroll
    for (int f = 0; f < 4; ++f)
      af[f] = *(const bf16x8*)&Asm[cur*4096 + (kgl*128 + wr*64 + f*16 + rl) * 8];
    #pragma unroll
    for (int f = 0; f < 4; ++f)
      bfr[f] = *(const bf16x8*)&Bsm[cur*4096 + (kgl*128 + wc*64 + f*16 + rl) * 8];
    if (kt + 2 < nk) {
      int nb = cur + 2; if (nb >= 3) nb -= 3;
      STAGE(kt + 2, nb);
    }
    __builtin_amdgcn_s_setprio(1);
    #pragma unroll
    for (int i = 0; i < 4; ++i)
      #pragma unroll
      for (int j = 0; j < 4; ++j)
        acc[i][j] = __builtin_amdgcn_mfma_f32_16x16x32_bf16(af[i], bfr[j], acc[i][j], 0, 0, 0);
    __builtin_amdgcn_s_setprio(0);
    if (++cur == 3) cur = 0;
  }
  #undef STAGE

  const int rbase = (l >> 4) * 4, cn = l & 15;
  #pragma unroll
  for (int i = 0; i < 4; ++i) {
    #pragma unroll
    for (int j = 0; j < 4; ++j) {
      #pragma unroll
      for (int r = 0; r < 4; ++r) {
        int m = m0 + wr*64 + i*16 + rbase + r;
        int n = n0 + wc*64 + j*16 + cn;
        float vv = acc[i][j][r];
        if (res) vv += res[(size_t)m * NR + n];
        if (act == 1) vv = 0.5f*vv*(1.f + erff(vv * 0.70710678118f));
        else if (act == 2) vv = 1.f/(1.f + expf(-vv));
        if (outb) outb[((size_t)(n >> 3) * MR + m) * 8 + (n & 7)] = f2bf(vv);
        else outf[(size_t)m * NR + n] = vv;
      }
    }
  }
}

__global__ __launch_bounds__(256) void gemm_qkvg(const u16* __restrict__ xall,
    const u16* __restrict__ Wall, float* __restrict__ outall)
{
  __shared__ __align__(16) u16 Asm[3*4096];
  __shared__ __align__(16) u16 Bsm[3*4096];
  int z = blockIdx.z;
  const size_t E = (size_t)Mrows * Cc;
  gemm_core<Mrows,512,512>(xall + z*E, Wall + (size_t)z*262144, nullptr,
            outall + z*E, nullptr, z == 3 ? 2 : 0,
            blockIdx.y * 128, blockIdx.x * 128, Asm, Bsm);
}

__global__ __launch_bounds__(256) void gemm_wo(const u16* __restrict__ A,
    const u16* __restrict__ W, float* __restrict__ pbuf)
{
  __shared__ __align__(16) u16 Asm[3*4096];
  __shared__ __align__(16) u16 Bsm[3*4096];
  int z = blockIdx.z;
  const size_t E = (size_t)Mrows * Cc;
  gemm_core<Mrows,512,256>(A + (size_t)z*32*Mrows*8, W + (size_t)z*32*512*8, nullptr,
            pbuf + z*E, nullptr, 0, blockIdx.y * 128, blockIdx.x * 128, Asm, Bsm);
}

__global__ __launch_bounds__(256) void gemm_w1(const u16* __restrict__ A,
    const u16* __restrict__ W, u16* __restrict__ outb)
{
  __shared__ __align__(16) u16 Asm[3*4096];
  __shared__ __align__(16) u16 Bsm[3*4096];
  gemm_core<Mrows,2048,512>(A, W, nullptr, nullptr, outb, 1,
            blockIdx.y * 128, blockIdx.x * 128, Asm, Bsm);
}

__global__ __launch_bounds__(256) void gemm_w2(const u16* __restrict__ A,
    const u16* __restrict__ W, float* __restrict__ pbuf)
{
  __shared__ __align__(16) u16 Asm[3*4096];
  __shared__ __align__(16) u16 Bsm[3*4096];
  int z = blockIdx.z;
  const size_t E = (size_t)Mrows * Cc;
  gemm_core<Mrows,512,512>(A + (size_t)z*64*Mrows*8, W + (size_t)z*64*512*8, nullptr,
            pbuf + z*E, nullptr, 0, blockIdx.y * 128, blockIdx.x * 128, Asm, Bsm);
}

// ---------------- out = x1 + p0+p1+p2+p3 ----------------
__global__ __launch_bounds__(256) void reduce4_kernel(const float* __restrict__ x1,
    const float* __restrict__ p, float* __restrict__ out)
{
  const size_t E = (size_t)Mrows * Cc;
  size_t f = ((size_t)blockIdx.x * 256 + threadIdx.x) * 4;
  float4 a = *(const float4*)(x1 + f);
  float4 q0 = *(const float4*)(p + f);
  float4 q1 = *(const float4*)(p + E + f);
  float4 q2 = *(const float4*)(p + 2*E + f);
  float4 q3 = *(const float4*)(p + 3*E + f);
  float4 o;
  o.x = a.x + q0.x + q1.x + q2.x + q3.x;
  o.y = a.y + q0.y + q1.y + q2.y + q3.y;
  o.z = a.z + q0.z + q1.z + q2.z + q3.z;
  o.w = a.w + q0.w + q1.w + q2.w + q3.w;
  *(float4*)(out + f) = o;
}

// ---------------- exp(rmsnorm(x)) in place (q and k in one dispatch) ----------------
__global__ __launch_bounds__(256) void rmsexp_kernel(float* __restrict__ qm,
    float* __restrict__ km, const float* __restrict__ scale)
{
  int row = blockIdx.x, tid = threadIdx.x;
  float* xr = (blockIdx.y ? km : qm) + (size_t)row * Cc;
  float v0 = xr[tid], v1 = xr[tid+256];
  float s2 = v0*v0 + v1*v1;
  #pragma unroll
  for (int off = 32; off > 0; off >>= 1) s2 += __shfl_down(s2, off, 64);
  __shared__ float rq[4];
  int w = tid >> 6;
  if ((tid & 63) == 0) rq[w] = s2;
  __syncthreads();
  float S2 = rq[0]+rq[1]+rq[2]+rq[3];
  float norm = sqrtf(S2) * 0.044194173824159216f;  // 1/sqrt(512)
  float r = 1.f / (norm + 1e-8f);
  xr[tid]     = expf(scale[tid]     * v0 * r);
  xr[tid+256] = expf(scale[tid+256] * v1 * r);
}

// ---------------- Phase A: chunk-local end state (incl. z as col 128) ----------------
__global__ __launch_bounds__(256) void chunk_state_kernel(const float* __restrict__ k,
    const float* __restrict__ v, const float* __restrict__ td, float* __restrict__ Aug)
{
  __shared__ float k_lds[CL][Dd];
  __shared__ float v_lds[CL][Dd];
  int blk = blockIdx.x; int c = blk & (NC-1); int bh = blk >> 5;
  int b = bh >> 2, h = bh & 3;
  int tid = threadIdx.x;
  size_t base = ((size_t)b*Tt + (size_t)c*CL)*Cc + h*Dd;
  #pragma unroll
  for (int r = 0; r < 4; ++r) {
    int idx4 = r*256 + tid;
    int s = idx4 >> 5; int i4 = (idx4 & 31) << 2;
    *(float4*)&k_lds[s][i4] = *(const float4*)&k[base + (size_t)s*Cc + i4];
    *(float4*)&v_lds[s][i4] = *(const float4*)&v[base + (size_t)s*Cc + i4];
  }
  __syncthreads();
  int iq = tid >> 3; int i0 = iq << 2;
  int jg = tid & 7;  int j0 = jg << 4;
  float lam4[4], powv[4], zacc[4];
  #pragma unroll
  for (int ci=0; ci<4; ++ci) {
    lam4[ci] = expf(-expf(td[h*Dd + i0 + ci]));
    powv[ci] = 1.f; zacc[ci] = 0.f;
  }
  float acc[4][16];
  #pragma unroll
  for (int ci=0; ci<4; ++ci)
    #pragma unroll
    for (int jj=0; jj<16; ++jj) acc[ci][jj] = 0.f;

  for (int s = CL-1; s >= 0; --s) {
    float4 k4 = *(const float4*)&k_lds[s][i0];
    float kw0 = powv[0]*k4.x, kw1 = powv[1]*k4.y, kw2 = powv[2]*k4.z, kw3 = powv[3]*k4.w;
    zacc[0]+=kw0; zacc[1]+=kw1; zacc[2]+=kw2; zacc[3]+=kw3;
    #pragma unroll
    for (int q4 = 0; q4 < 4; ++q4) {
      float4 v4 = *(const float4*)&v_lds[s][j0 + q4*4];
      float vv[4] = {v4.x, v4.y, v4.z, v4.w};
      #pragma unroll
      for (int u=0; u<4; ++u) {
        acc[0][q4*4+u] += kw0*vv[u];
        acc[1][q4*4+u] += kw1*vv[u];
        acc[2][q4*4+u] += kw2*vv[u];
        acc[3][q4*4+u] += kw3*vv[u];
      }
    }
    powv[0]*=lam4[0]; powv[1]*=lam4[1]; powv[2]*=lam4[2]; powv[3]*=lam4[3];
  }
  float* aug = Aug + ((size_t)c*16 + bh)*AUGSZ;
  #pragma unroll
  for (int jj=0; jj<16; ++jj) {
    int j = j0 + jj;
    float4 wv = make_float4(acc[0][jj], acc[1][jj], acc[2][jj], acc[3][jj]);
    *(float4*)&aug[(size_t)j*Dd + i0] = wv;
  }
  if (jg == 0)
    *(float4*)&aug[(size_t)Dd*Dd + i0] = make_float4(zacc[0],zacc[1],zacc[2],zacc[3]);
}

// ---------------- Phase B: inter-chunk prefix scan -> bf16 blocked Augb ----------------
__global__ __launch_bounds__(256) void combine_kernel(const float* __restrict__ Aug,
    const float* __restrict__ td, u16* __restrict__ Augb)
{
  int idx = blockIdx.x*256 + threadIdx.x;   // [0, 144*128)
  int bh = blockIdx.y; int h = bh & 3;
  int j = idx >> 7, i = idx & 127;
  size_t aoff = (size_t)(i >> 3) * 1152 + (size_t)j * 8 + (i & 7);
  if (j >= 129) {
    for (int c = 0; c < NC; ++c)
      Augb[((size_t)c*16 + bh)*AUGB_CB + aoff] = 0;
    return;
  }
  float lamL = expf(-expf(td[h*Dd + i]) * (float)CL);
  const float* p = Aug + (size_t)bh*AUGSZ + (size_t)j*Dd + i;
  float prev = 0.f;
  for (int c = 0; c < NC; ++c) {
    float val = p[(size_t)c*AUGSTRIDE];
    Augb[((size_t)c*16 + bh)*AUGB_CB + aoff] = f2bf(prev);
    prev = lamL*prev + val;
  }
}

// ---------------- Phase C: chunked MFMA scan; fused gatt = g*S/Z -> blocked bf16 ----
__global__ __launch_bounds__(256, 2) void scan_mfma_kernel(
    const float* __restrict__ q, const float* __restrict__ k,
    const float* __restrict__ v, const float* __restrict__ td,
    const u16* __restrict__ Augb, const float* __restrict__ gmat,
    u16* __restrict__ out)
{
  __shared__ float k_lds[32*192];     // [s][is*24 + e]
  __shared__ u16  qfrag[32*128];      // [t][(k8 ^ (t&7))*8 + e]
  __shared__ u16  vfrag[4*1152];      // [s8][j(144)][s&7]
  __shared__ float P32[32*33];
  __shared__ u16  pfrag[32*32];       // [t][(s8 ^ (t&3))*8 + (s&7)]
  __shared__ float lam_lds[128];
  __shared__ float zbuf[32];

  const int tid = threadIdx.x;
  const int blk = blockIdx.x; const int c = blk & 31, bh = blk >> 5;
  const int b = bh >> 2, h = bh & 3;
  const int w = tid >> 6, l = tid & 63;
  const int t = (w << 3) + (l >> 3);
  const int is = l & 7;

  if (tid < 128) lam_lds[tid] = expf(-expf(td[h*Dd + tid]));

  const size_t rowbase = ((size_t)(b*Tt + c*CL + t))*Cc + h*Dd + is*16;

  float qv[16];
  {
    #pragma unroll
    for (int c4 = 0; c4 < 4; ++c4) {
      float4 q4 = *(const float4*)(q + rowbase + c4*4);
      qv[c4*4+0]=q4.x; qv[c4*4+1]=q4.y; qv[c4*4+2]=q4.z; qv[c4*4+3]=q4.w;
    }
    float lt = (float)(t + 1);
    u16 qt[16];
    #pragma unroll
    for (int e = 0; e < 16; ++e) {
      float el2 = -expf(td[h*Dd + is*16 + e]) * 1.4426950408889634f;
      qt[e] = f2bf(qv[e] * exp2f(el2 * lt));
    }
    #pragma unroll
    for (int hf = 0; hf < 2; ++hf) {
      int k8 = is*2 + hf;
      uint4 pk;
      pk.x = (unsigned)qt[hf*8+0] | ((unsigned)qt[hf*8+1]<<16);
      pk.y = (unsigned)qt[hf*8+2] | ((unsigned)qt[hf*8+3]<<16);
      pk.z = (unsigned)qt[hf*8+4] | ((unsigned)qt[hf*8+5]<<16);
      pk.w = (unsigned)qt[hf*8+6] | ((unsigned)qt[hf*8+7]<<16);
      *(uint4*)&qfrag[t*128 + ((k8 ^ (t&7))<<3)] = pk;
    }
  }
  #pragma unroll
  for (int c4 = 0; c4 < 4; ++c4)
    *(float4*)&k_lds[t*192 + is*24 + c4*4] = *(const float4*)(k + rowbase + c4*4);
  #pragma unroll
  for (int c4 = 0; c4 < 4; ++c4) {
    float4 v4 = *(const float4*)(v + rowbase + c4*4);
    int j0 = is*16 + c4*4;
    vfrag[(t>>3)*1152 + (j0+0)*8 + (t&7)] = f2bf(v4.x);
    vfrag[(t>>3)*1152 + (j0+1)*8 + (t&7)] = f2bf(v4.y);
    vfrag[(t>>3)*1152 + (j0+2)*8 + (t&7)] = f2bf(v4.z);
    vfrag[(t>>3)*1152 + (j0+3)*8 + (t&7)] = f2bf(v4.w);
  }
  if (tid < 32) vfrag[(tid>>3)*1152 + 128*8 + (tid&7)] = 0x3F80;
  if (tid < 240) {
    #pragma unroll
    for (int u = 0; u < 2; ++u) {
      int e = tid*2 + u;
      int ig = e / 120, rem = e % 120;
      vfrag[ig*1152 + (129 + rem/8)*8 + (rem&7)] = 0;
    }
  }
  __syncthreads();

  {
    float lamr[16], wrun[16];
    #pragma unroll
    for (int e4 = 0; e4 < 4; ++e4) {
      float4 l4 = *(const float4*)&lam_lds[is*16 + e4*4];
      lamr[e4*4+0]=l4.x; lamr[e4*4+1]=l4.y; lamr[e4*4+2]=l4.z; lamr[e4*4+3]=l4.w;
    }
    #pragma unroll
    for (int e = 0; e < 16; ++e) wrun[e] = 1.f;
    const int smax = (w << 3) + 7;
    for (int s = smax; s >= 0; --s) {
      float dot = 0.f;
      #pragma unroll
      for (int c4 = 0; c4 < 4; ++c4) {
        float4 k4 = *(const float4*)&k_lds[s*192 + is*24 + c4*4];
        dot = fmaf(qv[c4*4+0], k4.x*wrun[c4*4+0], dot);
        dot = fmaf(qv[c4*4+1], k4.y*wrun[c4*4+1], dot);
        dot = fmaf(qv[c4*4+2], k4.z*wrun[c4*4+2], dot);
        dot = fmaf(qv[c4*4+3], k4.w*wrun[c4*4+3], dot);
      }
      dot += __shfl_xor(dot, 1);
      dot += __shfl_xor(dot, 2);
      dot += __shfl_xor(dot, 4);
      bool act = (s <= t);
      if (act && is == 0) P32[t*33 + s] = dot;
      if (act) {
        #pragma unroll
        for (int e = 0; e < 16; ++e) wrun[e] *= lamr[e];
      }
    }
  }
  __syncthreads();
  {
    int tt = tid >> 3, s0 = (tid & 7) * 4;
    #pragma unroll
    for (int ss = 0; ss < 4; ++ss) {
      int s = s0 + ss;
      float val = (s <= tt) ? P32[tt*33 + s] : 0.f;
      pfrag[tt*32 + (((s>>3) ^ (tt&3))<<3) + (s&7)] = f2bf(val);
    }
  }
  __syncthreads();

  const int tau = w >> 1;
  const int jt0 = (w & 1) ? 5 : 0;
  const int njt = (w & 1) ? 4 : 5;
  const int rl = l & 15, kg = l >> 4;
  const int trow = tau*16 + rl;
  const u16* augb_base = Augb + ((size_t)c*16 + bh)*AUGB_CB;

  bf16x8 aq[4];
  #pragma unroll
  for (int kk = 0; kk < 4; ++kk)
    aq[kk] = *(const bf16x8*)&qfrag[trow*128 + ((((kk<<2)+kg) ^ (trow&7))<<3)];
  bf16x8 ap = *(const bf16x8*)&pfrag[trow*32 + ((kg ^ (trow&3))<<3)];

  f32x4 acc[5];
  #pragma unroll
  for (int u = 0; u < 5; ++u) acc[u] = (f32x4){0.f,0.f,0.f,0.f};

  #pragma unroll
  for (int u = 0; u < 5; ++u) {
    if (u < njt) {
      int jt = jt0 + u;
      #pragma unroll
      for (int kk = 0; kk < 4; ++kk) {
        bf16x8 bfr = *(const bf16x8*)&augb_base[(size_t)(((kk<<2)+kg)*1152 + (jt*16 + rl)*8)];
        acc[u] = __builtin_amdgcn_mfma_f32_16x16x32_bf16(aq[kk], bfr, acc[u], 0, 0, 0);
      }
      bf16x8 bv = *(const bf16x8*)&vfrag[kg*1152 + (jt*16 + rl)*8];
      acc[u] = __builtin_amdgcn_mfma_f32_16x16x32_bf16(ap, bv, acc[u], 0, 0, 0);
    }
  }
  if ((w & 1) && rl == 0) {
    #pragma unroll
    for (int r = 0; r < 4; ++r) zbuf[tau*16 + kg*4 + r] = acc[3][r];
  }
  __syncthreads();

  const int nout = (w & 1) ? 3 : 5;
  #pragma unroll
  for (int u = 0; u < 5; ++u) {
    if (u < nout) {
      int jt = jt0 + u;
      int cc = h*Dd + jt*16 + rl;
      #pragma unroll
      for (int r = 0; r < 4; ++r) {
        int tr = tau*16 + kg*4 + r;
        int m = b*Tt + c*CL + tr;
        float zv = zbuf[tr];
        float gv = gmat[(size_t)m*Cc + cc];
        out[((size_t)(cc >> 3) * Mrows + m) * 8 + (cc & 7)] = f2bf(gv * acc[u][r] / zv);
      }
    }
  }
}

extern "C" void kernel_launch(void* const* d_in, const int* in_sizes, int n_in,
                              void* d_out, int out_size, void* d_ws, size_t ws_size,
                              hipStream_t stream) {
  const float* x    = (const float*)d_in[0];
  const float* ln1g = (const float*)d_in[1];
  const float* ln1b = (const float*)d_in[2];
  const float* ln2g = (const float*)d_in[3];
  const float* ln2b = (const float*)d_in[4];
  const float* td   = (const float*)d_in[5];
  const float* tmq  = (const float*)d_in[6];
  const float* tmk  = (const float*)d_in[7];
  const float* tmv  = (const float*)d_in[8];
  const float* tmg  = (const float*)d_in[9];
  const float* Wq   = (const float*)d_in[10];
  const float* Wk   = (const float*)d_in[11];
  const float* Wv   = (const float*)d_in[12];
  const float* Wg   = (const float*)d_in[13];
  const float* Wo   = (const float*)d_in[14];
  const float* rsc  = (const float*)d_in[15];
  const float* W1   = (const float*)d_in[16];
  const float* W2   = (const float*)d_in[17];
  float* ws = (float*)d_ws;
  const size_t E = (size_t)Mrows*Cc;           // 2,097,152 floats
  float* s0 = ws;          // h -> q -> W2 partial0
  float* s1 = ws + E;      // k -> W2 p1
  float* s2 = ws + 2*E;    // v -> Wo p0 -> W2 p2
  float* s3 = ws + 3*E;    // g -> Wo p1 -> W2 p3
  float* x1 = ws + 4*E;    // x + att
  u16* xqb = (u16*)(ws + 5*E);             // E u16 each, contiguous x4
  u16* xkb = xqb + E;
  u16* xvb = xkb + E;
  u16* xgb = xvb + E;
  float* Aug = ws + 7*E;                   // 8,454,144 floats; reused as midb
  u16* midb = (u16*)Aug;                   // 4096*2048 u16 = 16.8MB
  float* wreg = ws + 7*E + (size_t)NC*16*AUGSZ;
  u16* Wqb = (u16*)wreg;                   // 5 x 262144 u16, contiguous
  u16* W1b = Wqb + 5*262144;               // 1,048,576 u16
  u16* W2b = W1b + 1048576;                // 1,048,576 u16
  u16* Wob = Wqb + 4*262144;
  u16* Augb = W2b + 1048576;               // NC*16*AUGB_CB u16 (18.9MB)
  u16* gattb = xqb;                        // reuse (xq dead after qkvg GEMM)
  u16* h2b   = xkb;                        // reuse (xk dead after qkvg GEMM)

  wconv_all_kernel<<<1664,256,0,stream>>>(Wq, Wk, Wv, Wg, Wo, W1, W2, Wqb);

  ln_kernel<<<Mrows,256,0,stream>>>(x, ln1g, ln1b, s0);
  mix_kernel<<<1024,256,0,stream>>>(s0, tmq,tmk,tmv,tmg, xqb,xkb,xvb,xgb);
  gemm_qkvg<<<dim3(4,32,4),256,0,stream>>>(xqb, Wqb, s0);                  // q,k,v,g
  rmsexp_kernel<<<dim3(Mrows,2),256,0,stream>>>(s0, s1, rsc);              // q,k
  chunk_state_kernel<<<16*NC,256,0,stream>>>(s1, s2, td, Aug);
  combine_kernel<<<dim3(72,16),256,0,stream>>>(Aug, td, Augb);             // -> bf16 frags
  scan_mfma_kernel<<<16*NC,256,0,stream>>>(s0, s1, s2, td, Augb, s3, gattb);
  gemm_wo<<<dim3(4,32,2),256,0,stream>>>(gattb, Wob, s2);                  // p0,p1 -> s2,s3
  ln2b_kernel<<<Mrows,256,0,stream>>>(x, s2, s3, ln2g, ln2b, x1, h2b);     // x1, h2 bf16
  gemm_w1<<<dim3(16,32),256,0,stream>>>(h2b, W1b, midb);                   // gelu -> midb
  gemm_w2<<<dim3(4,32,4),256,0,stream>>>(midb, W2b, s0);                   // partials s0..s3
  reduce4_kernel<<<2048,256,0,stream>>>(x1, s0, (float*)d_out);
}